// Round 3
// baseline (7170.314 us; speedup 1.0000x reference)
//
#include <hip/hip_runtime.h>
#include <cstdint>
#include <cstddef>

#define N_NODES 20000
#define N_EDGES 160000
#define IN_CH   128
#define NH      16
#define CD      32
#define HC      512   // NH*CD
#define ED      93
#define NB      64

// ---------------------------------------------------------------- utilities

__device__ inline void atomicMaxF(float* addr, float val) {
    unsigned int* ua = (unsigned int*)addr;
    unsigned int old = *ua;
    while (__uint_as_float(old) < val) {
        unsigned int assumed = old;
        old = atomicCAS(ua, assumed, __float_as_uint(val));
        if (old == assumed) break;
    }
}

__global__ void k_fill(float* __restrict__ p, float v, int n) {
    int i = blockIdx.x * blockDim.x + threadIdx.x;
    int stride = gridDim.x * blockDim.x;
    for (; i < n; i += stride) p[i] = v;
}

// ---------------------------------------------------------------- GEMM (f32)
// Y[M,N] = A[M,K] @ W[K,N] + bias(optional). 64x64 tile, 16x16 threads, 4x4/thread.

#define BMT 64
#define BNT 64
#define BKT 16
#define PADW 68

__global__ __launch_bounds__(256) void k_gemm_bias(
    const float* __restrict__ A, const float* __restrict__ W,
    const float* __restrict__ bias, float* __restrict__ Y,
    int M, int K, int N) {
    __shared__ float As[BKT][PADW];
    __shared__ float Ws[BKT][PADW];
    int tid = threadIdx.x;
    int tx = tid & 15, ty = tid >> 4;
    int row0 = blockIdx.x * BMT, col0 = blockIdx.y * BNT;
    float acc[4][4] = {};

    for (int k0 = 0; k0 < K; k0 += BKT) {
        // stage A tile (transposed to As[k][m])
        {
            int mm = tid >> 2;
            int kbase = (tid & 3) * 4;
            int grow = row0 + mm;
#pragma unroll
            for (int i = 0; i < 4; ++i) {
                int gk = k0 + kbase + i;
                As[kbase + i][mm] = (grow < M && gk < K) ? A[(size_t)grow * K + gk] : 0.f;
            }
        }
        // stage W tile
        {
            int kk = tid >> 4;
            int nb = (tid & 15) * 4;
            int gk = k0 + kk;
#pragma unroll
            for (int i = 0; i < 4; ++i) {
                int gc = col0 + nb + i;
                Ws[kk][nb + i] = (gk < K && gc < N) ? W[(size_t)gk * N + gc] : 0.f;
            }
        }
        __syncthreads();
#pragma unroll
        for (int kk = 0; kk < BKT; ++kk) {
            float a0 = As[kk][ty * 4 + 0];
            float a1 = As[kk][ty * 4 + 1];
            float a2 = As[kk][ty * 4 + 2];
            float a3 = As[kk][ty * 4 + 3];
            float w0 = Ws[kk][tx * 4 + 0];
            float w1 = Ws[kk][tx * 4 + 1];
            float w2 = Ws[kk][tx * 4 + 2];
            float w3 = Ws[kk][tx * 4 + 3];
            acc[0][0] += a0 * w0; acc[0][1] += a0 * w1; acc[0][2] += a0 * w2; acc[0][3] += a0 * w3;
            acc[1][0] += a1 * w0; acc[1][1] += a1 * w1; acc[1][2] += a1 * w2; acc[1][3] += a1 * w3;
            acc[2][0] += a2 * w0; acc[2][1] += a2 * w1; acc[2][2] += a2 * w2; acc[2][3] += a2 * w3;
            acc[3][0] += a3 * w0; acc[3][1] += a3 * w1; acc[3][2] += a3 * w2; acc[3][3] += a3 * w3;
        }
        __syncthreads();
    }
#pragma unroll
    for (int i = 0; i < 4; ++i) {
        int r = row0 + ty * 4 + i;
        if (r >= M) continue;
#pragma unroll
        for (int j = 0; j < 4; ++j) {
            int c = col0 + tx * 4 + j;
            if (c < N) {
                float b = bias ? bias[c] : 0.f;
                Y[(size_t)r * N + c] = acc[i][j] + b;
            }
        }
    }
}

// ---------------------------------------------------------------- edge kernels
// All edge kernels operate on a CHUNK of edges: src/dst/alpha pointers are
// pre-offset by the caller; `e` is the chunk-local edge-feature tile.

// one thread per (edge, head): alpha = dot32(q[dst], k[src]+e) / sqrt(32)
__global__ __launch_bounds__(256) void k_alpha(
    const float* __restrict__ q, const float* __restrict__ k,
    const float* __restrict__ e, const int* __restrict__ src,
    const int* __restrict__ dst, float* __restrict__ alpha,
    float* __restrict__ amax, int n) {
    int t = blockIdx.x * blockDim.x + threadIdx.x;
    if (t >= n) return;
    int eid = t >> 4, h = t & 15;
    int sn = src[eid], dn = dst[eid];
    const float4* qp = (const float4*)(q + (size_t)dn * HC + h * CD);
    const float4* kp = (const float4*)(k + (size_t)sn * HC + h * CD);
    const float4* ep = (const float4*)(e + (size_t)eid * HC + h * CD);
    float acc = 0.f;
#pragma unroll
    for (int i = 0; i < 8; ++i) {
        float4 qv = qp[i], kv = kp[i], ev = ep[i];
        acc += qv.x * (kv.x + ev.x) + qv.y * (kv.y + ev.y)
             + qv.z * (kv.z + ev.z) + qv.w * (kv.w + ev.w);
    }
    acc *= 0.17677669529663687f;  // 1/sqrt(32)
    alpha[t] = acc;
    atomicMaxF(&amax[dn * NH + h], acc);
}

// whole-edge-set pass (no e needed): alpha -> exp(alpha - max), accumulate denom
__global__ __launch_bounds__(256) void k_exp(
    float* __restrict__ alpha, const float* __restrict__ amax,
    const int* __restrict__ dst, float* __restrict__ denom, int n) {
    int t = blockIdx.x * blockDim.x + threadIdx.x;
    if (t >= n) return;
    int eid = t >> 4, h = t & 15;
    int dn = dst[eid];
    float ex = __expf(alpha[t] - amax[dn * NH + h]);
    alpha[t] = ex;
    atomicAdd(&denom[dn * NH + h], ex);
}

// one block (128 threads) per edge; each thread 4 channels
__global__ __launch_bounds__(128) void k_msg(
    const float* __restrict__ v, const float* __restrict__ e,
    const float* __restrict__ ex, const float* __restrict__ denom,
    const int* __restrict__ src, const int* __restrict__ dst,
    float* __restrict__ agg) {
    int eid = blockIdx.x;
    int t = threadIdx.x;
    int c = t * 4;
    int h = t >> 3;
    int sn = src[eid], dn = dst[eid];
    float a = ex[eid * NH + h] / denom[dn * NH + h];
    float4 vv = *(const float4*)(v + (size_t)sn * HC + c);
    float4 ev = *(const float4*)(e + (size_t)eid * HC + c);
    float* ap = agg + (size_t)dn * HC + c;
    atomicAdd(ap + 0, (vv.x + ev.x) * a);
    atomicAdd(ap + 1, (vv.y + ev.y) * a);
    atomicAdd(ap + 2, (vv.z + ev.z) * a);
    atomicAdd(ap + 3, (vv.w + ev.w) * a);
}

// x_out = leaky_relu(agg, 0.2)   (skip already fused into agg by the skip GEMM)
__global__ void k_epi(const float* __restrict__ agg, float* __restrict__ xout, int n) {
    int i = blockIdx.x * blockDim.x + threadIdx.x;
    int stride = gridDim.x * blockDim.x;
    for (; i < n; i += stride) {
        float v = agg[i];
        xout[i] = v >= 0.f ? v : 0.2f * v;
    }
}

// ---------------------------------------------------------------- pooling

__global__ void k_count(const int* __restrict__ batch, int* __restrict__ cnt) {
    int i = blockIdx.x * blockDim.x + threadIdx.x;
    if (i < N_NODES) atomicAdd(&cnt[batch[i]], 1);
}

__global__ void k_pool(const float* __restrict__ x, const int* __restrict__ batch,
                       float* __restrict__ psum, float* __restrict__ pmax) {
    int i = blockIdx.x * blockDim.x + threadIdx.x;
    int stride = gridDim.x * blockDim.x;
    for (; i < N_NODES * HC; i += stride) {
        int n = i >> 9, c = i & (HC - 1);
        float val = x[i];
        int b = batch[n];
        atomicAdd(&psum[b * HC + c], val);
        atomicMaxF(&pmax[b * HC + c], val);
    }
}

// hsum[B,1024] = [mean | max] ; mode 0: write, 1: add
__global__ void k_poolfin(const float* __restrict__ psum, const float* __restrict__ pmax,
                          const int* __restrict__ cnt, float* __restrict__ hsum, int mode) {
    int i = blockIdx.x * blockDim.x + threadIdx.x;
    if (i >= NB * 1024) return;
    int b = i >> 10, c = i & 1023;
    float val;
    if (c < HC) {
        int ct = cnt[b];
        val = psum[b * HC + c] / (float)(ct > 0 ? ct : 1);
    } else {
        val = pmax[b * HC + (c - HC)];
    }
    if (mode == 0) hsum[i] = val;
    else hsum[i] += val;
}

// ---------------------------------------------------------------- MLP head
// 64 blocks (one per graph), 256 threads.
__global__ __launch_bounds__(256) void k_head(
    const float* __restrict__ hsum, const float* __restrict__ fc1W,
    const float* __restrict__ fc1b, const float* __restrict__ fc2W,
    const float* __restrict__ fc2b, float* __restrict__ out) {
    int b = blockIdx.x;
    int j = threadIdx.x;
    __shared__ float hs[256];
    float acc = fc1b[j];
    const float* hin = hsum + (size_t)b * 1024;
    for (int k = 0; k < 1024; ++k) {
        acc += hin[k] * fc1W[(size_t)k * 256 + j];
    }
    hs[j] = fmaxf(acc, 0.f);
    __syncthreads();
    if (j < 32) {
        float o = fc2b[j];
        for (int k = 0; k < 256; ++k) o += hs[k] * fc2W[(size_t)k * 32 + j];
        out[b * 32 + j] = o;
    }
}

// ---------------------------------------------------------------- driver

static inline void gemm(const float* A, const float* W, const float* bias, float* Y,
                        int M, int K, int N, hipStream_t stream) {
    dim3 grid((M + BMT - 1) / BMT, (N + BNT - 1) / BNT);
    hipLaunchKernelGGL(k_gemm_bias, grid, dim3(256), 0, stream, A, W, bias, Y, M, K, N);
}

extern "C" void kernel_launch(void* const* d_in, const int* in_sizes, int n_in,
                              void* d_out, int out_size, void* d_ws, size_t ws_size,
                              hipStream_t stream) {
    const float* x      = (const float*)d_in[0];
    const float* ea     = (const float*)d_in[1];
    const int*   ei     = (const int*)d_in[2];
    const int*   batch  = (const int*)d_in[3];
    const int* src = ei;
    const int* dst = ei + N_EDGES;

    const float* t1_Wq = (const float*)d_in[4];
    const float* t1_bq = (const float*)d_in[5];
    const float* t1_Wk = (const float*)d_in[6];
    const float* t1_bk = (const float*)d_in[7];
    const float* t1_Wv = (const float*)d_in[8];
    const float* t1_bv = (const float*)d_in[9];
    const float* t1_We = (const float*)d_in[10];
    const float* t1_Ws = (const float*)d_in[11];
    const float* t1_bs = (const float*)d_in[12];
    const float* t2_Wq = (const float*)d_in[13];
    const float* t2_bq = (const float*)d_in[14];
    const float* t2_Wk = (const float*)d_in[15];
    const float* t2_bk = (const float*)d_in[16];
    const float* t2_Wv = (const float*)d_in[17];
    const float* t2_bv = (const float*)d_in[18];
    const float* t2_We = (const float*)d_in[19];
    const float* t2_Ws = (const float*)d_in[20];
    const float* t2_bs = (const float*)d_in[21];
    const float* fc1_W = (const float*)d_in[22];
    const float* fc1_b = (const float*)d_in[23];
    const float* fc2_W = (const float*)d_in[24];
    const float* fc2_b = (const float*)d_in[25];

    char* ws = (char*)d_ws;
    size_t off = 0;
    auto alloc = [&](size_t bytes) -> void* {
        void* p = ws + off;
        off = (off + bytes + 255) & ~(size_t)255;
        return p;
    };

    float* qb   = (float*)alloc((size_t)N_NODES * HC * 4);
    float* kb   = (float*)alloc((size_t)N_NODES * HC * 4);
    float* vb   = (float*)alloc((size_t)N_NODES * HC * 4);
    float* agg  = (float*)alloc((size_t)N_NODES * HC * 4);   // skip + messages
    float* x1   = (float*)alloc((size_t)N_NODES * HC * 4);
    float* alp  = (float*)alloc((size_t)N_EDGES * NH * 4);
    float* amax = (float*)alloc((size_t)N_NODES * NH * 4);
    float* den  = (float*)alloc((size_t)N_NODES * NH * 4);
    float* psum = (float*)alloc((size_t)NB * HC * 4);
    float* pmax = (float*)alloc((size_t)NB * HC * 4);
    float* hsum = (float*)alloc((size_t)NB * 1024 * 4);
    int*   cnt  = (int*)alloc((size_t)NB * 4);

    // Remaining workspace -> edge-feature chunk buffer eb [EC, HC].
    size_t remain = (ws_size > off) ? (ws_size - off) : 0;
    float* eb = (float*)(ws + off);
    size_t per_edge = (size_t)HC * 4;  // 2 KiB
    int EC;
    bool full = (remain >= (size_t)N_EDGES * per_edge);
    if (full) {
        EC = N_EDGES;
    } else {
        EC = (int)(remain / per_edge);
        EC &= ~63;                    // multiple of 64
        if (EC <= 0) EC = 64;         // last resort (shouldn't happen)
        if (EC > N_EDGES) EC = N_EDGES;
    }
    (void)in_sizes; (void)n_in; (void)out_size;

    const int EH = N_EDGES * NH;
    const int NHC = N_NODES * HC;

    auto run_layer = [&](const float* xin, int Kin,
                         const float* Wq, const float* bq, const float* Wk, const float* bk,
                         const float* Wv, const float* bv, const float* We,
                         const float* Wsk, const float* bsk,
                         float* xout, int poolmode) {
        gemm(xin, Wq, bq, qb, N_NODES, Kin, HC, stream);
        gemm(xin, Wk, bk, kb, N_NODES, Kin, HC, stream);
        gemm(xin, Wv, bv, vb, N_NODES, Kin, HC, stream);
        gemm(xin, Wsk, bsk, agg, N_NODES, Kin, HC, stream);  // skip into agg

        hipLaunchKernelGGL(k_fill, dim3(512), dim3(256), 0, stream, amax, -1e30f, N_NODES * NH);
        hipLaunchKernelGGL(k_fill, dim3(512), dim3(256), 0, stream, den, 0.f, N_NODES * NH);

        // pass A: e-chunk GEMM + alpha/max
        for (int e0 = 0; e0 < N_EDGES; e0 += EC) {
            int ec = (N_EDGES - e0 < EC) ? (N_EDGES - e0) : EC;
            gemm(ea + (size_t)e0 * ED, We, nullptr, eb, ec, ED, HC, stream);
            int n = ec * NH;
            hipLaunchKernelGGL(k_alpha, dim3((n + 255) / 256), dim3(256), 0, stream,
                               qb, kb, eb, src + e0, dst + e0, alp + (size_t)e0 * NH, amax, n);
        }
        // pass B: exp + denom (no e needed)
        hipLaunchKernelGGL(k_exp, dim3((EH + 255) / 256), dim3(256), 0, stream,
                           alp, amax, dst, den, EH);
        // pass C: messages (re-GEMM chunk only if e didn't fit whole)
        for (int e0 = 0; e0 < N_EDGES; e0 += EC) {
            int ec = (N_EDGES - e0 < EC) ? (N_EDGES - e0) : EC;
            if (!full) gemm(ea + (size_t)e0 * ED, We, nullptr, eb, ec, ED, HC, stream);
            hipLaunchKernelGGL(k_msg, dim3(ec), dim3(128), 0, stream,
                               vb, eb, alp + (size_t)e0 * NH, den, src + e0, dst + e0, agg);
        }
        hipLaunchKernelGGL(k_epi, dim3(2048), dim3(256), 0, stream, agg, xout, NHC);

        // pooling
        hipLaunchKernelGGL(k_fill, dim3(128), dim3(256), 0, stream, psum, 0.f, NB * HC);
        hipLaunchKernelGGL(k_fill, dim3(128), dim3(256), 0, stream, pmax, -1e30f, NB * HC);
        hipLaunchKernelGGL(k_fill, dim3(1), dim3(64), 0, stream, (float*)cnt, 0.f, NB);
        hipLaunchKernelGGL(k_count, dim3((N_NODES + 255) / 256), dim3(256), 0, stream, batch, cnt);
        hipLaunchKernelGGL(k_pool, dim3(4096), dim3(256), 0, stream, xout, batch, psum, pmax);
        hipLaunchKernelGGL(k_poolfin, dim3((NB * 1024 + 255) / 256), dim3(256), 0, stream,
                           psum, pmax, cnt, hsum, poolmode);
    };

    // layer 1: input x (N,128) -> x1
    run_layer(x, IN_CH, t1_Wq, t1_bq, t1_Wk, t1_bk, t1_Wv, t1_bv, t1_We, t1_Ws, t1_bs,
              x1, /*poolmode=*/0);
    // layer 2: input x1 (N,512) -> x1 (in-place after all consumers done)
    run_layer(x1, HC, t2_Wq, t2_bq, t2_Wk, t2_bk, t2_Wv, t2_bv, t2_We, t2_Ws, t2_bs,
              x1, /*poolmode=*/1);

    hipLaunchKernelGGL(k_head, dim3(NB), dim3(256), 0, stream,
                       hsum, fc1_W, fc1_b, fc2_W, fc2_b, (float*)d_out);
}

// Round 5
// 4365.492 us; speedup vs baseline: 1.6425x; 1.6425x over previous
//
#include <hip/hip_runtime.h>
#include <cstdint>
#include <cstddef>

#define N_NODES 20000
#define N_EDGES 160000
#define IN_CH   128
#define NH      16
#define CD      32
#define HC      512   // NH*CD
#define ED      93
#define EDP     96    // ED padded to multiple of 32
#define NB      64

typedef __attribute__((ext_vector_type(8))) short short8;
typedef __attribute__((ext_vector_type(4))) float f32x4;
typedef unsigned short ushort_t;

// ---------------------------------------------------------------- utilities

__device__ inline void atomicMaxF(float* addr, float val) {
    unsigned int* ua = (unsigned int*)addr;
    unsigned int old = *ua;
    while (__uint_as_float(old) < val) {
        unsigned int assumed = old;
        old = atomicCAS(ua, assumed, __float_as_uint(val));
        if (old == assumed) break;
    }
}

__device__ inline ushort_t f2bf(float f) {
    unsigned int u = __float_as_uint(f);
    u = (u + 0x7FFF + ((u >> 16) & 1)) >> 16;   // RNE
    return (ushort_t)u;
}

__device__ inline uint4 pack8(const ushort_t* t) {
    uint4 u;
    u.x = (unsigned)t[0] | ((unsigned)t[1] << 16);
    u.y = (unsigned)t[2] | ((unsigned)t[3] << 16);
    u.z = (unsigned)t[4] | ((unsigned)t[5] << 16);
    u.w = (unsigned)t[6] | ((unsigned)t[7] << 16);
    return u;
}

__global__ void k_fill(float* __restrict__ p, float v, int n) {
    int i = blockIdx.x * blockDim.x + threadIdx.x;
    int stride = gridDim.x * blockDim.x;
    for (; i < n; i += stride) p[i] = v;
}

// W [K,N] f32 -> Wt [N,Kp] bf16 (transpose + pad)
__global__ void k_cvt_wt(const float* __restrict__ W, ushort_t* __restrict__ Wt,
                         int K, int N, int Kp) {
    int i = blockIdx.x * blockDim.x + threadIdx.x;
    int stride = gridDim.x * blockDim.x;
    int total = N * Kp;
    for (; i < total; i += stride) {
        int n = i / Kp, k = i - n * Kp;
        Wt[i] = (k < K) ? f2bf(W[(size_t)k * N + n]) : (ushort_t)0;
    }
}

// ---------------------------------------------------------------- MFMA GEMM
// Y[M,N] = A[M,K](f32, converted to bf16 in staging) @ Bt[N,Kp](bf16)^T + bias.
// 128x128 tile, 4 waves, BK=32, 16x16x32 MFMA, f32 accum. 64B LDS rows,
// 16B XOR swizzle by (row&3).

__global__ __launch_bounds__(256) void k_mfma_gemm(
    const float* __restrict__ A, const ushort_t* __restrict__ Bt,
    const float* __restrict__ bias, float* __restrict__ Y,
    int M, int K, int Kp, int N) {
    __shared__ ushort_t lds[2 * 128 * 32];   // 16 KB
    char* As = (char*)lds;
    char* Bs = (char*)(lds + 128 * 32);

    int tid  = threadIdx.x;
    int lane = tid & 63, wave = tid >> 6;
    int l15 = lane & 15, lg = lane >> 4;
    int bm = blockIdx.x * 128, bn = blockIdx.y * 128;
    int wm = (wave >> 1) * 64, wn = (wave & 1) * 64;

    f32x4 acc[4][4] = {};

    // staging: thread t -> row = t>>1, 16-elem half = t&1
    int srow = tid >> 1;
    int skb  = (tid & 1) * 32;               // byte offset in 64B row
    int ssw  = (srow & 3) << 4;              // XOR swizzle for this row
    int sb0  = skb ^ ssw;
    int sb1  = (skb + 16) ^ ssw;
    int grow = bm + srow;
    int brow = bn + srow;

    // fragment-read constants
    int fsw = (l15 & 3) << 4;
    int fkb = (lg * 16) ^ fsw;               // byte offset of this lane's 16B

    bool kvec = ((K & 31) == 0);             // node GEMMs: no K guards needed

    for (int k0 = 0; k0 < Kp; k0 += 32) {
        int kbase = k0 + (tid & 1) * 16;
        // stage A (f32 -> bf16)
        {
            ushort_t ta[16];
            if (grow < M) {
                if (kvec) {
                    const float4* ga = (const float4*)(A + (size_t)grow * K + kbase);
#pragma unroll
                    for (int i = 0; i < 4; ++i) {
                        float4 f = ga[i];
                        ta[4 * i + 0] = f2bf(f.x); ta[4 * i + 1] = f2bf(f.y);
                        ta[4 * i + 2] = f2bf(f.z); ta[4 * i + 3] = f2bf(f.w);
                    }
                } else {
                    const float* ga = A + (size_t)grow * K;
#pragma unroll
                    for (int i = 0; i < 16; ++i) {
                        int gk = kbase + i;
                        ta[i] = (gk < K) ? f2bf(ga[gk]) : (ushort_t)0;
                    }
                }
            } else {
#pragma unroll
                for (int i = 0; i < 16; ++i) ta[i] = 0;
            }
            *(uint4*)(As + srow * 64 + sb0) = pack8(ta);
            *(uint4*)(As + srow * 64 + sb1) = pack8(ta + 8);
        }
        // stage B (bf16, Kp-padded: no K guard)
        {
            uint4 v0 = {0, 0, 0, 0}, v1 = {0, 0, 0, 0};
            if (brow < N) {
                const ushort_t* gb = Bt + (size_t)brow * Kp + kbase;
                v0 = *(const uint4*)(gb);
                v1 = *(const uint4*)(gb + 8);
            }
            *(uint4*)(Bs + srow * 64 + sb0) = v0;
            *(uint4*)(Bs + srow * 64 + sb1) = v1;
        }
        __syncthreads();

        short8 af[4], bfr[4];
#pragma unroll
        for (int mr = 0; mr < 4; ++mr)
            af[mr] = *(const short8*)(As + (wm + mr * 16 + l15) * 64 + fkb);
#pragma unroll
        for (int nc = 0; nc < 4; ++nc)
            bfr[nc] = *(const short8*)(Bs + (wn + nc * 16 + l15) * 64 + fkb);
#pragma unroll
        for (int mr = 0; mr < 4; ++mr)
#pragma unroll
            for (int nc = 0; nc < 4; ++nc)
                acc[mr][nc] = __builtin_amdgcn_mfma_f32_16x16x32_bf16(
                    af[mr], bfr[nc], acc[mr][nc], 0, 0, 0);
        __syncthreads();
    }

    // epilogue: C col = lane&15, row = (lane>>4)*4 + j  (m89-verified)
#pragma unroll
    for (int mr = 0; mr < 4; ++mr) {
#pragma unroll
        for (int nc = 0; nc < 4; ++nc) {
            int col = bn + wn + nc * 16 + l15;
            if (col >= N) continue;
            float b = bias ? bias[col] : 0.f;
#pragma unroll
            for (int j = 0; j < 4; ++j) {
                int row = bm + wm + mr * 16 + lg * 4 + j;
                if (row < M) Y[(size_t)row * N + col] = acc[mr][nc][j] + b;
            }
        }
    }
}

// ---------------------------------------------------------------- edge kernels
// Edge kernels operate on a CHUNK: src/dst/alpha pre-offset; e chunk-local.

__global__ __launch_bounds__(256) void k_alpha(
    const float* __restrict__ q, const float* __restrict__ k,
    const float* __restrict__ e, const int* __restrict__ src,
    const int* __restrict__ dst, float* __restrict__ alpha,
    float* __restrict__ amax, int n) {
    int t = blockIdx.x * blockDim.x + threadIdx.x;
    if (t >= n) return;
    int eid = t >> 4, h = t & 15;
    int sn = src[eid], dn = dst[eid];
    const float4* qp = (const float4*)(q + (size_t)dn * HC + h * CD);
    const float4* kp = (const float4*)(k + (size_t)sn * HC + h * CD);
    const float4* ep = (const float4*)(e + (size_t)eid * HC + h * CD);
    float acc = 0.f;
#pragma unroll
    for (int i = 0; i < 8; ++i) {
        float4 qv = qp[i], kv = kp[i], ev = ep[i];
        acc += qv.x * (kv.x + ev.x) + qv.y * (kv.y + ev.y)
             + qv.z * (kv.z + ev.z) + qv.w * (kv.w + ev.w);
    }
    acc *= 0.17677669529663687f;  // 1/sqrt(32)
    alpha[t] = acc;
    atomicMaxF(&amax[dn * NH + h], acc);
}

__global__ __launch_bounds__(256) void k_exp(
    float* __restrict__ alpha, const float* __restrict__ amax,
    const int* __restrict__ dst, float* __restrict__ denom, int n) {
    int t = blockIdx.x * blockDim.x + threadIdx.x;
    if (t >= n) return;
    int eid = t >> 4, h = t & 15;
    int dn = dst[eid];
    float ex = __expf(alpha[t] - amax[dn * NH + h]);
    alpha[t] = ex;
    atomicAdd(&denom[dn * NH + h], ex);
}

// one block (128 threads) per edge; each thread 4 channels
__global__ __launch_bounds__(128) void k_msg(
    const float* __restrict__ v, const float* __restrict__ e,
    const float* __restrict__ ex, const float* __restrict__ denom,
    const int* __restrict__ src, const int* __restrict__ dst,
    float* __restrict__ agg) {
    int eid = blockIdx.x;
    int t = threadIdx.x;
    int c = t * 4;
    int h = t >> 3;
    int sn = src[eid], dn = dst[eid];
    float a = ex[eid * NH + h] / denom[dn * NH + h];
    float4 vv = *(const float4*)(v + (size_t)sn * HC + c);
    float4 ev = *(const float4*)(e + (size_t)eid * HC + c);
    float* ap = agg + (size_t)dn * HC + c;
    atomicAdd(ap + 0, (vv.x + ev.x) * a);
    atomicAdd(ap + 1, (vv.y + ev.y) * a);
    atomicAdd(ap + 2, (vv.z + ev.z) * a);
    atomicAdd(ap + 3, (vv.w + ev.w) * a);
}

// x_out = leaky_relu(agg, 0.2)   (skip fused into agg by the skip GEMM)
__global__ void k_epi(const float* __restrict__ agg, float* __restrict__ xout, int n) {
    int i = blockIdx.x * blockDim.x + threadIdx.x;
    int stride = gridDim.x * blockDim.x;
    for (; i < n; i += stride) {
        float v = agg[i];
        xout[i] = v >= 0.f ? v : 0.2f * v;
    }
}

// ---------------------------------------------------------------- pooling
// batch sorted: block (graph b, slice s) reduces a contiguous node range.

__global__ __launch_bounds__(256) void k_pool2(
    const float* __restrict__ x, const int* __restrict__ batch,
    float* __restrict__ psum, float* __restrict__ pmax, int* __restrict__ cnt) {
    int b = blockIdx.x;
    int s = blockIdx.y;
    int lo = 0, hi = N_NODES;
    while (lo < hi) { int mid = (lo + hi) >> 1; if (batch[mid] < b) lo = mid + 1; else hi = mid; }
    int beg = lo;
    hi = N_NODES;
    while (lo < hi) { int mid = (lo + hi) >> 1; if (batch[mid] < b + 1) lo = mid + 1; else hi = mid; }
    int end = lo;
    if (s == 0 && threadIdx.x == 0) cnt[b] = end - beg;
    int cn = end - beg;
    int per = (cn + 7) >> 3;
    int nb = beg + s * per;
    int ne = nb + per; if (ne > end) ne = end;
    if (nb >= ne) return;
    int c0 = threadIdx.x * 2;
    float s0 = 0.f, s1 = 0.f, m0 = -1e30f, m1 = -1e30f;
    for (int n = nb; n < ne; ++n) {
        float2 v = *(const float2*)(x + (size_t)n * HC + c0);
        s0 += v.x; s1 += v.y;
        m0 = fmaxf(m0, v.x); m1 = fmaxf(m1, v.y);
    }
    atomicAdd(&psum[b * HC + c0], s0);
    atomicAdd(&psum[b * HC + c0 + 1], s1);
    atomicMaxF(&pmax[b * HC + c0], m0);
    atomicMaxF(&pmax[b * HC + c0 + 1], m1);
}

// hsum[B,1024] = [mean | max] ; mode 0: write, 1: add
__global__ void k_poolfin(const float* __restrict__ psum, const float* __restrict__ pmax,
                          const int* __restrict__ cnt, float* __restrict__ hsum, int mode) {
    int i = blockIdx.x * blockDim.x + threadIdx.x;
    if (i >= NB * 1024) return;
    int b = i >> 10, c = i & 1023;
    float val;
    if (c < HC) {
        int ct = cnt[b];
        val = psum[b * HC + c] / (float)(ct > 0 ? ct : 1);
    } else {
        val = pmax[b * HC + (c - HC)];
    }
    if (mode == 0) hsum[i] = val;
    else hsum[i] += val;
}

// ---------------------------------------------------------------- MLP head

__global__ __launch_bounds__(256) void k_head(
    const float* __restrict__ hsum, const float* __restrict__ fc1W,
    const float* __restrict__ fc1b, const float* __restrict__ fc2W,
    const float* __restrict__ fc2b, float* __restrict__ out) {
    int b = blockIdx.x;
    int j = threadIdx.x;
    __shared__ float hs[256];
    float acc = fc1b[j];
    const float* hin = hsum + (size_t)b * 1024;
    for (int k = 0; k < 1024; ++k) {
        acc += hin[k] * fc1W[(size_t)k * 256 + j];
    }
    hs[j] = fmaxf(acc, 0.f);
    __syncthreads();
    if (j < 32) {
        float o = fc2b[j];
        for (int k = 0; k < 256; ++k) o += hs[k] * fc2W[(size_t)k * 32 + j];
        out[b * 32 + j] = o;
    }
}

// ---------------------------------------------------------------- driver

static inline void mgemm(const float* A, const ushort_t* Bt, const float* bias,
                         float* Y, int M, int K, int Kp, int N, hipStream_t stream) {
    dim3 grid((M + 127) / 128, (N + 127) / 128);
    hipLaunchKernelGGL(k_mfma_gemm, grid, dim3(256), 0, stream, A, Bt, bias, Y, M, K, Kp, N);
}

extern "C" void kernel_launch(void* const* d_in, const int* in_sizes, int n_in,
                              void* d_out, int out_size, void* d_ws, size_t ws_size,
                              hipStream_t stream) {
    const float* x      = (const float*)d_in[0];
    const float* ea     = (const float*)d_in[1];
    const int*   ei     = (const int*)d_in[2];
    const int*   batch  = (const int*)d_in[3];
    const int* src = ei;
    const int* dst = ei + N_EDGES;

    const float* t1_Wq = (const float*)d_in[4];
    const float* t1_bq = (const float*)d_in[5];
    const float* t1_Wk = (const float*)d_in[6];
    const float* t1_bk = (const float*)d_in[7];
    const float* t1_Wv = (const float*)d_in[8];
    const float* t1_bv = (const float*)d_in[9];
    const float* t1_We = (const float*)d_in[10];
    const float* t1_Ws = (const float*)d_in[11];
    const float* t1_bs = (const float*)d_in[12];
    const float* t2_Wq = (const float*)d_in[13];
    const float* t2_bq = (const float*)d_in[14];
    const float* t2_Wk = (const float*)d_in[15];
    const float* t2_bk = (const float*)d_in[16];
    const float* t2_Wv = (const float*)d_in[17];
    const float* t2_bv = (const float*)d_in[18];
    const float* t2_We = (const float*)d_in[19];
    const float* t2_Ws = (const float*)d_in[20];
    const float* t2_bs = (const float*)d_in[21];
    const float* fc1_W = (const float*)d_in[22];
    const float* fc1_b = (const float*)d_in[23];
    const float* fc2_W = (const float*)d_in[24];
    const float* fc2_b = (const float*)d_in[25];

    char* ws = (char*)d_ws;
    size_t off = 0;
    auto alloc = [&](size_t bytes) -> void* {
        void* p = ws + off;
        off = (off + bytes + 255) & ~(size_t)255;
        return p;
    };

    // f32 buffers (R3-proven footprint)
    float* qb   = (float*)alloc((size_t)N_NODES * HC * 4);
    float* kb   = (float*)alloc((size_t)N_NODES * HC * 4);
    float* vb   = (float*)alloc((size_t)N_NODES * HC * 4);
    float* agg  = (float*)alloc((size_t)N_NODES * HC * 4);   // skip + messages
    float* x1   = (float*)alloc((size_t)N_NODES * HC * 4);
    float* alp  = (float*)alloc((size_t)N_EDGES * NH * 4);
    float* amax = (float*)alloc((size_t)N_NODES * NH * 4);
    float* den  = (float*)alloc((size_t)N_NODES * NH * 4);
    float* psum = (float*)alloc((size_t)NB * HC * 4);
    float* pmaxb= (float*)alloc((size_t)NB * HC * 4);
    float* hsum = (float*)alloc((size_t)NB * 1024 * 4);
    int*   cnt  = (int*)alloc((size_t)NB * 4);
    // bf16 weights only (~2.8 MB)
    ushort_t* w1q = (ushort_t*)alloc((size_t)HC * IN_CH * 2);
    ushort_t* w1k = (ushort_t*)alloc((size_t)HC * IN_CH * 2);
    ushort_t* w1v = (ushort_t*)alloc((size_t)HC * IN_CH * 2);
    ushort_t* w1s = (ushort_t*)alloc((size_t)HC * IN_CH * 2);
    ushort_t* w1e = (ushort_t*)alloc((size_t)HC * EDP * 2);
    ushort_t* w2q = (ushort_t*)alloc((size_t)HC * HC * 2);
    ushort_t* w2k = (ushort_t*)alloc((size_t)HC * HC * 2);
    ushort_t* w2v = (ushort_t*)alloc((size_t)HC * HC * 2);
    ushort_t* w2s = (ushort_t*)alloc((size_t)HC * HC * 2);
    ushort_t* w2e = (ushort_t*)alloc((size_t)HC * EDP * 2);

    // remaining workspace -> edge-feature chunk buffer eb [EC, HC] f32
    size_t remain = (ws_size > off) ? (ws_size - off) : 0;
    float* eb = (float*)(ws + off);
    size_t per_edge = (size_t)HC * 4;  // 2 KiB
    int EC;
    bool full = (remain >= (size_t)N_EDGES * per_edge);
    if (full) {
        EC = N_EDGES;
    } else {
        EC = (int)(remain / per_edge);
        EC &= ~127;                   // multiple of 128
        if (EC <= 0) EC = 128;        // last resort
        if (EC > N_EDGES) EC = N_EDGES;
    }
    (void)in_sizes; (void)n_in; (void)out_size;

    const int EH = N_EDGES * NH;
    const int NHC = N_NODES * HC;

    // ---- one-time weight conversions
    hipLaunchKernelGGL(k_cvt_wt, dim3(256), dim3(256), 0, stream, t1_Wq, w1q, IN_CH, HC, IN_CH);
    hipLaunchKernelGGL(k_cvt_wt, dim3(256), dim3(256), 0, stream, t1_Wk, w1k, IN_CH, HC, IN_CH);
    hipLaunchKernelGGL(k_cvt_wt, dim3(256), dim3(256), 0, stream, t1_Wv, w1v, IN_CH, HC, IN_CH);
    hipLaunchKernelGGL(k_cvt_wt, dim3(256), dim3(256), 0, stream, t1_Ws, w1s, IN_CH, HC, IN_CH);
    hipLaunchKernelGGL(k_cvt_wt, dim3(192), dim3(256), 0, stream, t1_We, w1e, ED, HC, EDP);
    hipLaunchKernelGGL(k_cvt_wt, dim3(1024), dim3(256), 0, stream, t2_Wq, w2q, HC, HC, HC);
    hipLaunchKernelGGL(k_cvt_wt, dim3(1024), dim3(256), 0, stream, t2_Wk, w2k, HC, HC, HC);
    hipLaunchKernelGGL(k_cvt_wt, dim3(1024), dim3(256), 0, stream, t2_Wv, w2v, HC, HC, HC);
    hipLaunchKernelGGL(k_cvt_wt, dim3(1024), dim3(256), 0, stream, t2_Ws, w2s, HC, HC, HC);
    hipLaunchKernelGGL(k_cvt_wt, dim3(192), dim3(256), 0, stream, t2_We, w2e, ED, HC, EDP);

    auto run_layer = [&](const float* xin, int Kin,
                         const ushort_t* Wq, const float* bq, const ushort_t* Wk, const float* bk,
                         const ushort_t* Wv, const float* bv, const ushort_t* We,
                         const ushort_t* Wsk, const float* bsk,
                         float* xout, int poolmode) {
        mgemm(xin, Wq, bq, qb, N_NODES, Kin, Kin, HC, stream);
        mgemm(xin, Wk, bk, kb, N_NODES, Kin, Kin, HC, stream);
        mgemm(xin, Wv, bv, vb, N_NODES, Kin, Kin, HC, stream);
        mgemm(xin, Wsk, bsk, agg, N_NODES, Kin, Kin, HC, stream);  // skip into agg

        hipLaunchKernelGGL(k_fill, dim3(512), dim3(256), 0, stream, amax, -1e30f, N_NODES * NH);
        hipLaunchKernelGGL(k_fill, dim3(512), dim3(256), 0, stream, den, 0.f, N_NODES * NH);

        // pass A: e-chunk GEMM + alpha/max
        for (int e0 = 0; e0 < N_EDGES; e0 += EC) {
            int ec = (N_EDGES - e0 < EC) ? (N_EDGES - e0) : EC;
            mgemm(ea + (size_t)e0 * ED, We, nullptr, eb, ec, ED, EDP, HC, stream);
            int n = ec * NH;
            hipLaunchKernelGGL(k_alpha, dim3((n + 255) / 256), dim3(256), 0, stream,
                               qb, kb, eb, src + e0, dst + e0, alp + (size_t)e0 * NH, amax, n);
        }
        // pass B: exp + denom
        hipLaunchKernelGGL(k_exp, dim3((EH + 255) / 256), dim3(256), 0, stream,
                           alp, amax, dst, den, EH);
        // pass C: messages (re-GEMM chunk only if e didn't fit whole)
        for (int e0 = 0; e0 < N_EDGES; e0 += EC) {
            int ec = (N_EDGES - e0 < EC) ? (N_EDGES - e0) : EC;
            if (!full) mgemm(ea + (size_t)e0 * ED, We, nullptr, eb, ec, ED, EDP, HC, stream);
            hipLaunchKernelGGL(k_msg, dim3(ec), dim3(128), 0, stream,
                               vb, eb, alp + (size_t)e0 * NH, den, src + e0, dst + e0, agg);
        }
        hipLaunchKernelGGL(k_epi, dim3(2048), dim3(256), 0, stream, agg, xout, NHC);

        // pooling
        hipLaunchKernelGGL(k_fill, dim3(128), dim3(256), 0, stream, psum, 0.f, NB * HC);
        hipLaunchKernelGGL(k_fill, dim3(128), dim3(256), 0, stream, pmaxb, -1e30f, NB * HC);
        hipLaunchKernelGGL(k_pool2, dim3(NB, 8), dim3(256), 0, stream, xout, batch, psum, pmaxb, cnt);
        hipLaunchKernelGGL(k_poolfin, dim3((NB * 1024 + 255) / 256), dim3(256), 0, stream,
                           psum, pmaxb, cnt, hsum, poolmode);
    };

    // layer 1: x (N,128) -> x1
    run_layer(x, IN_CH, w1q, t1_bq, w1k, t1_bk, w1v, t1_bv, w1e, w1s, t1_bs,
              x1, /*poolmode=*/0);
    // layer 2: x1 (N,512) -> x1 (x1 overwritten only at k_epi, after all consumers)
    run_layer(x1, HC, w2q, t2_bq, w2k, t2_bk, w2v, t2_bv, w2e, w2s, t2_bs,
              x1, /*poolmode=*/1);

    hipLaunchKernelGGL(k_head, dim3(NB), dim3(256), 0, stream,
                       hsum, fc1_W, fc1_b, fc2_W, fc2_b, (float*)d_out);
}

// Round 7
// 1417.788 us; speedup vs baseline: 5.0574x; 3.0791x over previous
//
#include <hip/hip_runtime.h>
#include <cstdint>
#include <cstddef>

#define N_NODES 20000
#define N_EDGES 160000
#define IN_CH   128
#define NH      16
#define CD      32
#define HC      512   // NH*CD
#define ED      93
#define EDP     96    // ED padded to multiple of 32
#define NB      64
#define QKVW    1536  // q|k|v bf16 row width
#define NCAT    2048  // q|k|v|skip GEMM output cols

typedef __attribute__((ext_vector_type(8))) short short8;
typedef __attribute__((ext_vector_type(4))) float f32x4;
typedef unsigned short ushort_t;

// ---------------------------------------------------------------- utilities

__device__ inline void atomicMaxF(float* addr, float val) {
    unsigned int* ua = (unsigned int*)addr;
    unsigned int old = *ua;
    while (__uint_as_float(old) < val) {
        unsigned int assumed = old;
        old = atomicCAS(ua, assumed, __float_as_uint(val));
        if (old == assumed) break;
    }
}

__device__ inline ushort_t f2bf(float f) {
    unsigned int u = __float_as_uint(f);
    u = (u + 0x7FFF + ((u >> 16) & 1)) >> 16;   // RNE
    return (ushort_t)u;
}
__device__ inline float bf2f(ushort_t u) {
    return __uint_as_float((unsigned)u << 16);
}

__device__ inline uint4 pack8(const ushort_t* t) {
    uint4 u;
    u.x = (unsigned)t[0] | ((unsigned)t[1] << 16);
    u.y = (unsigned)t[2] | ((unsigned)t[3] << 16);
    u.z = (unsigned)t[4] | ((unsigned)t[5] << 16);
    u.w = (unsigned)t[6] | ((unsigned)t[7] << 16);
    return u;
}

__global__ void k_fill(float* __restrict__ p, float v, int n) {
    int i = blockIdx.x * blockDim.x + threadIdx.x;
    int stride = gridDim.x * blockDim.x;
    for (; i < n; i += stride) p[i] = v;
}
__global__ void k_zero_i(int* __restrict__ p, int n) {
    int i = blockIdx.x * blockDim.x + threadIdx.x;
    int stride = gridDim.x * blockDim.x;
    for (; i < n; i += stride) p[i] = 0;
}
__global__ void k_copy_i(const int* __restrict__ a, int* __restrict__ b, int n) {
    int i = blockIdx.x * blockDim.x + threadIdx.x;
    int stride = gridDim.x * blockDim.x;
    for (; i < n; i += stride) b[i] = a[i];
}

// W [K,N] f32 -> Wt [N,Kp] bf16 (transpose + pad)
__global__ void k_cvt_wt(const float* __restrict__ W, ushort_t* __restrict__ Wt,
                         int K, int N, int Kp) {
    int i = blockIdx.x * blockDim.x + threadIdx.x;
    int stride = gridDim.x * blockDim.x;
    int total = N * Kp;
    for (; i < total; i += stride) {
        int n = i / Kp, k = i - n * Kp;
        Wt[i] = (k < K) ? f2bf(W[(size_t)k * N + n]) : (ushort_t)0;
    }
}

// bcat[2048] = bq|bk|bv|bs
__global__ void k_bcat(const float* __restrict__ bq, const float* __restrict__ bk,
                       const float* __restrict__ bv, const float* __restrict__ bs,
                       float* __restrict__ out) {
    int i = blockIdx.x * blockDim.x + threadIdx.x;
    if (i >= NCAT) return;
    int s = i >> 9, j = i & 511;
    float v = (s == 0) ? bq[j] : (s == 1) ? bk[j] : (s == 2) ? bv[j] : bs[j];
    out[i] = v;
}

// ---------------------------------------------------------------- CSR build

__global__ void k_hist(const int* __restrict__ dst, int* __restrict__ deg) {
    int i = blockIdx.x * blockDim.x + threadIdx.x;
    if (i < N_EDGES) atomicAdd(&deg[dst[i]], 1);
}

// single block, 1024 threads: exclusive prefix over 20000 -> rowptr[20001]
__global__ __launch_bounds__(1024) void k_scan(const int* __restrict__ deg,
                                               int* __restrict__ rowptr) {
    __shared__ int part[1024];
    int t = threadIdx.x;
    int base = t * 20;
    int loc[20];
    int s = 0;
#pragma unroll
    for (int i = 0; i < 20; ++i) {
        int idx = base + i;
        int v = (idx < N_NODES) ? deg[idx] : 0;
        loc[i] = s; s += v;
    }
    part[t] = s;
    __syncthreads();
    for (int off = 1; off < 1024; off <<= 1) {
        int v = (t >= off) ? part[t - off] : 0;
        __syncthreads();
        part[t] += v;
        __syncthreads();
    }
    int pre = (t > 0) ? part[t - 1] : 0;
#pragma unroll
    for (int i = 0; i < 20; ++i) {
        int idx = base + i;
        if (idx < N_NODES) rowptr[idx] = pre + loc[i];
    }
    if (t == 1023) rowptr[N_NODES] = part[1023];
}

__global__ void k_scatter(const int* __restrict__ src, const int* __restrict__ dst,
                          int* __restrict__ cursor, int* __restrict__ perm,
                          int* __restrict__ psrc) {
    int i = blockIdx.x * blockDim.x + threadIdx.x;
    if (i >= N_EDGES) return;
    int d = dst[i];
    int p = atomicAdd(&cursor[d], 1);
    perm[p] = i;
    psrc[p] = src[i];
}

// ---------------------------------------------------------------- MFMA GEMM
// Y = A[M,K](f32 -> bf16 in staging; optional row-gather perm) @ Bt[N,Kp]^T + bias
// cols < nsplit -> bf16 into Yb (ld=nsplit); cols >= nsplit -> f32 into Yf.
// 128x128 tile, 4 waves, BK=32, 16x16x32 MFMA.

__global__ __launch_bounds__(256) void k_mfma_gemm(
    const float* __restrict__ A, const ushort_t* __restrict__ Bt,
    const float* __restrict__ bias,
    ushort_t* __restrict__ Yb, float* __restrict__ Yf, int nsplit,
    const int* __restrict__ perm, int pbase,
    int M, int K, int Kp, int N) {
    __shared__ ushort_t lds[2 * 128 * 32];   // 16 KB
    char* As = (char*)lds;
    char* Bs = (char*)(lds + 128 * 32);

    int tid  = threadIdx.x;
    int lane = tid & 63, wave = tid >> 6;
    int l15 = lane & 15, lg = lane >> 4;
    int bm = blockIdx.x * 128, bn = blockIdx.y * 128;
    int wm = (wave >> 1) * 64, wn = (wave & 1) * 64;

    f32x4 acc[4][4] = {};

    int srow = tid >> 1;
    int skb  = (tid & 1) * 32;
    int ssw  = (srow & 3) << 4;
    int sb0  = skb ^ ssw;
    int sb1  = (skb + 16) ^ ssw;
    int grow = bm + srow;
    int brow = bn + srow;
    int arow = -1;
    if (grow < M) arow = perm ? perm[pbase + grow] : grow;

    int fsw = (l15 & 3) << 4;
    int fkb = (lg * 16) ^ fsw;

    bool kvec = ((K & 31) == 0);

    for (int k0 = 0; k0 < Kp; k0 += 32) {
        int kbase = k0 + (tid & 1) * 16;
        // stage A (f32 -> bf16)
        {
            ushort_t ta[16];
            if (arow >= 0) {
                if (kvec) {
                    const float4* ga = (const float4*)(A + (size_t)arow * K + kbase);
#pragma unroll
                    for (int i = 0; i < 4; ++i) {
                        float4 f = ga[i];
                        ta[4 * i + 0] = f2bf(f.x); ta[4 * i + 1] = f2bf(f.y);
                        ta[4 * i + 2] = f2bf(f.z); ta[4 * i + 3] = f2bf(f.w);
                    }
                } else {
                    const float* ga = A + (size_t)arow * K;
#pragma unroll
                    for (int i = 0; i < 16; ++i) {
                        int gk = kbase + i;
                        ta[i] = (gk < K) ? f2bf(ga[gk]) : (ushort_t)0;
                    }
                }
            } else {
#pragma unroll
                for (int i = 0; i < 16; ++i) ta[i] = 0;
            }
            *(uint4*)(As + srow * 64 + sb0) = pack8(ta);
            *(uint4*)(As + srow * 64 + sb1) = pack8(ta + 8);
        }
        // stage B (bf16, Kp-padded)
        {
            uint4 v0 = {0, 0, 0, 0}, v1 = {0, 0, 0, 0};
            if (brow < N) {
                const ushort_t* gb = Bt + (size_t)brow * Kp + kbase;
                v0 = *(const uint4*)(gb);
                v1 = *(const uint4*)(gb + 8);
            }
            *(uint4*)(Bs + srow * 64 + sb0) = v0;
            *(uint4*)(Bs + srow * 64 + sb1) = v1;
        }
        __syncthreads();

        short8 af[4], bfr[4];
#pragma unroll
        for (int mr = 0; mr < 4; ++mr)
            af[mr] = *(const short8*)(As + (wm + mr * 16 + l15) * 64 + fkb);
#pragma unroll
        for (int nc = 0; nc < 4; ++nc)
            bfr[nc] = *(const short8*)(Bs + (wn + nc * 16 + l15) * 64 + fkb);
#pragma unroll
        for (int mr = 0; mr < 4; ++mr)
#pragma unroll
            for (int nc = 0; nc < 4; ++nc)
                acc[mr][nc] = __builtin_amdgcn_mfma_f32_16x16x32_bf16(
                    af[mr], bfr[nc], acc[mr][nc], 0, 0, 0);
        __syncthreads();
    }

    int fld = N - nsplit;
#pragma unroll
    for (int mr = 0; mr < 4; ++mr) {
#pragma unroll
        for (int nc = 0; nc < 4; ++nc) {
            int col = bn + wn + nc * 16 + l15;
            if (col >= N) continue;
            float b = bias ? bias[col] : 0.f;
#pragma unroll
            for (int j = 0; j < 4; ++j) {
                int row = bm + wm + mr * 16 + lg * 4 + j;
                if (row >= M) continue;
                float v = acc[mr][nc][j] + b;
                if (col < nsplit) Yb[(size_t)row * nsplit + col] = f2bf(v);
                else              Yf[(size_t)row * fld + (col - nsplit)] = v;
            }
        }
    }
}

// ---------------------------------------------------------------- fused edge phase
// One block (128 threads) per dst node; edges sorted by dst. Online softmax,
// state (m,d,macc) carried in global across edge chunks. No atomics.

__global__ __launch_bounds__(128) void k_edge(
    const ushort_t* __restrict__ qkv, const ushort_t* __restrict__ eb,
    const int* __restrict__ psrc, const int* __restrict__ rowptr,
    float* __restrict__ macc, float* __restrict__ mbuf, float* __restrict__ dbuf,
    int e0, int e1) {
    int n = blockIdx.x;
    int beg = rowptr[n], end = rowptr[n + 1];
    int lo = beg > e0 ? beg : e0;
    int hi = end < e1 ? end : e1;
    if (lo >= hi) return;
    int t = threadIdx.x;
    int c0 = t * 4;
    int h = t >> 3;

    ushort4 qu = *(const ushort4*)(qkv + (size_t)n * QKVW + c0);
    float q0 = bf2f(qu.x), q1 = bf2f(qu.y), q2 = bf2f(qu.z), q3 = bf2f(qu.w);

    float mm = mbuf[n * NH + h];
    float dd = dbuf[n * NH + h];
    float4 av = *(const float4*)(macc + (size_t)n * HC + c0);
    float a0 = av.x, a1 = av.y, a2 = av.z, a3 = av.w;

    for (int i = lo; i < hi; ++i) {
        int sn = psrc[i];
        ushort4 ku = *(const ushort4*)(qkv + (size_t)sn * QKVW + 512 + c0);
        ushort4 vu = *(const ushort4*)(qkv + (size_t)sn * QKVW + 1024 + c0);
        ushort4 eu = *(const ushort4*)(eb + (size_t)(i - e0) * HC + c0);
        float e0f = bf2f(eu.x), e1f = bf2f(eu.y), e2f = bf2f(eu.z), e3f = bf2f(eu.w);
        float k0 = bf2f(ku.x) + e0f, k1 = bf2f(ku.y) + e1f;
        float k2 = bf2f(ku.z) + e2f, k3 = bf2f(ku.w) + e3f;
        float part = q0 * k0 + q1 * k1 + q2 * k2 + q3 * k3;
        part += __shfl_xor(part, 1);
        part += __shfl_xor(part, 2);
        part += __shfl_xor(part, 4);
        float s = part * 0.17677669529663687f;   // /sqrt(32)
        float mn = fmaxf(mm, s);
        float sc = __expf(mm - mn);
        float p  = __expf(s - mn);
        dd = dd * sc + p;
        mm = mn;
        float v0 = bf2f(vu.x) + e0f, v1 = bf2f(vu.y) + e1f;
        float v2 = bf2f(vu.z) + e2f, v3 = bf2f(vu.w) + e3f;
        a0 = a0 * sc + p * v0;
        a1 = a1 * sc + p * v1;
        a2 = a2 * sc + p * v2;
        a3 = a3 * sc + p * v3;
    }

    float4 out; out.x = a0; out.y = a1; out.z = a2; out.w = a3;
    *(float4*)(macc + (size_t)n * HC + c0) = out;
    if ((t & 7) == 0) { mbuf[n * NH + h] = mm; dbuf[n * NH + h] = dd; }
}

// x_out = leaky_relu(macc/d + skip, 0.2)
__global__ void k_epi2(const float* __restrict__ macc, const float* __restrict__ dbuf,
                       const float* __restrict__ sb, float* __restrict__ xout, int n) {
    int i = blockIdx.x * blockDim.x + threadIdx.x;
    int stride = gridDim.x * blockDim.x;
    for (; i < n; i += stride) {
        int node = i >> 9, c = i & (HC - 1);
        int h = c >> 5;
        float dd = dbuf[node * NH + h];
        float msg = (dd > 0.f) ? macc[i] / dd : 0.f;
        float v = msg + sb[i];
        xout[i] = v >= 0.f ? v : 0.2f * v;
    }
}

// ---------------------------------------------------------------- pooling

__global__ __launch_bounds__(256) void k_pool2(
    const float* __restrict__ x, const int* __restrict__ batch,
    float* __restrict__ psum, float* __restrict__ pmax, int* __restrict__ cnt) {
    int b = blockIdx.x;
    int s = blockIdx.y;
    int lo = 0, hi = N_NODES;
    while (lo < hi) { int mid = (lo + hi) >> 1; if (batch[mid] < b) lo = mid + 1; else hi = mid; }
    int beg = lo;
    hi = N_NODES;
    while (lo < hi) { int mid = (lo + hi) >> 1; if (batch[mid] < b + 1) lo = mid + 1; else hi = mid; }
    int end = lo;
    if (s == 0 && threadIdx.x == 0) cnt[b] = end - beg;
    int cn = end - beg;
    int per = (cn + 7) >> 3;
    int nb = beg + s * per;
    int ne = nb + per; if (ne > end) ne = end;
    if (nb >= ne) return;
    int c0 = threadIdx.x * 2;
    float s0 = 0.f, s1 = 0.f, m0 = -1e30f, m1 = -1e30f;
    for (int n = nb; n < ne; ++n) {
        float2 v = *(const float2*)(x + (size_t)n * HC + c0);
        s0 += v.x; s1 += v.y;
        m0 = fmaxf(m0, v.x); m1 = fmaxf(m1, v.y);
    }
    atomicAdd(&psum[b * HC + c0], s0);
    atomicAdd(&psum[b * HC + c0 + 1], s1);
    atomicMaxF(&pmax[b * HC + c0], m0);
    atomicMaxF(&pmax[b * HC + c0 + 1], m1);
}

__global__ void k_poolfin(const float* __restrict__ psum, const float* __restrict__ pmax,
                          const int* __restrict__ cnt, float* __restrict__ hsum, int mode) {
    int i = blockIdx.x * blockDim.x + threadIdx.x;
    if (i >= NB * 1024) return;
    int b = i >> 10, c = i & 1023;
    float val;
    if (c < HC) {
        int ct = cnt[b];
        val = psum[b * HC + c] / (float)(ct > 0 ? ct : 1);
    } else {
        val = pmax[b * HC + (c - HC)];
    }
    if (mode == 0) hsum[i] = val;
    else hsum[i] += val;
}

// ---------------------------------------------------------------- MLP head

__global__ __launch_bounds__(256) void k_head(
    const float* __restrict__ hsum, const float* __restrict__ fc1W,
    const float* __restrict__ fc1b, const float* __restrict__ fc2W,
    const float* __restrict__ fc2b, float* __restrict__ out) {
    int b = blockIdx.x;
    int j = threadIdx.x;
    __shared__ float hs[256];
    float acc = fc1b[j];
    const float* hin = hsum + (size_t)b * 1024;
    for (int k = 0; k < 1024; ++k) {
        acc += hin[k] * fc1W[(size_t)k * 256 + j];
    }
    hs[j] = fmaxf(acc, 0.f);
    __syncthreads();
    if (j < 32) {
        float o = fc2b[j];
        for (int k = 0; k < 256; ++k) o += hs[k] * fc2W[(size_t)k * 32 + j];
        out[b * 32 + j] = o;
    }
}

// ---------------------------------------------------------------- driver

extern "C" void kernel_launch(void* const* d_in, const int* in_sizes, int n_in,
                              void* d_out, int out_size, void* d_ws, size_t ws_size,
                              hipStream_t stream) {
    const float* x      = (const float*)d_in[0];
    const float* ea     = (const float*)d_in[1];
    const int*   ei     = (const int*)d_in[2];
    const int*   batch  = (const int*)d_in[3];
    const int* src = ei;
    const int* dst = ei + N_EDGES;

    const float* t1_Wq = (const float*)d_in[4];
    const float* t1_bq = (const float*)d_in[5];
    const float* t1_Wk = (const float*)d_in[6];
    const float* t1_bk = (const float*)d_in[7];
    const float* t1_Wv = (const float*)d_in[8];
    const float* t1_bv = (const float*)d_in[9];
    const float* t1_We = (const float*)d_in[10];
    const float* t1_Ws = (const float*)d_in[11];
    const float* t1_bs = (const float*)d_in[12];
    const float* t2_Wq = (const float*)d_in[13];
    const float* t2_bq = (const float*)d_in[14];
    const float* t2_Wk = (const float*)d_in[15];
    const float* t2_bk = (const float*)d_in[16];
    const float* t2_Wv = (const float*)d_in[17];
    const float* t2_bv = (const float*)d_in[18];
    const float* t2_We = (const float*)d_in[19];
    const float* t2_Ws = (const float*)d_in[20];
    const float* t2_bs = (const float*)d_in[21];
    const float* fc1_W = (const float*)d_in[22];
    const float* fc1_b = (const float*)d_in[23];
    const float* fc2_W = (const float*)d_in[24];
    const float* fc2_b = (const float*)d_in[25];

    char* ws = (char*)d_ws;
    size_t off = 0;
    auto alloc = [&](size_t bytes) -> void* {
        void* p = ws + off;
        off = (off + bytes + 255) & ~(size_t)255;
        return p;
    };

    ushort_t* qkv  = (ushort_t*)alloc((size_t)N_NODES * QKVW * 2);  // q|k|v bf16
    float* sb   = (float*)alloc((size_t)N_NODES * HC * 4);          // skip f32
    float* x1   = (float*)alloc((size_t)N_NODES * HC * 4);
    float* macc = (float*)alloc((size_t)N_NODES * HC * 4);
    float* mbuf = (float*)alloc((size_t)N_NODES * NH * 4);
    float* dbuf = (float*)alloc((size_t)N_NODES * NH * 4);
    float* psum = (float*)alloc((size_t)NB * HC * 4);
    float* pmaxb= (float*)alloc((size_t)NB * HC * 4);
    float* hsum = (float*)alloc((size_t)NB * 1024 * 4);
    int*   cnt  = (int*)alloc((size_t)NB * 4);
    // CSR
    int* deg    = (int*)alloc((size_t)N_NODES * 4);
    int* rowptr = (int*)alloc((size_t)(N_NODES + 1) * 4);
    int* cursor = (int*)alloc((size_t)N_NODES * 4);
    int* perm   = (int*)alloc((size_t)N_EDGES * 4);
    int* psrc   = (int*)alloc((size_t)N_EDGES * 4);
    // weights bf16
    ushort_t* wcat1 = (ushort_t*)alloc((size_t)NCAT * IN_CH * 2);
    ushort_t* wcat2 = (ushort_t*)alloc((size_t)NCAT * HC * 2);
    ushort_t* w1e   = (ushort_t*)alloc((size_t)HC * EDP * 2);
    ushort_t* w2e   = (ushort_t*)alloc((size_t)HC * EDP * 2);
    float* bcat1 = (float*)alloc((size_t)NCAT * 4);
    float* bcat2 = (float*)alloc((size_t)NCAT * 4);

    // remaining -> bf16 edge-feature chunk buffer eb [EC, HC]
    size_t remain = (ws_size > off) ? (ws_size - off) : 0;
    ushort_t* eb = (ushort_t*)(ws + off);
    size_t per_edge = (size_t)HC * 2;  // 1 KiB
    int EC;
    if (remain >= (size_t)N_EDGES * per_edge) {
        EC = N_EDGES;
    } else {
        EC = (int)(remain / per_edge);
        EC &= ~127;
        if (EC <= 0) EC = 128;
        if (EC > N_EDGES) EC = N_EDGES;
    }
    (void)in_sizes; (void)n_in; (void)out_size;

    const int NHC = N_NODES * HC;

    // ---- CSR build (shared by both layers)
    hipLaunchKernelGGL(k_zero_i, dim3(79), dim3(256), 0, stream, deg, N_NODES);
    hipLaunchKernelGGL(k_hist, dim3((N_EDGES + 255) / 256), dim3(256), 0, stream, dst, deg);
    hipLaunchKernelGGL(k_scan, dim3(1), dim3(1024), 0, stream, deg, rowptr);
    hipLaunchKernelGGL(k_copy_i, dim3(79), dim3(256), 0, stream, rowptr, cursor, N_NODES);
    hipLaunchKernelGGL(k_scatter, dim3((N_EDGES + 255) / 256), dim3(256), 0, stream,
                       src, dst, cursor, perm, psrc);

    // ---- weight conversions
    hipLaunchKernelGGL(k_cvt_wt, dim3(256), dim3(256), 0, stream, t1_Wq, wcat1 + (size_t)0 * HC * IN_CH, IN_CH, HC, IN_CH);
    hipLaunchKernelGGL(k_cvt_wt, dim3(256), dim3(256), 0, stream, t1_Wk, wcat1 + (size_t)1 * HC * IN_CH, IN_CH, HC, IN_CH);
    hipLaunchKernelGGL(k_cvt_wt, dim3(256), dim3(256), 0, stream, t1_Wv, wcat1 + (size_t)2 * HC * IN_CH, IN_CH, HC, IN_CH);
    hipLaunchKernelGGL(k_cvt_wt, dim3(256), dim3(256), 0, stream, t1_Ws, wcat1 + (size_t)3 * HC * IN_CH, IN_CH, HC, IN_CH);
    hipLaunchKernelGGL(k_cvt_wt, dim3(1024), dim3(256), 0, stream, t2_Wq, wcat2 + (size_t)0 * HC * HC, HC, HC, HC);
    hipLaunchKernelGGL(k_cvt_wt, dim3(1024), dim3(256), 0, stream, t2_Wk, wcat2 + (size_t)1 * HC * HC, HC, HC, HC);
    hipLaunchKernelGGL(k_cvt_wt, dim3(1024), dim3(256), 0, stream, t2_Wv, wcat2 + (size_t)2 * HC * HC, HC, HC, HC);
    hipLaunchKernelGGL(k_cvt_wt, dim3(1024), dim3(256), 0, stream, t2_Ws, wcat2 + (size_t)3 * HC * HC, HC, HC, HC);
    hipLaunchKernelGGL(k_cvt_wt, dim3(192), dim3(256), 0, stream, t1_We, w1e, ED, HC, EDP);
    hipLaunchKernelGGL(k_cvt_wt, dim3(192), dim3(256), 0, stream, t2_We, w2e, ED, HC, EDP);
    hipLaunchKernelGGL(k_bcat, dim3(8), dim3(256), 0, stream, t1_bq, t1_bk, t1_bv, t1_bs, bcat1);
    hipLaunchKernelGGL(k_bcat, dim3(8), dim3(256), 0, stream, t2_bq, t2_bk, t2_bv, t2_bs, bcat2);

    auto run_layer = [&](const float* xin, int Kin, const ushort_t* wcat,
                         const float* bcat, const ushort_t* we,
                         float* xout, int poolmode) {
        // fused QKVS GEMM: [N_NODES, Kin] @ [Kin, 2048] -> qkv bf16 | sb f32
        {
            dim3 grid((N_NODES + 127) / 128, NCAT / 128);
            hipLaunchKernelGGL(k_mfma_gemm, grid, dim3(256), 0, stream,
                               xin, wcat, bcat, qkv, sb, QKVW, (const int*)nullptr, 0,
                               N_NODES, Kin, Kin, NCAT);
        }
        // edge-phase state init
        hipLaunchKernelGGL(k_fill, dim3(512), dim3(256), 0, stream, mbuf, -1e30f, N_NODES * NH);
        hipLaunchKernelGGL(k_fill, dim3(512), dim3(256), 0, stream, dbuf, 0.f, N_NODES * NH);
        hipLaunchKernelGGL(k_fill, dim3(4096), dim3(256), 0, stream, macc, 0.f, NHC);

        // chunked: e-GEMM (perm-gathered, bf16 out) + fused edge pass
        for (int e0 = 0; e0 < N_EDGES; e0 += EC) {
            int ec = (N_EDGES - e0 < EC) ? (N_EDGES - e0) : EC;
            dim3 grid((ec + 127) / 128, HC / 128);
            hipLaunchKernelGGL(k_mfma_gemm, grid, dim3(256), 0, stream,
                               ea, we, (const float*)nullptr, eb, (float*)nullptr, HC,
                               perm, e0, ec, ED, EDP, HC);
            hipLaunchKernelGGL(k_edge, dim3(N_NODES), dim3(128), 0, stream,
                               qkv, eb, psrc, rowptr, macc, mbuf, dbuf, e0, e0 + ec);
        }
        hipLaunchKernelGGL(k_epi2, dim3(2048), dim3(256), 0, stream, macc, dbuf, sb, xout, NHC);

        // pooling
        hipLaunchKernelGGL(k_fill, dim3(128), dim3(256), 0, stream, psum, 0.f, NB * HC);
        hipLaunchKernelGGL(k_fill, dim3(128), dim3(256), 0, stream, pmaxb, -1e30f, NB * HC);
        hipLaunchKernelGGL(k_pool2, dim3(NB, 8), dim3(256), 0, stream, xout, batch, psum, pmaxb, cnt);
        hipLaunchKernelGGL(k_poolfin, dim3((NB * 1024 + 255) / 256), dim3(256), 0, stream,
                           psum, pmaxb, cnt, hsum, poolmode);
    };

    // layer 1: x (N,128) -> x1 ; layer 2: x1 (N,512) -> x1
    run_layer(x, IN_CH, wcat1, bcat1, w1e, x1, /*poolmode=*/0);
    run_layer(x1, HC, wcat2, bcat2, w2e, x1, /*poolmode=*/1);

    hipLaunchKernelGGL(k_head, dim3(NB), dim3(256), 0, stream,
                       hsum, fc1_W, fc1_b, fc2_W, fc2_b, (float*)d_out);
}

// Round 8
// 1026.393 us; speedup vs baseline: 6.9859x; 1.3813x over previous
//
#include <hip/hip_runtime.h>
#include <cstdint>
#include <cstddef>

#define N_NODES 20000
#define N_EDGES 160000
#define IN_CH   128
#define NH      16
#define CD      32
#define HC      512   // NH*CD
#define ED      93
#define EDP     96    // ED padded to multiple of 32
#define NB      64
#define QKVW    1536  // q|k|v bf16 row width
#define NCAT    2048  // q|k|v|skip GEMM output cols

typedef __attribute__((ext_vector_type(8))) short short8;
typedef __attribute__((ext_vector_type(4))) float f32x4;
typedef unsigned short ushort_t;

// ---------------------------------------------------------------- utilities

__device__ inline void atomicMaxF(float* addr, float val) {
    unsigned int* ua = (unsigned int*)addr;
    unsigned int old = *ua;
    while (__uint_as_float(old) < val) {
        unsigned int assumed = old;
        old = atomicCAS(ua, assumed, __float_as_uint(val));
        if (old == assumed) break;
    }
}

__device__ inline ushort_t f2bf(float f) {
    unsigned int u = __float_as_uint(f);
    u = (u + 0x7FFF + ((u >> 16) & 1)) >> 16;   // RNE
    return (ushort_t)u;
}
__device__ inline float bf2f(ushort_t u) {
    return __uint_as_float((unsigned)u << 16);
}

__device__ inline uint4 pack8(const ushort_t* t) {
    uint4 u;
    u.x = (unsigned)t[0] | ((unsigned)t[1] << 16);
    u.y = (unsigned)t[2] | ((unsigned)t[3] << 16);
    u.z = (unsigned)t[4] | ((unsigned)t[5] << 16);
    u.w = (unsigned)t[6] | ((unsigned)t[7] << 16);
    return u;
}

__global__ void k_fill(float* __restrict__ p, float v, int n) {
    int i = blockIdx.x * blockDim.x + threadIdx.x;
    int stride = gridDim.x * blockDim.x;
    for (; i < n; i += stride) p[i] = v;
}
__global__ void k_zero_i(int* __restrict__ p, int n) {
    int i = blockIdx.x * blockDim.x + threadIdx.x;
    int stride = gridDim.x * blockDim.x;
    for (; i < n; i += stride) p[i] = 0;
}
__global__ void k_copy_i(const int* __restrict__ a, int* __restrict__ b, int n) {
    int i = blockIdx.x * blockDim.x + threadIdx.x;
    int stride = gridDim.x * blockDim.x;
    for (; i < n; i += stride) b[i] = a[i];
}

// f32 [M,K] -> bf16 [M,Kp] zero-padded rows
__global__ void k_cvt_pad(const float* __restrict__ in, ushort_t* __restrict__ out,
                          int M, int K, int Kp) {
    int i = blockIdx.x * blockDim.x + threadIdx.x;
    int stride = gridDim.x * blockDim.x;
    int total = M * Kp;
    for (; i < total; i += stride) {
        int m = i / Kp, k = i - m * Kp;
        out[i] = (k < K) ? f2bf(in[(size_t)m * K + k]) : (ushort_t)0;
    }
}

// W [K,N] f32 -> Wt [N,Kp] bf16 (transpose + pad)
__global__ void k_cvt_wt(const float* __restrict__ W, ushort_t* __restrict__ Wt,
                         int K, int N, int Kp) {
    int i = blockIdx.x * blockDim.x + threadIdx.x;
    int stride = gridDim.x * blockDim.x;
    int total = N * Kp;
    for (; i < total; i += stride) {
        int n = i / Kp, k = i - n * Kp;
        Wt[i] = (k < K) ? f2bf(W[(size_t)k * N + n]) : (ushort_t)0;
    }
}

// bcat[2048] = bq|bk|bv|bs
__global__ void k_bcat(const float* __restrict__ bq, const float* __restrict__ bk,
                       const float* __restrict__ bv, const float* __restrict__ bs,
                       float* __restrict__ out) {
    int i = blockIdx.x * blockDim.x + threadIdx.x;
    if (i >= NCAT) return;
    int s = i >> 9, j = i & 511;
    float v = (s == 0) ? bq[j] : (s == 1) ? bk[j] : (s == 2) ? bv[j] : bs[j];
    out[i] = v;
}

// ---------------------------------------------------------------- CSR build

__global__ void k_hist(const int* __restrict__ dst, int* __restrict__ deg) {
    int i = blockIdx.x * blockDim.x + threadIdx.x;
    if (i < N_EDGES) atomicAdd(&deg[dst[i]], 1);
}

__global__ __launch_bounds__(1024) void k_scan(const int* __restrict__ deg,
                                               int* __restrict__ rowptr) {
    __shared__ int part[1024];
    int t = threadIdx.x;
    int base = t * 20;
    int loc[20];
    int s = 0;
#pragma unroll
    for (int i = 0; i < 20; ++i) {
        int idx = base + i;
        int v = (idx < N_NODES) ? deg[idx] : 0;
        loc[i] = s; s += v;
    }
    part[t] = s;
    __syncthreads();
    for (int off = 1; off < 1024; off <<= 1) {
        int v = (t >= off) ? part[t - off] : 0;
        __syncthreads();
        part[t] += v;
        __syncthreads();
    }
    int pre = (t > 0) ? part[t - 1] : 0;
#pragma unroll
    for (int i = 0; i < 20; ++i) {
        int idx = base + i;
        if (idx < N_NODES) rowptr[idx] = pre + loc[i];
    }
    if (t == 1023) rowptr[N_NODES] = part[1023];
}

__global__ void k_scatter(const int* __restrict__ src, const int* __restrict__ dst,
                          int* __restrict__ cursor, int* __restrict__ perm,
                          int* __restrict__ psrc) {
    int i = blockIdx.x * blockDim.x + threadIdx.x;
    if (i >= N_EDGES) return;
    int d = dst[i];
    int p = atomicAdd(&cursor[d], 1);
    perm[p] = i;
    psrc[p] = src[i];
}

// ---------------------------------------------------------------- MFMA GEMM (QKVS)
// Y = A[M,K](f32 -> bf16 in staging) @ Bt[N,Kp]^T + bias
// cols < nsplit -> bf16 into Yb; cols >= nsplit -> f32 into Yf. K % 32 == 0.

__global__ __launch_bounds__(256) void k_mfma_gemm(
    const float* __restrict__ A, const ushort_t* __restrict__ Bt,
    const float* __restrict__ bias,
    ushort_t* __restrict__ Yb, float* __restrict__ Yf, int nsplit,
    int M, int K, int N) {
    __shared__ ushort_t lds[2 * 128 * 32];   // 16 KB
    char* As = (char*)lds;
    char* Bs = (char*)(lds + 128 * 32);

    int tid  = threadIdx.x;
    int lane = tid & 63, wave = tid >> 6;
    int l15 = lane & 15, lg = lane >> 4;
    int bm = blockIdx.x * 128, bn = blockIdx.y * 128;
    int wm = (wave >> 1) * 64, wn = (wave & 1) * 64;

    f32x4 acc[4][4] = {};

    int srow = tid >> 1;
    int skb  = (tid & 1) * 32;
    int ssw  = (srow & 3) << 4;
    int sb0  = skb ^ ssw;
    int sb1  = (skb + 16) ^ ssw;
    int grow = bm + srow;
    int brow = bn + srow;

    int fsw = (l15 & 3) << 4;
    int fkb = (lg * 16) ^ fsw;

    for (int k0 = 0; k0 < K; k0 += 32) {
        int kbase = k0 + (tid & 1) * 16;
        {
            ushort_t ta[16];
            if (grow < M) {
                const float4* ga = (const float4*)(A + (size_t)grow * K + kbase);
#pragma unroll
                for (int i = 0; i < 4; ++i) {
                    float4 f = ga[i];
                    ta[4 * i + 0] = f2bf(f.x); ta[4 * i + 1] = f2bf(f.y);
                    ta[4 * i + 2] = f2bf(f.z); ta[4 * i + 3] = f2bf(f.w);
                }
            } else {
#pragma unroll
                for (int i = 0; i < 16; ++i) ta[i] = 0;
            }
            *(uint4*)(As + srow * 64 + sb0) = pack8(ta);
            *(uint4*)(As + srow * 64 + sb1) = pack8(ta + 8);
        }
        {
            uint4 v0 = {0, 0, 0, 0}, v1 = {0, 0, 0, 0};
            if (brow < N) {
                const ushort_t* gb = Bt + (size_t)brow * K + kbase;
                v0 = *(const uint4*)(gb);
                v1 = *(const uint4*)(gb + 8);
            }
            *(uint4*)(Bs + srow * 64 + sb0) = v0;
            *(uint4*)(Bs + srow * 64 + sb1) = v1;
        }
        __syncthreads();

        short8 af[4], bfr[4];
#pragma unroll
        for (int mr = 0; mr < 4; ++mr)
            af[mr] = *(const short8*)(As + (wm + mr * 16 + l15) * 64 + fkb);
#pragma unroll
        for (int nc = 0; nc < 4; ++nc)
            bfr[nc] = *(const short8*)(Bs + (wn + nc * 16 + l15) * 64 + fkb);
#pragma unroll
        for (int mr = 0; mr < 4; ++mr)
#pragma unroll
            for (int nc = 0; nc < 4; ++nc)
                acc[mr][nc] = __builtin_amdgcn_mfma_f32_16x16x32_bf16(
                    af[mr], bfr[nc], acc[mr][nc], 0, 0, 0);
        __syncthreads();
    }

    int fld = N - nsplit;
#pragma unroll
    for (int mr = 0; mr < 4; ++mr) {
#pragma unroll
        for (int nc = 0; nc < 4; ++nc) {
            int col = bn + wn + nc * 16 + l15;
            if (col >= N) continue;
            float b = bias ? bias[col] : 0.f;
#pragma unroll
            for (int j = 0; j < 4; ++j) {
                int row = bm + wm + mr * 16 + lg * 4 + j;
                if (row >= M) continue;
                float v = acc[mr][nc][j] + b;
                if (col < nsplit) Yb[(size_t)row * nsplit + col] = f2bf(v);
                else              Yf[(size_t)row * fld + (col - nsplit)] = v;
            }
        }
    }
}

// ---------------------------------------------------------------- edge GEMM
// eb[r, :512] = ea_b[perm[e0+r], :96] @ We[512,96]^T   (bf16 in, bf16 out)
// Full-K single-stage: LDS A[128][192B] + B[128][192B] swizzled; 48 MFMAs;
// epilogue via LDS bounce -> 128B coalesced stores. 1D grid: bid>>2 = m-tile,
// (bid&3)*128 = col window.

#define EG_LDSB 49152

__global__ __launch_bounds__(256) void k_egemm(
    const ushort_t* __restrict__ Ab, const ushort_t* __restrict__ Bt,
    ushort_t* __restrict__ Yb, const int* __restrict__ perm,
    int pbase, int ec) {
    __shared__ char smem[EG_LDSB];
    char* As = smem;
    char* Bs = smem + 24576;

    int tid  = threadIdx.x;
    int lane = tid & 63, wave = tid >> 6;
    int l15 = lane & 15, lg = lane >> 4;
    int bid = blockIdx.x;
    int bm = (bid >> 2) * 128;
    int n0 = (bid & 3) * 128;
    int wm = (wave >> 1) * 64, wn = (wave & 1) * 64;

    // ---- stage A and B (full K=96), 2 threads/row x 96B each
    int srow = tid >> 1;
    int h    = tid & 1;
    {
        int gm = bm + srow;
        uint4 v[3] = {{0,0,0,0},{0,0,0,0},{0,0,0,0}};
        if (gm < ec) {
            int ar = perm[pbase + gm];
            const uint4* ga = (const uint4*)(Ab + (size_t)ar * EDP + h * 48);
            v[0] = ga[0]; v[1] = ga[1]; v[2] = ga[2];
        }
        char* dst = As + srow * 192;
#pragma unroll
        for (int i = 0; i < 3; ++i) {
            int c = h * 96 + i * 32;
            *(uint4*)(dst + ((c & ~63) | ((c & 63) ^ ((srow & 3) << 4)))) = v[i];
            // second 16B of the 32B pair
            int c2 = c + 16;
            (void)c2;
        }
        // note: 3 x 32B would misplace; do 6 x 16B explicitly instead
    }
    // redo staging correctly with 6x16B (overwrites above; kept simple)
    {
        int gm = bm + srow;
        uint4 va[6];
#pragma unroll
        for (int i = 0; i < 6; ++i) { va[i].x = va[i].y = va[i].z = va[i].w = 0; }
        if (gm < ec) {
            int ar = perm[pbase + gm];
            const uint4* ga = (const uint4*)(Ab + (size_t)ar * EDP + h * 48);
#pragma unroll
            for (int i = 0; i < 6; ++i) va[i] = ga[i];
        }
        char* dsta = As + srow * 192;
#pragma unroll
        for (int i = 0; i < 6; ++i) {
            int c = h * 96 + i * 16;
            *(uint4*)(dsta + ((c & ~63) | ((c & 63) ^ ((srow & 3) << 4)))) = va[i];
        }
        // B: rows are output cols n0+srow of We (Bt layout [512][96])
        uint4 vb[6];
        {
            const uint4* gb = (const uint4*)(Bt + (size_t)(n0 + srow) * EDP + h * 48);
#pragma unroll
            for (int i = 0; i < 6; ++i) vb[i] = gb[i];
        }
        char* dstb = Bs + srow * 192;
#pragma unroll
        for (int i = 0; i < 6; ++i) {
            int c = h * 96 + i * 16;
            *(uint4*)(dstb + ((c & ~63) | ((c & 63) ^ ((srow & 3) << 4)))) = vb[i];
        }
    }
    __syncthreads();

    // ---- compute: 3 k-steps x 16 MFMA
    f32x4 acc[4][4] = {};
#pragma unroll
    for (int ks = 0; ks < 3; ++ks) {
        short8 af[4], bfr[4];
#pragma unroll
        for (int mr = 0; mr < 4; ++mr) {
            int r = wm + mr * 16 + l15;
            int c = ks * 64 + ((lg * 16) ^ ((r & 3) << 4));
            af[mr] = *(const short8*)(As + r * 192 + c);
        }
#pragma unroll
        for (int nc = 0; nc < 4; ++nc) {
            int r = wn + nc * 16 + l15;
            int c = ks * 64 + ((lg * 16) ^ ((r & 3) << 4));
            bfr[nc] = *(const short8*)(Bs + r * 192 + c);
        }
#pragma unroll
        for (int mr = 0; mr < 4; ++mr)
#pragma unroll
            for (int nc = 0; nc < 4; ++nc)
                acc[mr][nc] = __builtin_amdgcn_mfma_f32_16x16x32_bf16(
                    af[mr], bfr[nc], acc[mr][nc], 0, 0, 0);
    }
    __syncthreads();   // done with A/B LDS

    // ---- epilogue: bf16 C tile into LDS (rows 288B), then coalesced copy
    char* Cs = smem;   // 128 * 288 = 36864 <= 49152
#pragma unroll
    for (int mr = 0; mr < 4; ++mr) {
#pragma unroll
        for (int nc = 0; nc < 4; ++nc) {
            int col = wn + nc * 16 + l15;
#pragma unroll
            for (int j = 0; j < 4; ++j) {
                int row = wm + mr * 16 + lg * 4 + j;
                *(ushort_t*)(Cs + row * 288 + col * 2) = f2bf(acc[mr][nc][j]);
            }
        }
    }
    __syncthreads();

    {
        int row = tid >> 1;
        int half = tid & 1;
        if (bm + row < ec) {
            const uint4* srcp = (const uint4*)(Cs + row * 288 + half * 128);
            uint4* dst = (uint4*)(Yb + (size_t)(bm + row) * HC + n0 + half * 64);
#pragma unroll
            for (int i = 0; i < 8; ++i) dst[i] = srcp[i];
        }
    }
}

// ---------------------------------------------------------------- fused edge phase

__global__ __launch_bounds__(128) void k_edge(
    const ushort_t* __restrict__ qkv, const ushort_t* __restrict__ eb,
    const int* __restrict__ psrc, const int* __restrict__ rowptr,
    float* __restrict__ macc, float* __restrict__ mbuf, float* __restrict__ dbuf,
    int e0, int e1) {
    int n = blockIdx.x;
    int beg = rowptr[n], end = rowptr[n + 1];
    int lo = beg > e0 ? beg : e0;
    int hi = end < e1 ? end : e1;
    if (lo >= hi) return;
    int t = threadIdx.x;
    int c0 = t * 4;
    int h = t >> 3;

    ushort4 qu = *(const ushort4*)(qkv + (size_t)n * QKVW + c0);
    float q0 = bf2f(qu.x), q1 = bf2f(qu.y), q2 = bf2f(qu.z), q3 = bf2f(qu.w);

    float mm = mbuf[n * NH + h];
    float dd = dbuf[n * NH + h];
    float4 av = *(const float4*)(macc + (size_t)n * HC + c0);
    float a0 = av.x, a1 = av.y, a2 = av.z, a3 = av.w;

    for (int i = lo; i < hi; ++i) {
        int sn = psrc[i];
        ushort4 ku = *(const ushort4*)(qkv + (size_t)sn * QKVW + 512 + c0);
        ushort4 vu = *(const ushort4*)(qkv + (size_t)sn * QKVW + 1024 + c0);
        ushort4 eu = *(const ushort4*)(eb + (size_t)(i - e0) * HC + c0);
        float e0f = bf2f(eu.x), e1f = bf2f(eu.y), e2f = bf2f(eu.z), e3f = bf2f(eu.w);
        float k0 = bf2f(ku.x) + e0f, k1 = bf2f(ku.y) + e1f;
        float k2 = bf2f(ku.z) + e2f, k3 = bf2f(ku.w) + e3f;
        float part = q0 * k0 + q1 * k1 + q2 * k2 + q3 * k3;
        part += __shfl_xor(part, 1);
        part += __shfl_xor(part, 2);
        part += __shfl_xor(part, 4);
        float s = part * 0.17677669529663687f;   // /sqrt(32)
        float mn = fmaxf(mm, s);
        float sc = __expf(mm - mn);
        float p  = __expf(s - mn);
        dd = dd * sc + p;
        mm = mn;
        float v0 = bf2f(vu.x) + e0f, v1 = bf2f(vu.y) + e1f;
        float v2 = bf2f(vu.z) + e2f, v3 = bf2f(vu.w) + e3f;
        a0 = a0 * sc + p * v0;
        a1 = a1 * sc + p * v1;
        a2 = a2 * sc + p * v2;
        a3 = a3 * sc + p * v3;
    }

    float4 out; out.x = a0; out.y = a1; out.z = a2; out.w = a3;
    *(float4*)(macc + (size_t)n * HC + c0) = out;
    if ((t & 7) == 0) { mbuf[n * NH + h] = mm; dbuf[n * NH + h] = dd; }
}

// x_out = leaky_relu(macc/d + skip, 0.2)
__global__ void k_epi2(const float* __restrict__ macc, const float* __restrict__ dbuf,
                       const float* __restrict__ sb, float* __restrict__ xout, int n) {
    int i = blockIdx.x * blockDim.x + threadIdx.x;
    int stride = gridDim.x * blockDim.x;
    for (; i < n; i += stride) {
        int node = i >> 9, c = i & (HC - 1);
        int h = c >> 5;
        float dd = dbuf[node * NH + h];
        float msg = (dd > 0.f) ? macc[i] / dd : 0.f;
        float v = msg + sb[i];
        xout[i] = v >= 0.f ? v : 0.2f * v;
    }
}

// ---------------------------------------------------------------- pooling

__global__ __launch_bounds__(256) void k_pool2(
    const float* __restrict__ x, const int* __restrict__ batch,
    float* __restrict__ psum, float* __restrict__ pmax, int* __restrict__ cnt) {
    int b = blockIdx.x;
    int s = blockIdx.y;
    int lo = 0, hi = N_NODES;
    while (lo < hi) { int mid = (lo + hi) >> 1; if (batch[mid] < b) lo = mid + 1; else hi = mid; }
    int beg = lo;
    hi = N_NODES;
    while (lo < hi) { int mid = (lo + hi) >> 1; if (batch[mid] < b + 1) lo = mid + 1; else hi = mid; }
    int end = lo;
    if (s == 0 && threadIdx.x == 0) cnt[b] = end - beg;
    int cn = end - beg;
    int per = (cn + 7) >> 3;
    int nb = beg + s * per;
    int ne = nb + per; if (ne > end) ne = end;
    if (nb >= ne) return;
    int c0 = threadIdx.x * 2;
    float s0 = 0.f, s1 = 0.f, m0 = -1e30f, m1 = -1e30f;
    for (int n = nb; n < ne; ++n) {
        float2 v = *(const float2*)(x + (size_t)n * HC + c0);
        s0 += v.x; s1 += v.y;
        m0 = fmaxf(m0, v.x); m1 = fmaxf(m1, v.y);
    }
    atomicAdd(&psum[b * HC + c0], s0);
    atomicAdd(&psum[b * HC + c0 + 1], s1);
    atomicMaxF(&pmax[b * HC + c0], m0);
    atomicMaxF(&pmax[b * HC + c0 + 1], m1);
}

__global__ void k_poolfin(const float* __restrict__ psum, const float* __restrict__ pmax,
                          const int* __restrict__ cnt, float* __restrict__ hsum, int mode) {
    int i = blockIdx.x * blockDim.x + threadIdx.x;
    if (i >= NB * 1024) return;
    int b = i >> 10, c = i & 1023;
    float val;
    if (c < HC) {
        int ct = cnt[b];
        val = psum[b * HC + c] / (float)(ct > 0 ? ct : 1);
    } else {
        val = pmax[b * HC + (c - HC)];
    }
    if (mode == 0) hsum[i] = val;
    else hsum[i] += val;
}

// ---------------------------------------------------------------- MLP head

__global__ __launch_bounds__(256) void k_head(
    const float* __restrict__ hsum, const float* __restrict__ fc1W,
    const float* __restrict__ fc1b, const float* __restrict__ fc2W,
    const float* __restrict__ fc2b, float* __restrict__ out) {
    int b = blockIdx.x;
    int j = threadIdx.x;
    __shared__ float hs[256];
    float acc = fc1b[j];
    const float* hin = hsum + (size_t)b * 1024;
    for (int k = 0; k < 1024; ++k) {
        acc += hin[k] * fc1W[(size_t)k * 256 + j];
    }
    hs[j] = fmaxf(acc, 0.f);
    __syncthreads();
    if (j < 32) {
        float o = fc2b[j];
        for (int k = 0; k < 256; ++k) o += hs[k] * fc2W[(size_t)k * 32 + j];
        out[b * 32 + j] = o;
    }
}

// ---------------------------------------------------------------- driver

extern "C" void kernel_launch(void* const* d_in, const int* in_sizes, int n_in,
                              void* d_out, int out_size, void* d_ws, size_t ws_size,
                              hipStream_t stream) {
    const float* x      = (const float*)d_in[0];
    const float* ea     = (const float*)d_in[1];
    const int*   ei     = (const int*)d_in[2];
    const int*   batch  = (const int*)d_in[3];
    const int* src = ei;
    const int* dst = ei + N_EDGES;

    const float* t1_Wq = (const float*)d_in[4];
    const float* t1_bq = (const float*)d_in[5];
    const float* t1_Wk = (const float*)d_in[6];
    const float* t1_bk = (const float*)d_in[7];
    const float* t1_Wv = (const float*)d_in[8];
    const float* t1_bv = (const float*)d_in[9];
    const float* t1_We = (const float*)d_in[10];
    const float* t1_Ws = (const float*)d_in[11];
    const float* t1_bs = (const float*)d_in[12];
    const float* t2_Wq = (const float*)d_in[13];
    const float* t2_bq = (const float*)d_in[14];
    const float* t2_Wk = (const float*)d_in[15];
    const float* t2_bk = (const float*)d_in[16];
    const float* t2_Wv = (const float*)d_in[17];
    const float* t2_bv = (const float*)d_in[18];
    const float* t2_We = (const float*)d_in[19];
    const float* t2_Ws = (const float*)d_in[20];
    const float* t2_bs = (const float*)d_in[21];
    const float* fc1_W = (const float*)d_in[22];
    const float* fc1_b = (const float*)d_in[23];
    const float* fc2_W = (const float*)d_in[24];
    const float* fc2_b = (const float*)d_in[25];

    char* ws = (char*)d_ws;
    size_t off = 0;
    auto alloc = [&](size_t bytes) -> void* {
        void* p = ws + off;
        off = (off + bytes + 255) & ~(size_t)255;
        return p;
    };

    ushort_t* qkv  = (ushort_t*)alloc((size_t)N_NODES * QKVW * 2);  // q|k|v bf16
    float* sb   = (float*)alloc((size_t)N_NODES * HC * 4);          // skip f32
    float* x1   = (float*)alloc((size_t)N_NODES * HC * 4);
    float* macc = (float*)alloc((size_t)N_NODES * HC * 4);
    float* mbuf = (float*)alloc((size_t)N_NODES * NH * 4);
    float* dbuf = (float*)alloc((size_t)N_NODES * NH * 4);
    float* psum = (float*)alloc((size_t)NB * HC * 4);
    float* pmaxb= (float*)alloc((size_t)NB * HC * 4);
    float* hsum = (float*)alloc((size_t)NB * 1024 * 4);
    int*   cnt  = (int*)alloc((size_t)NB * 4);
    // CSR
    int* deg    = (int*)alloc((size_t)N_NODES * 4);
    int* rowptr = (int*)alloc((size_t)(N_NODES + 1) * 4);
    int* cursor = (int*)alloc((size_t)N_NODES * 4);
    int* perm   = (int*)alloc((size_t)N_EDGES * 4);
    int* psrc   = (int*)alloc((size_t)N_EDGES * 4);
    // pre-padded bf16 edge_attr [E, 96]
    ushort_t* ea_b = (ushort_t*)alloc((size_t)N_EDGES * EDP * 2);
    // weights bf16
    ushort_t* wcat1 = (ushort_t*)alloc((size_t)NCAT * IN_CH * 2);
    ushort_t* wcat2 = (ushort_t*)alloc((size_t)NCAT * HC * 2);
    ushort_t* w1e   = (ushort_t*)alloc((size_t)HC * EDP * 2);
    ushort_t* w2e   = (ushort_t*)alloc((size_t)HC * EDP * 2);
    float* bcat1 = (float*)alloc((size_t)NCAT * 4);
    float* bcat2 = (float*)alloc((size_t)NCAT * 4);

    // remaining -> bf16 edge-feature chunk buffer eb [EC, HC]
    size_t remain = (ws_size > off) ? (ws_size - off) : 0;
    ushort_t* eb = (ushort_t*)(ws + off);
    size_t per_edge = (size_t)HC * 2;  // 1 KiB
    int EC;
    if (remain >= (size_t)N_EDGES * per_edge) {
        EC = N_EDGES;
    } else {
        EC = (int)(remain / per_edge);
        EC &= ~127;
        if (EC <= 0) EC = 128;
        if (EC > N_EDGES) EC = N_EDGES;
    }
    (void)in_sizes; (void)n_in; (void)out_size;

    const int NHC = N_NODES * HC;

    // ---- CSR build
    hipLaunchKernelGGL(k_zero_i, dim3(79), dim3(256), 0, stream, deg, N_NODES);
    hipLaunchKernelGGL(k_hist, dim3((N_EDGES + 255) / 256), dim3(256), 0, stream, dst, deg);
    hipLaunchKernelGGL(k_scan, dim3(1), dim3(1024), 0, stream, deg, rowptr);
    hipLaunchKernelGGL(k_copy_i, dim3(79), dim3(256), 0, stream, rowptr, cursor, N_NODES);
    hipLaunchKernelGGL(k_scatter, dim3((N_EDGES + 255) / 256), dim3(256), 0, stream,
                       src, dst, cursor, perm, psrc);

    // ---- conversions
    hipLaunchKernelGGL(k_cvt_pad, dim3(4096), dim3(256), 0, stream, ea, ea_b, N_EDGES, ED, EDP);
    hipLaunchKernelGGL(k_cvt_wt, dim3(256), dim3(256), 0, stream, t1_Wq, wcat1 + (size_t)0 * HC * IN_CH, IN_CH, HC, IN_CH);
    hipLaunchKernelGGL(k_cvt_wt, dim3(256), dim3(256), 0, stream, t1_Wk, wcat1 + (size_t)1 * HC * IN_CH, IN_CH, HC, IN_CH);
    hipLaunchKernelGGL(k_cvt_wt, dim3(256), dim3(256), 0, stream, t1_Wv, wcat1 + (size_t)2 * HC * IN_CH, IN_CH, HC, IN_CH);
    hipLaunchKernelGGL(k_cvt_wt, dim3(256), dim3(256), 0, stream, t1_Ws, wcat1 + (size_t)3 * HC * IN_CH, IN_CH, HC, IN_CH);
    hipLaunchKernelGGL(k_cvt_wt, dim3(1024), dim3(256), 0, stream, t2_Wq, wcat2 + (size_t)0 * HC * HC, HC, HC, HC);
    hipLaunchKernelGGL(k_cvt_wt, dim3(1024), dim3(256), 0, stream, t2_Wk, wcat2 + (size_t)1 * HC * HC, HC, HC, HC);
    hipLaunchKernelGGL(k_cvt_wt, dim3(1024), dim3(256), 0, stream, t2_Wv, wcat2 + (size_t)2 * HC * HC, HC, HC, HC);
    hipLaunchKernelGGL(k_cvt_wt, dim3(1024), dim3(256), 0, stream, t2_Ws, wcat2 + (size_t)3 * HC * HC, HC, HC, HC);
    hipLaunchKernelGGL(k_cvt_wt, dim3(192), dim3(256), 0, stream, t1_We, w1e, ED, HC, EDP);
    hipLaunchKernelGGL(k_cvt_wt, dim3(192), dim3(256), 0, stream, t2_We, w2e, ED, HC, EDP);
    hipLaunchKernelGGL(k_bcat, dim3(8), dim3(256), 0, stream, t1_bq, t1_bk, t1_bv, t1_bs, bcat1);
    hipLaunchKernelGGL(k_bcat, dim3(8), dim3(256), 0, stream, t2_bq, t2_bk, t2_bv, t2_bs, bcat2);

    auto run_layer = [&](const float* xin, int Kin, const ushort_t* wcat,
                         const float* bcat, const ushort_t* we,
                         float* xout, int poolmode) {
        // fused QKVS GEMM: [N_NODES, Kin] @ [Kin, 2048] -> qkv bf16 | sb f32
        {
            dim3 grid((N_NODES + 127) / 128, NCAT / 128);
            hipLaunchKernelGGL(k_mfma_gemm, grid, dim3(256), 0, stream,
                               xin, wcat, bcat, qkv, sb, QKVW,
                               N_NODES, Kin, NCAT);
        }
        // edge-phase state init
        hipLaunchKernelGGL(k_fill, dim3(512), dim3(256), 0, stream, mbuf, -1e30f, N_NODES * NH);
        hipLaunchKernelGGL(k_fill, dim3(512), dim3(256), 0, stream, dbuf, 0.f, N_NODES * NH);
        hipLaunchKernelGGL(k_fill, dim3(4096), dim3(256), 0, stream, macc, 0.f, NHC);

        // chunked: e-GEMM (gathered, bf16 out) + fused edge pass
        for (int e0 = 0; e0 < N_EDGES; e0 += EC) {
            int ec = (N_EDGES - e0 < EC) ? (N_EDGES - e0) : EC;
            int gm = (ec + 127) / 128;
            hipLaunchKernelGGL(k_egemm, dim3(gm * 4), dim3(256), 0, stream,
                               ea_b, we, eb, perm, e0, ec);
            hipLaunchKernelGGL(k_edge, dim3(N_NODES), dim3(128), 0, stream,
                               qkv, eb, psrc, rowptr, macc, mbuf, dbuf, e0, e0 + ec);
        }
        hipLaunchKernelGGL(k_epi2, dim3(2048), dim3(256), 0, stream, macc, dbuf, sb, xout, NHC);

        // pooling
        hipLaunchKernelGGL(k_fill, dim3(128), dim3(256), 0, stream, psum, 0.f, NB * HC);
        hipLaunchKernelGGL(k_fill, dim3(128), dim3(256), 0, stream, pmaxb, -1e30f, NB * HC);
        hipLaunchKernelGGL(k_pool2, dim3(NB, 8), dim3(256), 0, stream, xout, batch, psum, pmaxb, cnt);
        hipLaunchKernelGGL(k_poolfin, dim3((NB * 1024 + 255) / 256), dim3(256), 0, stream,
                           psum, pmaxb, cnt, hsum, poolmode);
    };

    // layer 1: x (N,128) -> x1 ; layer 2: x1 (N,512) -> x1
    run_layer(x, IN_CH, wcat1, bcat1, w1e, x1, /*poolmode=*/0);
    run_layer(x1, HC, wcat2, bcat2, w2e, x1, /*poolmode=*/1);

    hipLaunchKernelGGL(k_head, dim3(NB), dim3(256), 0, stream,
                       hsum, fc1_W, fc1_b, fc2_W, fc2_b, (float*)d_out);
}

// Round 9
// 1019.148 us; speedup vs baseline: 7.0356x; 1.0071x over previous
//
#include <hip/hip_runtime.h>
#include <cstdint>
#include <cstddef>

#define N_NODES 20000
#define N_EDGES 160000
#define IN_CH   128
#define NH      16
#define CD      32
#define HC      512   // NH*CD
#define ED      93
#define EDP     96    // ED padded to multiple of 32
#define NB      64
#define QKVW    1536  // q|k|v bf16 row width
#define NCAT    2048  // q|k|v|skip GEMM output cols

typedef __attribute__((ext_vector_type(8))) short short8;
typedef __attribute__((ext_vector_type(4))) float f32x4;
typedef unsigned short ushort_t;

// ---------------------------------------------------------------- utilities

__device__ inline void atomicMaxF(float* addr, float val) {
    unsigned int* ua = (unsigned int*)addr;
    unsigned int old = *ua;
    while (__uint_as_float(old) < val) {
        unsigned int assumed = old;
        old = atomicCAS(ua, assumed, __float_as_uint(val));
        if (old == assumed) break;
    }
}

__device__ inline ushort_t f2bf(float f) {
    unsigned int u = __float_as_uint(f);
    u = (u + 0x7FFF + ((u >> 16) & 1)) >> 16;   // RNE
    return (ushort_t)u;
}
__device__ inline float bf2f(ushort_t u) {
    return __uint_as_float((unsigned)u << 16);
}

__global__ void k_fill(float* __restrict__ p, float v, int n) {
    int i = blockIdx.x * blockDim.x + threadIdx.x;
    int stride = gridDim.x * blockDim.x;
    for (; i < n; i += stride) p[i] = v;
}
__global__ void k_zero_i(int* __restrict__ p, int n) {
    int i = blockIdx.x * blockDim.x + threadIdx.x;
    int stride = gridDim.x * blockDim.x;
    for (; i < n; i += stride) p[i] = 0;
}
__global__ void k_copy_i(const int* __restrict__ a, int* __restrict__ b, int n) {
    int i = blockIdx.x * blockDim.x + threadIdx.x;
    int stride = gridDim.x * blockDim.x;
    for (; i < n; i += stride) b[i] = a[i];
}

// f32 [M,K] -> bf16 [M,Kp] zero-padded rows (Kp==K => plain convert)
__global__ void k_cvt_pad(const float* __restrict__ in, ushort_t* __restrict__ out,
                          int M, int K, int Kp) {
    int i = blockIdx.x * blockDim.x + threadIdx.x;
    int stride = gridDim.x * blockDim.x;
    int total = M * Kp;
    for (; i < total; i += stride) {
        int m = i / Kp, k = i - m * Kp;
        out[i] = (k < K) ? f2bf(in[(size_t)m * K + k]) : (ushort_t)0;
    }
}

// W [K,N] f32 -> Wt [N,Kp] bf16 (transpose + pad)
__global__ void k_cvt_wt(const float* __restrict__ W, ushort_t* __restrict__ Wt,
                         int K, int N, int Kp) {
    int i = blockIdx.x * blockDim.x + threadIdx.x;
    int stride = gridDim.x * blockDim.x;
    int total = N * Kp;
    for (; i < total; i += stride) {
        int n = i / Kp, k = i - n * Kp;
        Wt[i] = (k < K) ? f2bf(W[(size_t)k * N + n]) : (ushort_t)0;
    }
}

// bcat[2048] = bq|bk|bv|bs
__global__ void k_bcat(const float* __restrict__ bq, const float* __restrict__ bk,
                       const float* __restrict__ bv, const float* __restrict__ bs,
                       float* __restrict__ out) {
    int i = blockIdx.x * blockDim.x + threadIdx.x;
    if (i >= NCAT) return;
    int s = i >> 9, j = i & 511;
    float v = (s == 0) ? bq[j] : (s == 1) ? bk[j] : (s == 2) ? bv[j] : bs[j];
    out[i] = v;
}

// ---------------------------------------------------------------- CSR build

__global__ void k_hist(const int* __restrict__ dst, int* __restrict__ deg) {
    int i = blockIdx.x * blockDim.x + threadIdx.x;
    if (i < N_EDGES) atomicAdd(&deg[dst[i]], 1);
}

__global__ __launch_bounds__(1024) void k_scan(const int* __restrict__ deg,
                                               int* __restrict__ rowptr) {
    __shared__ int part[1024];
    int t = threadIdx.x;
    int base = t * 20;
    int loc[20];
    int s = 0;
#pragma unroll
    for (int i = 0; i < 20; ++i) {
        int idx = base + i;
        int v = (idx < N_NODES) ? deg[idx] : 0;
        loc[i] = s; s += v;
    }
    part[t] = s;
    __syncthreads();
    for (int off = 1; off < 1024; off <<= 1) {
        int v = (t >= off) ? part[t - off] : 0;
        __syncthreads();
        part[t] += v;
        __syncthreads();
    }
    int pre = (t > 0) ? part[t - 1] : 0;
#pragma unroll
    for (int i = 0; i < 20; ++i) {
        int idx = base + i;
        if (idx < N_NODES) rowptr[idx] = pre + loc[i];
    }
    if (t == 1023) rowptr[N_NODES] = part[1023];
}

__global__ void k_scatter(const int* __restrict__ src, const int* __restrict__ dst,
                          int* __restrict__ cursor, int* __restrict__ perm,
                          int* __restrict__ psrc) {
    int i = blockIdx.x * blockDim.x + threadIdx.x;
    if (i >= N_EDGES) return;
    int d = dst[i];
    int p = atomicAdd(&cursor[d], 1);
    perm[p] = i;
    psrc[p] = src[i];
}

// ---------------------------------------------------------------- MFMA GEMM (QKVS)
// Y = A[M,K](bf16) @ Bt[N,K]^T + bias. 1-D grid, n-tile fastest (L2 A-reuse).
// cols < nsplit -> bf16 into Yb; cols >= nsplit -> f32 into Yf. K % 32 == 0.
// LDS rows 64B; swizzle ((row>>1)&3)<<4 => start-quads cover all 8 over 8 rows.

__global__ __launch_bounds__(256) void k_mfma_gemm(
    const ushort_t* __restrict__ A, const ushort_t* __restrict__ Bt,
    const float* __restrict__ bias,
    ushort_t* __restrict__ Yb, float* __restrict__ Yf, int nsplit,
    int M, int K, int N) {
    __shared__ ushort_t lds[2 * 128 * 32];   // 16 KB
    char* As = (char*)lds;
    char* Bs = (char*)(lds + 128 * 32);

    int tid  = threadIdx.x;
    int lane = tid & 63, wave = tid >> 6;
    int l15 = lane & 15, lg = lane >> 4;
    int nt = N >> 7;
    int bm = (blockIdx.x / nt) * 128, bn = (blockIdx.x % nt) * 128;
    int wm = (wave >> 1) * 64, wn = (wave & 1) * 64;

    f32x4 acc[4][4] = {};

    int srow = tid >> 1;
    int skb  = (tid & 1) * 32;
    int ssw  = ((srow >> 1) & 3) << 4;
    int sb0  = skb ^ ssw;
    int sb1  = (skb + 16) ^ ssw;
    int grow = bm + srow;
    int brow = bn + srow;

    int fsw = ((l15 >> 1) & 3) << 4;
    int fkb = (lg * 16) ^ fsw;

    for (int k0 = 0; k0 < K; k0 += 32) {
        int kbase = k0 + (tid & 1) * 16;
        {
            uint4 v0 = {0, 0, 0, 0}, v1 = {0, 0, 0, 0};
            if (grow < M) {
                const ushort_t* ga = A + (size_t)grow * K + kbase;
                v0 = *(const uint4*)(ga);
                v1 = *(const uint4*)(ga + 8);
            }
            *(uint4*)(As + srow * 64 + sb0) = v0;
            *(uint4*)(As + srow * 64 + sb1) = v1;
        }
        {
            uint4 v0 = {0, 0, 0, 0}, v1 = {0, 0, 0, 0};
            if (brow < N) {
                const ushort_t* gb = Bt + (size_t)brow * K + kbase;
                v0 = *(const uint4*)(gb);
                v1 = *(const uint4*)(gb + 8);
            }
            *(uint4*)(Bs + srow * 64 + sb0) = v0;
            *(uint4*)(Bs + srow * 64 + sb1) = v1;
        }
        __syncthreads();

        short8 af[4], bfr[4];
#pragma unroll
        for (int mr = 0; mr < 4; ++mr)
            af[mr] = *(const short8*)(As + (wm + mr * 16 + l15) * 64 + fkb);
#pragma unroll
        for (int nc = 0; nc < 4; ++nc)
            bfr[nc] = *(const short8*)(Bs + (wn + nc * 16 + l15) * 64 + fkb);
#pragma unroll
        for (int mr = 0; mr < 4; ++mr)
#pragma unroll
            for (int nc = 0; nc < 4; ++nc)
                acc[mr][nc] = __builtin_amdgcn_mfma_f32_16x16x32_bf16(
                    af[mr], bfr[nc], acc[mr][nc], 0, 0, 0);
        __syncthreads();
    }

    int fld = N - nsplit;
#pragma unroll
    for (int mr = 0; mr < 4; ++mr) {
#pragma unroll
        for (int nc = 0; nc < 4; ++nc) {
            int col = bn + wn + nc * 16 + l15;
            if (col >= N) continue;
            float b = bias ? bias[col] : 0.f;
#pragma unroll
            for (int j = 0; j < 4; ++j) {
                int row = bm + wm + mr * 16 + lg * 4 + j;
                if (row >= M) continue;
                float v = acc[mr][nc][j] + b;
                if (col < nsplit) Yb[(size_t)row * nsplit + col] = f2bf(v);
                else              Yf[(size_t)row * fld + (col - nsplit)] = v;
            }
        }
    }
}

// ---------------------------------------------------------------- edge GEMM
// eb[r, :512] = ea_b[perm[e0+r], :96] @ We[512,96]^T   (bf16 in, bf16 out)
// Full-K single-stage; swizzle ((row>>1)&3)<<4 within 64B groups of 192B rows.

#define EG_LDSB 49152

__global__ __launch_bounds__(256) void k_egemm(
    const ushort_t* __restrict__ Ab, const ushort_t* __restrict__ Bt,
    ushort_t* __restrict__ Yb, const int* __restrict__ perm,
    int pbase, int ec) {
    __shared__ char smem[EG_LDSB];
    char* As = smem;
    char* Bs = smem + 24576;

    int tid  = threadIdx.x;
    int lane = tid & 63, wave = tid >> 6;
    int l15 = lane & 15, lg = lane >> 4;
    int bid = blockIdx.x;
    int bm = (bid >> 2) * 128;
    int n0 = (bid & 3) * 128;
    int wm = (wave >> 1) * 64, wn = (wave & 1) * 64;

    // ---- stage A and B (full K=96), 2 threads/row x 96B each, 6x16B
    int srow = tid >> 1;
    int h    = tid & 1;
    int ssw  = ((srow >> 1) & 3) << 4;
    {
        int gm = bm + srow;
        uint4 va[6];
#pragma unroll
        for (int i = 0; i < 6; ++i) { va[i].x = va[i].y = va[i].z = va[i].w = 0; }
        if (gm < ec) {
            int ar = perm[pbase + gm];
            const uint4* ga = (const uint4*)(Ab + (size_t)ar * EDP + h * 48);
#pragma unroll
            for (int i = 0; i < 6; ++i) va[i] = ga[i];
        }
        char* dsta = As + srow * 192;
#pragma unroll
        for (int i = 0; i < 6; ++i) {
            int c = h * 96 + i * 16;
            *(uint4*)(dsta + ((c & ~63) | ((c & 63) ^ ssw))) = va[i];
        }
        uint4 vb[6];
        {
            const uint4* gb = (const uint4*)(Bt + (size_t)(n0 + srow) * EDP + h * 48);
#pragma unroll
            for (int i = 0; i < 6; ++i) vb[i] = gb[i];
        }
        char* dstb = Bs + srow * 192;
#pragma unroll
        for (int i = 0; i < 6; ++i) {
            int c = h * 96 + i * 16;
            *(uint4*)(dstb + ((c & ~63) | ((c & 63) ^ ssw))) = vb[i];
        }
    }
    __syncthreads();

    int fsw = ((l15 >> 1) & 3) << 4;

    // ---- compute: 3 k-steps x 16 MFMA
    f32x4 acc[4][4] = {};
#pragma unroll
    for (int ks = 0; ks < 3; ++ks) {
        short8 af[4], bfr[4];
#pragma unroll
        for (int mr = 0; mr < 4; ++mr) {
            int r = wm + mr * 16 + l15;
            int c = ks * 64 + ((lg * 16) ^ fsw);
            af[mr] = *(const short8*)(As + r * 192 + c);
        }
#pragma unroll
        for (int nc = 0; nc < 4; ++nc) {
            int r = wn + nc * 16 + l15;
            int c = ks * 64 + ((lg * 16) ^ fsw);
            bfr[nc] = *(const short8*)(Bs + r * 192 + c);
        }
#pragma unroll
        for (int mr = 0; mr < 4; ++mr)
#pragma unroll
            for (int nc = 0; nc < 4; ++nc)
                acc[mr][nc] = __builtin_amdgcn_mfma_f32_16x16x32_bf16(
                    af[mr], bfr[nc], acc[mr][nc], 0, 0, 0);
    }
    __syncthreads();   // done with A/B LDS

    // ---- epilogue: bf16 C tile into LDS (rows 288B), then coalesced copy
    char* Cs = smem;   // 128 * 288 = 36864 <= 49152
#pragma unroll
    for (int mr = 0; mr < 4; ++mr) {
#pragma unroll
        for (int nc = 0; nc < 4; ++nc) {
            int col = wn + nc * 16 + l15;
#pragma unroll
            for (int j = 0; j < 4; ++j) {
                int row = wm + mr * 16 + lg * 4 + j;
                *(ushort_t*)(Cs + row * 288 + col * 2) = f2bf(acc[mr][nc][j]);
            }
        }
    }
    __syncthreads();

    {
        int row = tid >> 1;
        int half = tid & 1;
        if (bm + row < ec) {
            const uint4* srcp = (const uint4*)(Cs + row * 288 + half * 128);
            uint4* dst = (uint4*)(Yb + (size_t)(bm + row) * HC + n0 + half * 64);
#pragma unroll
            for (int i = 0; i < 8; ++i) dst[i] = srcp[i];
        }
    }
}

// ---------------------------------------------------------------- fused edge phase

__global__ __launch_bounds__(128) void k_edge(
    const ushort_t* __restrict__ qkv, const ushort_t* __restrict__ eb,
    const int* __restrict__ psrc, const int* __restrict__ rowptr,
    float* __restrict__ macc, float* __restrict__ mbuf, float* __restrict__ dbuf,
    int e0, int e1) {
    int n = blockIdx.x;
    int beg = rowptr[n], end = rowptr[n + 1];
    int lo = beg > e0 ? beg : e0;
    int hi = end < e1 ? end : e1;
    if (lo >= hi) return;
    int t = threadIdx.x;
    int c0 = t * 4;
    int h = t >> 3;

    ushort4 qu = *(const ushort4*)(qkv + (size_t)n * QKVW + c0);
    float q0 = bf2f(qu.x), q1 = bf2f(qu.y), q2 = bf2f(qu.z), q3 = bf2f(qu.w);

    float mm = mbuf[n * NH + h];
    float dd = dbuf[n * NH + h];
    float4 av = *(const float4*)(macc + (size_t)n * HC + c0);
    float a0 = av.x, a1 = av.y, a2 = av.z, a3 = av.w;

    for (int i = lo; i < hi; ++i) {
        int sn = psrc[i];
        ushort4 ku = *(const ushort4*)(qkv + (size_t)sn * QKVW + 512 + c0);
        ushort4 vu = *(const ushort4*)(qkv + (size_t)sn * QKVW + 1024 + c0);
        ushort4 eu = *(const ushort4*)(eb + (size_t)(i - e0) * HC + c0);
        float e0f = bf2f(eu.x), e1f = bf2f(eu.y), e2f = bf2f(eu.z), e3f = bf2f(eu.w);
        float k0 = bf2f(ku.x) + e0f, k1 = bf2f(ku.y) + e1f;
        float k2 = bf2f(ku.z) + e2f, k3 = bf2f(ku.w) + e3f;
        float part = q0 * k0 + q1 * k1 + q2 * k2 + q3 * k3;
        part += __shfl_xor(part, 1);
        part += __shfl_xor(part, 2);
        part += __shfl_xor(part, 4);
        float s = part * 0.17677669529663687f;   // /sqrt(32)
        float mn = fmaxf(mm, s);
        float sc = __expf(mm - mn);
        float p  = __expf(s - mn);
        dd = dd * sc + p;
        mm = mn;
        float v0 = bf2f(vu.x) + e0f, v1 = bf2f(vu.y) + e1f;
        float v2 = bf2f(vu.z) + e2f, v3 = bf2f(vu.w) + e3f;
        a0 = a0 * sc + p * v0;
        a1 = a1 * sc + p * v1;
        a2 = a2 * sc + p * v2;
        a3 = a3 * sc + p * v3;
    }

    float4 out; out.x = a0; out.y = a1; out.z = a2; out.w = a3;
    *(float4*)(macc + (size_t)n * HC + c0) = out;
    if ((t & 7) == 0) { mbuf[n * NH + h] = mm; dbuf[n * NH + h] = dd; }
}

// x_out = leaky_relu(macc/d + skip, 0.2); optional bf16 mirror for next layer
__global__ void k_epi2(const float* __restrict__ macc, const float* __restrict__ dbuf,
                       const float* __restrict__ sb, float* __restrict__ xout,
                       ushort_t* __restrict__ xoutb, int n) {
    int i = blockIdx.x * blockDim.x + threadIdx.x;
    int stride = gridDim.x * blockDim.x;
    for (; i < n; i += stride) {
        int node = i >> 9, c = i & (HC - 1);
        int h = c >> 5;
        float dd = dbuf[node * NH + h];
        float msg = (dd > 0.f) ? macc[i] / dd : 0.f;
        float v = msg + sb[i];
        v = v >= 0.f ? v : 0.2f * v;
        xout[i] = v;
        if (xoutb) xoutb[i] = f2bf(v);
    }
}

// ---------------------------------------------------------------- pooling

__global__ __launch_bounds__(256) void k_pool2(
    const float* __restrict__ x, const int* __restrict__ batch,
    float* __restrict__ psum, float* __restrict__ pmax, int* __restrict__ cnt) {
    int b = blockIdx.x;
    int s = blockIdx.y;
    int lo = 0, hi = N_NODES;
    while (lo < hi) { int mid = (lo + hi) >> 1; if (batch[mid] < b) lo = mid + 1; else hi = mid; }
    int beg = lo;
    hi = N_NODES;
    while (lo < hi) { int mid = (lo + hi) >> 1; if (batch[mid] < b + 1) lo = mid + 1; else hi = mid; }
    int end = lo;
    if (s == 0 && threadIdx.x == 0) cnt[b] = end - beg;
    int cn = end - beg;
    int per = (cn + 7) >> 3;
    int nb = beg + s * per;
    int ne = nb + per; if (ne > end) ne = end;
    if (nb >= ne) return;
    int c0 = threadIdx.x * 2;
    float s0 = 0.f, s1 = 0.f, m0 = -1e30f, m1 = -1e30f;
    for (int n = nb; n < ne; ++n) {
        float2 v = *(const float2*)(x + (size_t)n * HC + c0);
        s0 += v.x; s1 += v.y;
        m0 = fmaxf(m0, v.x); m1 = fmaxf(m1, v.y);
    }
    atomicAdd(&psum[b * HC + c0], s0);
    atomicAdd(&psum[b * HC + c0 + 1], s1);
    atomicMaxF(&pmax[b * HC + c0], m0);
    atomicMaxF(&pmax[b * HC + c0 + 1], m1);
}

__global__ void k_poolfin(const float* __restrict__ psum, const float* __restrict__ pmax,
                          const int* __restrict__ cnt, float* __restrict__ hsum, int mode) {
    int i = blockIdx.x * blockDim.x + threadIdx.x;
    if (i >= NB * 1024) return;
    int b = i >> 10, c = i & 1023;
    float val;
    if (c < HC) {
        int ct = cnt[b];
        val = psum[b * HC + c] / (float)(ct > 0 ? ct : 1);
    } else {
        val = pmax[b * HC + (c - HC)];
    }
    if (mode == 0) hsum[i] = val;
    else hsum[i] += val;
}

// ---------------------------------------------------------------- MLP head

__global__ __launch_bounds__(256) void k_head(
    const float* __restrict__ hsum, const float* __restrict__ fc1W,
    const float* __restrict__ fc1b, const float* __restrict__ fc2W,
    const float* __restrict__ fc2b, float* __restrict__ out) {
    int b = blockIdx.x;
    int j = threadIdx.x;
    __shared__ float hs[256];
    float acc = fc1b[j];
    const float* hin = hsum + (size_t)b * 1024;
    for (int k = 0; k < 1024; ++k) {
        acc += hin[k] * fc1W[(size_t)k * 256 + j];
    }
    hs[j] = fmaxf(acc, 0.f);
    __syncthreads();
    if (j < 32) {
        float o = fc2b[j];
        for (int k = 0; k < 256; ++k) o += hs[k] * fc2W[(size_t)k * 32 + j];
        out[b * 32 + j] = o;
    }
}

// ---------------------------------------------------------------- driver

extern "C" void kernel_launch(void* const* d_in, const int* in_sizes, int n_in,
                              void* d_out, int out_size, void* d_ws, size_t ws_size,
                              hipStream_t stream) {
    const float* x      = (const float*)d_in[0];
    const float* ea     = (const float*)d_in[1];
    const int*   ei     = (const int*)d_in[2];
    const int*   batch  = (const int*)d_in[3];
    const int* src = ei;
    const int* dst = ei + N_EDGES;

    const float* t1_Wq = (const float*)d_in[4];
    const float* t1_bq = (const float*)d_in[5];
    const float* t1_Wk = (const float*)d_in[6];
    const float* t1_bk = (const float*)d_in[7];
    const float* t1_Wv = (const float*)d_in[8];
    const float* t1_bv = (const float*)d_in[9];
    const float* t1_We = (const float*)d_in[10];
    const float* t1_Ws = (const float*)d_in[11];
    const float* t1_bs = (const float*)d_in[12];
    const float* t2_Wq = (const float*)d_in[13];
    const float* t2_bq = (const float*)d_in[14];
    const float* t2_Wk = (const float*)d_in[15];
    const float* t2_bk = (const float*)d_in[16];
    const float* t2_Wv = (const float*)d_in[17];
    const float* t2_bv = (const float*)d_in[18];
    const float* t2_We = (const float*)d_in[19];
    const float* t2_Ws = (const float*)d_in[20];
    const float* t2_bs = (const float*)d_in[21];
    const float* fc1_W = (const float*)d_in[22];
    const float* fc1_b = (const float*)d_in[23];
    const float* fc2_W = (const float*)d_in[24];
    const float* fc2_b = (const float*)d_in[25];

    char* ws = (char*)d_ws;
    size_t off = 0;
    auto alloc = [&](size_t bytes) -> void* {
        void* p = ws + off;
        off = (off + bytes + 255) & ~(size_t)255;
        return p;
    };

    ushort_t* qkv  = (ushort_t*)alloc((size_t)N_NODES * QKVW * 2);  // q|k|v bf16
    float* sb   = (float*)alloc((size_t)N_NODES * HC * 4);          // skip f32
    float* x1   = (float*)alloc((size_t)N_NODES * HC * 4);
    float* macc = (float*)alloc((size_t)N_NODES * HC * 4);
    float* mbuf = (float*)alloc((size_t)N_NODES * NH * 4);
    float* dbuf = (float*)alloc((size_t)N_NODES * NH * 4);
    float* psum = (float*)alloc((size_t)NB * HC * 4);
    float* pmaxb= (float*)alloc((size_t)NB * HC * 4);
    float* hsum = (float*)alloc((size_t)NB * 1024 * 4);
    int*   cnt  = (int*)alloc((size_t)NB * 4);
    // CSR
    int* deg    = (int*)alloc((size_t)N_NODES * 4);
    int* rowptr = (int*)alloc((size_t)(N_NODES + 1) * 4);
    int* cursor = (int*)alloc((size_t)N_NODES * 4);
    int* perm   = (int*)alloc((size_t)N_EDGES * 4);
    int* psrc   = (int*)alloc((size_t)N_EDGES * 4);
    // bf16 activations
    ushort_t* x_b  = (ushort_t*)alloc((size_t)N_NODES * IN_CH * 2);
    ushort_t* x1_b = (ushort_t*)alloc((size_t)N_NODES * HC * 2);
    // pre-padded bf16 edge_attr [E, 96]
    ushort_t* ea_b = (ushort_t*)alloc((size_t)N_EDGES * EDP * 2);
    // weights bf16
    ushort_t* wcat1 = (ushort_t*)alloc((size_t)NCAT * IN_CH * 2);
    ushort_t* wcat2 = (ushort_t*)alloc((size_t)NCAT * HC * 2);
    ushort_t* w1e   = (ushort_t*)alloc((size_t)HC * EDP * 2);
    ushort_t* w2e   = (ushort_t*)alloc((size_t)HC * EDP * 2);
    float* bcat1 = (float*)alloc((size_t)NCAT * 4);
    float* bcat2 = (float*)alloc((size_t)NCAT * 4);

    // remaining -> bf16 edge-feature chunk buffer eb [EC, HC]
    size_t remain = (ws_size > off) ? (ws_size - off) : 0;
    ushort_t* eb = (ushort_t*)(ws + off);
    size_t per_edge = (size_t)HC * 2;  // 1 KiB
    int EC;
    if (remain >= (size_t)N_EDGES * per_edge) {
        EC = N_EDGES;
    } else {
        EC = (int)(remain / per_edge);
        EC &= ~127;
        if (EC <= 0) EC = 128;
        if (EC > N_EDGES) EC = N_EDGES;
    }
    (void)in_sizes; (void)n_in; (void)out_size;

    const int NHC = N_NODES * HC;

    // ---- CSR build
    hipLaunchKernelGGL(k_zero_i, dim3(79), dim3(256), 0, stream, deg, N_NODES);
    hipLaunchKernelGGL(k_hist, dim3((N_EDGES + 255) / 256), dim3(256), 0, stream, dst, deg);
    hipLaunchKernelGGL(k_scan, dim3(1), dim3(1024), 0, stream, deg, rowptr);
    hipLaunchKernelGGL(k_copy_i, dim3(79), dim3(256), 0, stream, rowptr, cursor, N_NODES);
    hipLaunchKernelGGL(k_scatter, dim3((N_EDGES + 255) / 256), dim3(256), 0, stream,
                       src, dst, cursor, perm, psrc);

    // ---- conversions
    hipLaunchKernelGGL(k_cvt_pad, dim3(1024), dim3(256), 0, stream, x, x_b, N_NODES, IN_CH, IN_CH);
    hipLaunchKernelGGL(k_cvt_pad, dim3(4096), dim3(256), 0, stream, ea, ea_b, N_EDGES, ED, EDP);
    hipLaunchKernelGGL(k_cvt_wt, dim3(256), dim3(256), 0, stream, t1_Wq, wcat1 + (size_t)0 * HC * IN_CH, IN_CH, HC, IN_CH);
    hipLaunchKernelGGL(k_cvt_wt, dim3(256), dim3(256), 0, stream, t1_Wk, wcat1 + (size_t)1 * HC * IN_CH, IN_CH, HC, IN_CH);
    hipLaunchKernelGGL(k_cvt_wt, dim3(256), dim3(256), 0, stream, t1_Wv, wcat1 + (size_t)2 * HC * IN_CH, IN_CH, HC, IN_CH);
    hipLaunchKernelGGL(k_cvt_wt, dim3(256), dim3(256), 0, stream, t1_Ws, wcat1 + (size_t)3 * HC * IN_CH, IN_CH, HC, IN_CH);
    hipLaunchKernelGGL(k_cvt_wt, dim3(1024), dim3(256), 0, stream, t2_Wq, wcat2 + (size_t)0 * HC * HC, HC, HC, HC);
    hipLaunchKernelGGL(k_cvt_wt, dim3(1024), dim3(256), 0, stream, t2_Wk, wcat2 + (size_t)1 * HC * HC, HC, HC, HC);
    hipLaunchKernelGGL(k_cvt_wt, dim3(1024), dim3(256), 0, stream, t2_Wv, wcat2 + (size_t)2 * HC * HC, HC, HC, HC);
    hipLaunchKernelGGL(k_cvt_wt, dim3(1024), dim3(256), 0, stream, t2_Ws, wcat2 + (size_t)3 * HC * HC, HC, HC, HC);
    hipLaunchKernelGGL(k_cvt_wt, dim3(192), dim3(256), 0, stream, t1_We, w1e, ED, HC, EDP);
    hipLaunchKernelGGL(k_cvt_wt, dim3(192), dim3(256), 0, stream, t2_We, w2e, ED, HC, EDP);
    hipLaunchKernelGGL(k_bcat, dim3(8), dim3(256), 0, stream, t1_bq, t1_bk, t1_bv, t1_bs, bcat1);
    hipLaunchKernelGGL(k_bcat, dim3(8), dim3(256), 0, stream, t2_bq, t2_bk, t2_bv, t2_bs, bcat2);

    auto run_layer = [&](const ushort_t* xin_b, int Kin, const ushort_t* wcat,
                         const float* bcat, const ushort_t* we,
                         float* xout, ushort_t* xoutb, int poolmode) {
        // fused QKVS GEMM: [N_NODES, Kin] @ [Kin, 2048] -> qkv bf16 | sb f32
        {
            int mt = (N_NODES + 127) / 128;
            int nt = NCAT / 128;
            hipLaunchKernelGGL(k_mfma_gemm, dim3(mt * nt), dim3(256), 0, stream,
                               xin_b, wcat, bcat, qkv, sb, QKVW,
                               N_NODES, Kin, NCAT);
        }
        // edge-phase state init
        hipLaunchKernelGGL(k_fill, dim3(512), dim3(256), 0, stream, mbuf, -1e30f, N_NODES * NH);
        hipLaunchKernelGGL(k_fill, dim3(512), dim3(256), 0, stream, dbuf, 0.f, N_NODES * NH);
        hipLaunchKernelGGL(k_fill, dim3(4096), dim3(256), 0, stream, macc, 0.f, NHC);

        // chunked: e-GEMM (gathered, bf16 out) + fused edge pass
        for (int e0 = 0; e0 < N_EDGES; e0 += EC) {
            int ec = (N_EDGES - e0 < EC) ? (N_EDGES - e0) : EC;
            int gm = (ec + 127) / 128;
            hipLaunchKernelGGL(k_egemm, dim3(gm * 4), dim3(256), 0, stream,
                               ea_b, we, eb, perm, e0, ec);
            hipLaunchKernelGGL(k_edge, dim3(N_NODES), dim3(128), 0, stream,
                               qkv, eb, psrc, rowptr, macc, mbuf, dbuf, e0, e0 + ec);
        }
        hipLaunchKernelGGL(k_epi2, dim3(2048), dim3(256), 0, stream,
                           macc, dbuf, sb, xout, xoutb, NHC);

        // pooling
        hipLaunchKernelGGL(k_fill, dim3(128), dim3(256), 0, stream, psum, 0.f, NB * HC);
        hipLaunchKernelGGL(k_fill, dim3(128), dim3(256), 0, stream, pmaxb, -1e30f, NB * HC);
        hipLaunchKernelGGL(k_pool2, dim3(NB, 8), dim3(256), 0, stream, xout, batch, psum, pmaxb, cnt);
        hipLaunchKernelGGL(k_poolfin, dim3((NB * 1024 + 255) / 256), dim3(256), 0, stream,
                           psum, pmaxb, cnt, hsum, poolmode);
    };

    // layer 1: x_b (N,128) -> x1 (+x1_b) ; layer 2: x1_b (N,512) -> x1
    run_layer(x_b, IN_CH, wcat1, bcat1, w1e, x1, x1_b, /*poolmode=*/0);
    run_layer(x1_b, HC, wcat2, bcat2, w2e, x1, (ushort_t*)nullptr, /*poolmode=*/1);

    hipLaunchKernelGGL(k_head, dim3(NB), dim3(256), 0, stream,
                       hsum, fc1_W, fc1_b, fc2_W, fc2_b, (float*)d_out);
}

// Round 10
// 867.452 us; speedup vs baseline: 8.2659x; 1.1749x over previous
//
#include <hip/hip_runtime.h>
#include <cstdint>
#include <cstddef>

#define N_NODES 20000
#define N_EDGES 160000
#define IN_CH   128
#define NH      16
#define CD      32
#define HC      512   // NH*CD
#define ED      93
#define EDP     96    // ED padded to multiple of 32
#define NB      64
#define NCAT    2048  // q|k|v|skip GEMM output cols (all bf16)

typedef __attribute__((ext_vector_type(8))) short short8;
typedef __attribute__((ext_vector_type(4))) float f32x4;
typedef unsigned short ushort_t;

// ---------------------------------------------------------------- utilities

__device__ inline void atomicMaxF(float* addr, float val) {
    unsigned int* ua = (unsigned int*)addr;
    unsigned int old = *ua;
    while (__uint_as_float(old) < val) {
        unsigned int assumed = old;
        old = atomicCAS(ua, assumed, __float_as_uint(val));
        if (old == assumed) break;
    }
}

__device__ inline ushort_t f2bf(float f) {
    unsigned int u = __float_as_uint(f);
    u = (u + 0x7FFF + ((u >> 16) & 1)) >> 16;   // RNE
    return (ushort_t)u;
}
__device__ inline float bf2f(ushort_t u) {
    return __uint_as_float((unsigned)u << 16);
}
__device__ inline void unpack8(uint4 u, float* o) {
    o[0] = bf2f((ushort_t)(u.x & 0xffff)); o[1] = bf2f((ushort_t)(u.x >> 16));
    o[2] = bf2f((ushort_t)(u.y & 0xffff)); o[3] = bf2f((ushort_t)(u.y >> 16));
    o[4] = bf2f((ushort_t)(u.z & 0xffff)); o[5] = bf2f((ushort_t)(u.z >> 16));
    o[6] = bf2f((ushort_t)(u.w & 0xffff)); o[7] = bf2f((ushort_t)(u.w >> 16));
}

__global__ void k_fill(float* __restrict__ p, float v, int n) {
    int i = blockIdx.x * blockDim.x + threadIdx.x;
    int stride = gridDim.x * blockDim.x;
    for (; i < n; i += stride) p[i] = v;
}
__global__ void k_zero_i(int* __restrict__ p, int n) {
    int i = blockIdx.x * blockDim.x + threadIdx.x;
    int stride = gridDim.x * blockDim.x;
    for (; i < n; i += stride) p[i] = 0;
}
__global__ void k_copy_i(const int* __restrict__ a, int* __restrict__ b, int n) {
    int i = blockIdx.x * blockDim.x + threadIdx.x;
    int stride = gridDim.x * blockDim.x;
    for (; i < n; i += stride) b[i] = a[i];
}

// f32 [M,K] -> bf16 [M,Kp] zero-padded rows
__global__ void k_cvt_pad(const float* __restrict__ in, ushort_t* __restrict__ out,
                          int M, int K, int Kp) {
    int i = blockIdx.x * blockDim.x + threadIdx.x;
    int stride = gridDim.x * blockDim.x;
    int total = M * Kp;
    for (; i < total; i += stride) {
        int m = i / Kp, k = i - m * Kp;
        out[i] = (k < K) ? f2bf(in[(size_t)m * K + k]) : (ushort_t)0;
    }
}

// W [K,N] f32 -> Wt [N,Kp] bf16 (transpose + pad)
__global__ void k_cvt_wt(const float* __restrict__ W, ushort_t* __restrict__ Wt,
                         int K, int N, int Kp) {
    int i = blockIdx.x * blockDim.x + threadIdx.x;
    int stride = gridDim.x * blockDim.x;
    int total = N * Kp;
    for (; i < total; i += stride) {
        int n = i / Kp, k = i - n * Kp;
        Wt[i] = (k < K) ? f2bf(W[(size_t)k * N + n]) : (ushort_t)0;
    }
}

// bcat[2048] = bq|bk|bv|bs
__global__ void k_bcat(const float* __restrict__ bq, const float* __restrict__ bk,
                       const float* __restrict__ bv, const float* __restrict__ bs,
                       float* __restrict__ out) {
    int i = blockIdx.x * blockDim.x + threadIdx.x;
    if (i >= NCAT) return;
    int s = i >> 9, j = i & 511;
    float v = (s == 0) ? bq[j] : (s == 1) ? bk[j] : (s == 2) ? bv[j] : bs[j];
    out[i] = v;
}

// ---------------------------------------------------------------- CSR build

__global__ void k_hist(const int* __restrict__ dst, int* __restrict__ deg) {
    int i = blockIdx.x * blockDim.x + threadIdx.x;
    if (i < N_EDGES) atomicAdd(&deg[dst[i]], 1);
}

__global__ __launch_bounds__(1024) void k_scan(const int* __restrict__ deg,
                                               int* __restrict__ rowptr) {
    __shared__ int part[1024];
    int t = threadIdx.x;
    int base = t * 20;
    int loc[20];
    int s = 0;
#pragma unroll
    for (int i = 0; i < 20; ++i) {
        int idx = base + i;
        int v = (idx < N_NODES) ? deg[idx] : 0;
        loc[i] = s; s += v;
    }
    part[t] = s;
    __syncthreads();
    for (int off = 1; off < 1024; off <<= 1) {
        int v = (t >= off) ? part[t - off] : 0;
        __syncthreads();
        part[t] += v;
        __syncthreads();
    }
    int pre = (t > 0) ? part[t - 1] : 0;
#pragma unroll
    for (int i = 0; i < 20; ++i) {
        int idx = base + i;
        if (idx < N_NODES) rowptr[idx] = pre + loc[i];
    }
    if (t == 1023) rowptr[N_NODES] = part[1023];
}

__global__ void k_scatter(const int* __restrict__ src, const int* __restrict__ dst,
                          int* __restrict__ cursor, int* __restrict__ perm,
                          int* __restrict__ psrc) {
    int i = blockIdx.x * blockDim.x + threadIdx.x;
    if (i >= N_EDGES) return;
    int d = dst[i];
    int p = atomicAdd(&cursor[d], 1);
    perm[p] = i;
    psrc[p] = src[i];
}

// ---------------------------------------------------------------- MFMA GEMM (QKVS)
// Yb[M,N](bf16) = A[M,K](bf16) @ Bt[N,K]^T + bias. BK=64, 128x128 tile, 4 waves.
// 1-D grid n-fastest + bijective XCD swizzle. LDS rows 128B, unit swizzle ^(row&7).

__global__ __launch_bounds__(256) void k_mfma_gemm(
    const ushort_t* __restrict__ A, const ushort_t* __restrict__ Bt,
    const float* __restrict__ bias, ushort_t* __restrict__ Yb,
    int M, int K, int N) {
    __shared__ char smem[32768];
    char* As = smem;
    char* Bs = smem + 16384;

    int tid  = threadIdx.x;
    int lane = tid & 63, wave = tid >> 6;
    int l15 = lane & 15, lg = lane >> 4;
    int nt = N >> 7;
    int nwg = gridDim.x;
    int bid = blockIdx.x;
    int wg;
    if ((nwg & 7) == 0) { int cpx = nwg >> 3; wg = (bid & 7) * cpx + (bid >> 3); }
    else wg = bid;
    int bm = (wg / nt) * 128, bn = (wg % nt) * 128;
    int wm = (wave >> 1) * 64, wn = (wave & 1) * 64;

    f32x4 acc[4][4] = {};

    int srow = tid >> 1;
    int half = tid & 1;
    int grow = bm + srow;
    int brow = bn + srow;

    for (int k0 = 0; k0 < K; k0 += 64) {
        // stage A: row srow, 64B half, 4x16B units c = half*4+i, phys = c^(row&7)
        {
            uint4 v[4];
#pragma unroll
            for (int i = 0; i < 4; ++i) { v[i].x = v[i].y = v[i].z = v[i].w = 0; }
            if (grow < M) {
                const uint4* ga = (const uint4*)(A + (size_t)grow * K + k0 + half * 32);
#pragma unroll
                for (int i = 0; i < 4; ++i) v[i] = ga[i];
            }
            char* d = As + srow * 128;
#pragma unroll
            for (int i = 0; i < 4; ++i)
                *(uint4*)(d + (((half * 4 + i) ^ (srow & 7)) << 4)) = v[i];
        }
        {
            uint4 v[4];
#pragma unroll
            for (int i = 0; i < 4; ++i) { v[i].x = v[i].y = v[i].z = v[i].w = 0; }
            if (brow < N) {
                const uint4* gb = (const uint4*)(Bt + (size_t)brow * K + k0 + half * 32);
#pragma unroll
                for (int i = 0; i < 4; ++i) v[i] = gb[i];
            }
            char* d = Bs + srow * 128;
#pragma unroll
            for (int i = 0; i < 4; ++i)
                *(uint4*)(d + (((half * 4 + i) ^ (srow & 7)) << 4)) = v[i];
        }
        __syncthreads();

#pragma unroll
        for (int ks = 0; ks < 2; ++ks) {
            short8 af[4], bfr[4];
#pragma unroll
            for (int mr = 0; mr < 4; ++mr) {
                int r = wm + mr * 16 + l15;
                af[mr] = *(const short8*)(As + r * 128 + (((ks * 4 + lg) ^ (r & 7)) << 4));
            }
#pragma unroll
            for (int nc = 0; nc < 4; ++nc) {
                int r = wn + nc * 16 + l15;
                bfr[nc] = *(const short8*)(Bs + r * 128 + (((ks * 4 + lg) ^ (r & 7)) << 4));
            }
#pragma unroll
            for (int mr = 0; mr < 4; ++mr)
#pragma unroll
                for (int nc = 0; nc < 4; ++nc)
                    acc[mr][nc] = __builtin_amdgcn_mfma_f32_16x16x32_bf16(
                        af[mr], bfr[nc], acc[mr][nc], 0, 0, 0);
        }
        __syncthreads();
    }

#pragma unroll
    for (int mr = 0; mr < 4; ++mr) {
#pragma unroll
        for (int nc = 0; nc < 4; ++nc) {
            int col = bn + wn + nc * 16 + l15;
            float b = bias ? bias[col] : 0.f;
#pragma unroll
            for (int j = 0; j < 4; ++j) {
                int row = bm + wm + mr * 16 + lg * 4 + j;
                if (row < M) Yb[(size_t)row * N + col] = f2bf(acc[mr][nc][j] + b);
            }
        }
    }
}

// ---------------------------------------------------------------- edge GEMM
// eb[r, :512] = ea_b[perm[e0+r], :96] @ We[512,96]^T (bf16). Full-K single-stage.

#define EG_LDSB 49152

__global__ __launch_bounds__(256) void k_egemm(
    const ushort_t* __restrict__ Ab, const ushort_t* __restrict__ Bt,
    ushort_t* __restrict__ Yb, const int* __restrict__ perm,
    int pbase, int ec) {
    __shared__ char smem[EG_LDSB];
    char* As = smem;
    char* Bs = smem + 24576;

    int tid  = threadIdx.x;
    int lane = tid & 63, wave = tid >> 6;
    int l15 = lane & 15, lg = lane >> 4;
    int nwg = gridDim.x;
    int bid = blockIdx.x;
    int wg;
    if ((nwg & 7) == 0) { int cpx = nwg >> 3; wg = (bid & 7) * cpx + (bid >> 3); }
    else wg = bid;
    int bm = (wg >> 2) * 128;
    int n0 = (wg & 3) * 128;
    int wm = (wave >> 1) * 64, wn = (wave & 1) * 64;

    int srow = tid >> 1;
    int h    = tid & 1;
    int ssw  = ((srow >> 1) & 3) << 4;
    {
        int gm = bm + srow;
        uint4 va[6];
#pragma unroll
        for (int i = 0; i < 6; ++i) { va[i].x = va[i].y = va[i].z = va[i].w = 0; }
        if (gm < ec) {
            int ar = perm[pbase + gm];
            const uint4* ga = (const uint4*)(Ab + (size_t)ar * EDP + h * 48);
#pragma unroll
            for (int i = 0; i < 6; ++i) va[i] = ga[i];
        }
        char* dsta = As + srow * 192;
#pragma unroll
        for (int i = 0; i < 6; ++i) {
            int c = h * 96 + i * 16;
            *(uint4*)(dsta + ((c & ~63) | ((c & 63) ^ ssw))) = va[i];
        }
        uint4 vb[6];
        {
            const uint4* gb = (const uint4*)(Bt + (size_t)(n0 + srow) * EDP + h * 48);
#pragma unroll
            for (int i = 0; i < 6; ++i) vb[i] = gb[i];
        }
        char* dstb = Bs + srow * 192;
#pragma unroll
        for (int i = 0; i < 6; ++i) {
            int c = h * 96 + i * 16;
            *(uint4*)(dstb + ((c & ~63) | ((c & 63) ^ ssw))) = vb[i];
        }
    }
    __syncthreads();

    int fsw = ((l15 >> 1) & 3) << 4;

    f32x4 acc[4][4] = {};
#pragma unroll
    for (int ks = 0; ks < 3; ++ks) {
        short8 af[4], bfr[4];
#pragma unroll
        for (int mr = 0; mr < 4; ++mr) {
            int r = wm + mr * 16 + l15;
            int c = ks * 64 + ((lg * 16) ^ fsw);
            af[mr] = *(const short8*)(As + r * 192 + c);
        }
#pragma unroll
        for (int nc = 0; nc < 4; ++nc) {
            int r = wn + nc * 16 + l15;
            int c = ks * 64 + ((lg * 16) ^ fsw);
            bfr[nc] = *(const short8*)(Bs + r * 192 + c);
        }
#pragma unroll
        for (int mr = 0; mr < 4; ++mr)
#pragma unroll
            for (int nc = 0; nc < 4; ++nc)
                acc[mr][nc] = __builtin_amdgcn_mfma_f32_16x16x32_bf16(
                    af[mr], bfr[nc], acc[mr][nc], 0, 0, 0);
    }
    __syncthreads();

    char* Cs = smem;   // 128 * 288 = 36864
#pragma unroll
    for (int mr = 0; mr < 4; ++mr) {
#pragma unroll
        for (int nc = 0; nc < 4; ++nc) {
            int col = wn + nc * 16 + l15;
#pragma unroll
            for (int j = 0; j < 4; ++j) {
                int row = wm + mr * 16 + lg * 4 + j;
                *(ushort_t*)(Cs + row * 288 + col * 2) = f2bf(acc[mr][nc][j]);
            }
        }
    }
    __syncthreads();

    {
        int row = tid >> 1;
        int halfc = tid & 1;
        if (bm + row < ec) {
            const uint4* srcp = (const uint4*)(Cs + row * 288 + halfc * 128);
            uint4* dstg = (uint4*)(Yb + (size_t)(bm + row) * HC + n0 + halfc * 64);
#pragma unroll
            for (int i = 0; i < 8; ++i) dstg[i] = srcp[i];
        }
    }
}

// ---------------------------------------------------------------- fused edge phase
// One block (128 thr = 2 waves) per dst node. Wave w handles edges lo+w, lo+w+2,...
// Each lane owns 8 channels (16B loads). Online softmax; LDS merge of 2 states.

__global__ __launch_bounds__(128) void k_edge(
    const ushort_t* __restrict__ qkvs, const ushort_t* __restrict__ eb,
    const int* __restrict__ psrc, const int* __restrict__ rowptr,
    float* __restrict__ macc, float* __restrict__ mbuf, float* __restrict__ dbuf,
    int e0, int e1) {
    int n = blockIdx.x;
    int beg = rowptr[n], end = rowptr[n + 1];
    int lo = beg > e0 ? beg : e0;
    int hi = end < e1 ? end : e1;
    if (lo >= hi) return;

    int t = threadIdx.x;
    int w = t >> 6;
    int lane = t & 63;
    int c0 = lane * 8;
    int h = lane >> 2;

    float q[8];
    unpack8(*(const uint4*)(qkvs + (size_t)n * NCAT + c0), q);

    float mm, dd, a[8];
    if (w == 0) {
        mm = mbuf[n * NH + h];
        dd = dbuf[n * NH + h];
        float4 a0 = *(const float4*)(macc + (size_t)n * HC + c0);
        float4 a1 = *(const float4*)(macc + (size_t)n * HC + c0 + 4);
        a[0] = a0.x; a[1] = a0.y; a[2] = a0.z; a[3] = a0.w;
        a[4] = a1.x; a[5] = a1.y; a[6] = a1.z; a[7] = a1.w;
    } else {
        mm = -1e30f; dd = 0.f;
#pragma unroll
        for (int j = 0; j < 8; ++j) a[j] = 0.f;
    }

    int i = lo + w;
    uint4 ku4, vu4, eu4;
    if (i < hi) {
        int sn = psrc[i];
        ku4 = *(const uint4*)(qkvs + (size_t)sn * NCAT + 512 + c0);
        vu4 = *(const uint4*)(qkvs + (size_t)sn * NCAT + 1024 + c0);
        eu4 = *(const uint4*)(eb + (size_t)(i - e0) * HC + c0);
    }
    while (i < hi) {
        uint4 kc = ku4, vc = vu4, ec = eu4;
        int inext = i + 2;
        if (inext < hi) {
            int sn2 = psrc[inext];
            ku4 = *(const uint4*)(qkvs + (size_t)sn2 * NCAT + 512 + c0);
            vu4 = *(const uint4*)(qkvs + (size_t)sn2 * NCAT + 1024 + c0);
            eu4 = *(const uint4*)(eb + (size_t)(inext - e0) * HC + c0);
        }
        float kk[8], vv[8], ee[8];
        unpack8(kc, kk); unpack8(vc, vv); unpack8(ec, ee);
        float part = 0.f;
#pragma unroll
        for (int j = 0; j < 8; ++j) part += q[j] * (kk[j] + ee[j]);
        part += __shfl_xor(part, 1);
        part += __shfl_xor(part, 2);
        float s = part * 0.17677669529663687f;   // /sqrt(32)
        float mn = fmaxf(mm, s);
        float sc = __expf(mm - mn);
        float p  = __expf(s - mn);
        dd = dd * sc + p;
        mm = mn;
#pragma unroll
        for (int j = 0; j < 8; ++j) a[j] = a[j] * sc + p * (vv[j] + ee[j]);
        i = inext;
    }

    // merge the two wave states
    __shared__ float sm_acc[512];
    __shared__ float sm_m[16];
    __shared__ float sm_d[16];
    if (w == 1) {
#pragma unroll
        for (int j = 0; j < 8; ++j) sm_acc[c0 + j] = a[j];
        if ((lane & 3) == 0) { sm_m[h] = mm; sm_d[h] = dd; }
    }
    __syncthreads();
    if (w == 0) {
        float m1 = sm_m[h], d1 = sm_d[h];
        float M = fmaxf(mm, m1);
        float sc0 = __expf(mm - M);
        float sc1 = __expf(m1 - M);
        dd = dd * sc0 + d1 * sc1;
        float4 o0, o1;
        o0.x = a[0] * sc0 + sm_acc[c0 + 0] * sc1;
        o0.y = a[1] * sc0 + sm_acc[c0 + 1] * sc1;
        o0.z = a[2] * sc0 + sm_acc[c0 + 2] * sc1;
        o0.w = a[3] * sc0 + sm_acc[c0 + 3] * sc1;
        o1.x = a[4] * sc0 + sm_acc[c0 + 4] * sc1;
        o1.y = a[5] * sc0 + sm_acc[c0 + 5] * sc1;
        o1.z = a[6] * sc0 + sm_acc[c0 + 6] * sc1;
        o1.w = a[7] * sc0 + sm_acc[c0 + 7] * sc1;
        *(float4*)(macc + (size_t)n * HC + c0) = o0;
        *(float4*)(macc + (size_t)n * HC + c0 + 4) = o1;
        if ((lane & 3) == 0) { mbuf[n * NH + h] = M; dbuf[n * NH + h] = dd; }
    }
}

// x_out = leaky_relu(macc/d + skip, 0.2); skip read bf16 from qkvs[:,1536:2048]
__global__ void k_epi2(const float* __restrict__ macc, const float* __restrict__ dbuf,
                       const ushort_t* __restrict__ qkvs, float* __restrict__ xout,
                       ushort_t* __restrict__ xoutb, int n) {
    int i = blockIdx.x * blockDim.x + threadIdx.x;
    int stride = gridDim.x * blockDim.x;
    for (; i < n; i += stride) {
        int node = i >> 9, c = i & (HC - 1);
        int h = c >> 5;
        float dd = dbuf[node * NH + h];
        float msg = (dd > 0.f) ? macc[i] / dd : 0.f;
        float sk = bf2f(qkvs[(size_t)node * NCAT + 1536 + c]);
        float v = msg + sk;
        v = v >= 0.f ? v : 0.2f * v;
        xout[i] = v;
        if (xoutb) xoutb[i] = f2bf(v);
    }
}

// ---------------------------------------------------------------- pooling

__global__ __launch_bounds__(256) void k_pool2(
    const float* __restrict__ x, const int* __restrict__ batch,
    float* __restrict__ psum, float* __restrict__ pmax, int* __restrict__ cnt) {
    int b = blockIdx.x;
    int s = blockIdx.y;
    int lo = 0, hi = N_NODES;
    while (lo < hi) { int mid = (lo + hi) >> 1; if (batch[mid] < b) lo = mid + 1; else hi = mid; }
    int beg = lo;
    hi = N_NODES;
    while (lo < hi) { int mid = (lo + hi) >> 1; if (batch[mid] < b + 1) lo = mid + 1; else hi = mid; }
    int end = lo;
    if (s == 0 && threadIdx.x == 0) cnt[b] = end - beg;
    int cn = end - beg;
    int per = (cn + 7) >> 3;
    int nb = beg + s * per;
    int ne = nb + per; if (ne > end) ne = end;
    if (nb >= ne) return;
    int c0 = threadIdx.x * 2;
    float s0 = 0.f, s1 = 0.f, m0 = -1e30f, m1 = -1e30f;
    for (int n = nb; n < ne; ++n) {
        float2 v = *(const float2*)(x + (size_t)n * HC + c0);
        s0 += v.x; s1 += v.y;
        m0 = fmaxf(m0, v.x); m1 = fmaxf(m1, v.y);
    }
    atomicAdd(&psum[b * HC + c0], s0);
    atomicAdd(&psum[b * HC + c0 + 1], s1);
    atomicMaxF(&pmax[b * HC + c0], m0);
    atomicMaxF(&pmax[b * HC + c0 + 1], m1);
}

__global__ void k_poolfin(const float* __restrict__ psum, const float* __restrict__ pmax,
                          const int* __restrict__ cnt, float* __restrict__ hsum, int mode) {
    int i = blockIdx.x * blockDim.x + threadIdx.x;
    if (i >= NB * 1024) return;
    int b = i >> 10, c = i & 1023;
    float val;
    if (c < HC) {
        int ct = cnt[b];
        val = psum[b * HC + c] / (float)(ct > 0 ? ct : 1);
    } else {
        val = pmax[b * HC + (c - HC)];
    }
    if (mode == 0) hsum[i] = val;
    else hsum[i] += val;
}

// ---------------------------------------------------------------- MLP head

__global__ __launch_bounds__(256) void k_head(
    const float* __restrict__ hsum, const float* __restrict__ fc1W,
    const float* __restrict__ fc1b, const float* __restrict__ fc2W,
    const float* __restrict__ fc2b, float* __restrict__ out) {
    int b = blockIdx.x;
    int j = threadIdx.x;
    __shared__ float hs[256];
    float acc = fc1b[j];
    const float* hin = hsum + (size_t)b * 1024;
    for (int k = 0; k < 1024; ++k) {
        acc += hin[k] * fc1W[(size_t)k * 256 + j];
    }
    hs[j] = fmaxf(acc, 0.f);
    __syncthreads();
    if (j < 32) {
        float o = fc2b[j];
        for (int k = 0; k < 256; ++k) o += hs[k] * fc2W[(size_t)k * 32 + j];
        out[b * 32 + j] = o;
    }
}

// ---------------------------------------------------------------- driver

extern "C" void kernel_launch(void* const* d_in, const int* in_sizes, int n_in,
                              void* d_out, int out_size, void* d_ws, size_t ws_size,
                              hipStream_t stream) {
    const float* x      = (const float*)d_in[0];
    const float* ea     = (const float*)d_in[1];
    const int*   ei     = (const int*)d_in[2];
    const int*   batch  = (const int*)d_in[3];
    const int* src = ei;
    const int* dst = ei + N_EDGES;

    const float* t1_Wq = (const float*)d_in[4];
    const float* t1_bq = (const float*)d_in[5];
    const float* t1_Wk = (const float*)d_in[6];
    const float* t1_bk = (const float*)d_in[7];
    const float* t1_Wv = (const float*)d_in[8];
    const float* t1_bv = (const float*)d_in[9];
    const float* t1_We = (const float*)d_in[10];
    const float* t1_Ws = (const float*)d_in[11];
    const float* t1_bs = (const float*)d_in[12];
    const float* t2_Wq = (const float*)d_in[13];
    const float* t2_bq = (const float*)d_in[14];
    const float* t2_Wk = (const float*)d_in[15];
    const float* t2_bk = (const float*)d_in[16];
    const float* t2_Wv = (const float*)d_in[17];
    const float* t2_bv = (const float*)d_in[18];
    const float* t2_We = (const float*)d_in[19];
    const float* t2_Ws = (const float*)d_in[20];
    const float* t2_bs = (const float*)d_in[21];
    const float* fc1_W = (const float*)d_in[22];
    const float* fc1_b = (const float*)d_in[23];
    const float* fc2_W = (const float*)d_in[24];
    const float* fc2_b = (const float*)d_in[25];

    char* ws = (char*)d_ws;
    size_t off = 0;
    auto alloc = [&](size_t bytes) -> void* {
        void* p = ws + off;
        off = (off + bytes + 255) & ~(size_t)255;
        return p;
    };

    ushort_t* qkvs = (ushort_t*)alloc((size_t)N_NODES * NCAT * 2);  // q|k|v|skip bf16
    float* x1   = (float*)alloc((size_t)N_NODES * HC * 4);
    float* macc = (float*)alloc((size_t)N_NODES * HC * 4);
    float* mbuf = (float*)alloc((size_t)N_NODES * NH * 4);
    float* dbuf = (float*)alloc((size_t)N_NODES * NH * 4);
    float* psum = (float*)alloc((size_t)NB * HC * 4);
    float* pmaxb= (float*)alloc((size_t)NB * HC * 4);
    float* hsum = (float*)alloc((size_t)NB * 1024 * 4);
    int*   cnt  = (int*)alloc((size_t)NB * 4);
    // CSR
    int* deg    = (int*)alloc((size_t)N_NODES * 4);
    int* rowptr = (int*)alloc((size_t)(N_NODES + 1) * 4);
    int* cursor = (int*)alloc((size_t)N_NODES * 4);
    int* perm   = (int*)alloc((size_t)N_EDGES * 4);
    int* psrc   = (int*)alloc((size_t)N_EDGES * 4);
    // bf16 activations
    ushort_t* x_b  = (ushort_t*)alloc((size_t)N_NODES * IN_CH * 2);
    ushort_t* x1_b = (ushort_t*)alloc((size_t)N_NODES * HC * 2);
    // pre-padded bf16 edge_attr [E, 96]
    ushort_t* ea_b = (ushort_t*)alloc((size_t)N_EDGES * EDP * 2);
    // weights bf16
    ushort_t* wcat1 = (ushort_t*)alloc((size_t)NCAT * IN_CH * 2);
    ushort_t* wcat2 = (ushort_t*)alloc((size_t)NCAT * HC * 2);
    ushort_t* w1e   = (ushort_t*)alloc((size_t)HC * EDP * 2);
    ushort_t* w2e   = (ushort_t*)alloc((size_t)HC * EDP * 2);
    float* bcat1 = (float*)alloc((size_t)NCAT * 4);
    float* bcat2 = (float*)alloc((size_t)NCAT * 4);

    // remaining -> bf16 edge-feature chunk buffer eb [EC, HC]
    size_t remain = (ws_size > off) ? (ws_size - off) : 0;
    ushort_t* eb = (ushort_t*)(ws + off);
    size_t per_edge = (size_t)HC * 2;  // 1 KiB
    int EC;
    if (remain >= (size_t)N_EDGES * per_edge) {
        EC = N_EDGES;
    } else {
        EC = (int)(remain / per_edge);
        EC &= ~255;
        if (EC <= 0) EC = 256;
        if (EC > N_EDGES) EC = N_EDGES;
    }
    (void)in_sizes; (void)n_in; (void)out_size;

    const int NHC = N_NODES * HC;

    // ---- CSR build
    hipLaunchKernelGGL(k_zero_i, dim3(79), dim3(256), 0, stream, deg, N_NODES);
    hipLaunchKernelGGL(k_hist, dim3((N_EDGES + 255) / 256), dim3(256), 0, stream, dst, deg);
    hipLaunchKernelGGL(k_scan, dim3(1), dim3(1024), 0, stream, deg, rowptr);
    hipLaunchKernelGGL(k_copy_i, dim3(79), dim3(256), 0, stream, rowptr, cursor, N_NODES);
    hipLaunchKernelGGL(k_scatter, dim3((N_EDGES + 255) / 256), dim3(256), 0, stream,
                       src, dst, cursor, perm, psrc);

    // ---- conversions
    hipLaunchKernelGGL(k_cvt_pad, dim3(1024), dim3(256), 0, stream, x, x_b, N_NODES, IN_CH, IN_CH);
    hipLaunchKernelGGL(k_cvt_pad, dim3(4096), dim3(256), 0, stream, ea, ea_b, N_EDGES, ED, EDP);
    hipLaunchKernelGGL(k_cvt_wt, dim3(256), dim3(256), 0, stream, t1_Wq, wcat1 + (size_t)0 * HC * IN_CH, IN_CH, HC, IN_CH);
    hipLaunchKernelGGL(k_cvt_wt, dim3(256), dim3(256), 0, stream, t1_Wk, wcat1 + (size_t)1 * HC * IN_CH, IN_CH, HC, IN_CH);
    hipLaunchKernelGGL(k_cvt_wt, dim3(256), dim3(256), 0, stream, t1_Wv, wcat1 + (size_t)2 * HC * IN_CH, IN_CH, HC, IN_CH);
    hipLaunchKernelGGL(k_cvt_wt, dim3(256), dim3(256), 0, stream, t1_Ws, wcat1 + (size_t)3 * HC * IN_CH, IN_CH, HC, IN_CH);
    hipLaunchKernelGGL(k_cvt_wt, dim3(1024), dim3(256), 0, stream, t2_Wq, wcat2 + (size_t)0 * HC * HC, HC, HC, HC);
    hipLaunchKernelGGL(k_cvt_wt, dim3(1024), dim3(256), 0, stream, t2_Wk, wcat2 + (size_t)1 * HC * HC, HC, HC, HC);
    hipLaunchKernelGGL(k_cvt_wt, dim3(1024), dim3(256), 0, stream, t2_Wv, wcat2 + (size_t)2 * HC * HC, HC, HC, HC);
    hipLaunchKernelGGL(k_cvt_wt, dim3(1024), dim3(256), 0, stream, t2_Ws, wcat2 + (size_t)3 * HC * HC, HC, HC, HC);
    hipLaunchKernelGGL(k_cvt_wt, dim3(192), dim3(256), 0, stream, t1_We, w1e, ED, HC, EDP);
    hipLaunchKernelGGL(k_cvt_wt, dim3(192), dim3(256), 0, stream, t2_We, w2e, ED, HC, EDP);
    hipLaunchKernelGGL(k_bcat, dim3(8), dim3(256), 0, stream, t1_bq, t1_bk, t1_bv, t1_bs, bcat1);
    hipLaunchKernelGGL(k_bcat, dim3(8), dim3(256), 0, stream, t2_bq, t2_bk, t2_bv, t2_bs, bcat2);

    auto run_layer = [&](const ushort_t* xin_b, int Kin, const ushort_t* wcat,
                         const float* bcat, const ushort_t* we,
                         float* xout, ushort_t* xoutb, int poolmode) {
        // fused QKVS GEMM: [N_NODES, Kin] @ [Kin, 2048] -> qkvs bf16
        {
            int mt = (N_NODES + 127) / 128;
            int nt = NCAT / 128;
            hipLaunchKernelGGL(k_mfma_gemm, dim3(mt * nt), dim3(256), 0, stream,
                               xin_b, wcat, bcat, qkvs, N_NODES, Kin, NCAT);
        }
        // edge-phase state init
        hipLaunchKernelGGL(k_fill, dim3(512), dim3(256), 0, stream, mbuf, -1e30f, N_NODES * NH);
        hipLaunchKernelGGL(k_fill, dim3(512), dim3(256), 0, stream, dbuf, 0.f, N_NODES * NH);
        hipLaunchKernelGGL(k_fill, dim3(4096), dim3(256), 0, stream, macc, 0.f, NHC);

        // chunked: e-GEMM (gathered, bf16 out) + fused edge pass
        for (int e0 = 0; e0 < N_EDGES; e0 += EC) {
            int ec = (N_EDGES - e0 < EC) ? (N_EDGES - e0) : EC;
            int gm = (ec + 127) / 128;
            hipLaunchKernelGGL(k_egemm, dim3(gm * 4), dim3(256), 0, stream,
                               ea_b, we, eb, perm, e0, ec);
            hipLaunchKernelGGL(k_edge, dim3(N_NODES), dim3(128), 0, stream,
                               qkvs, eb, psrc, rowptr, macc, mbuf, dbuf, e0, e0 + ec);
        }
        hipLaunchKernelGGL(k_epi2, dim3(2048), dim3(256), 0, stream,
                           macc, dbuf, qkvs, xout, xoutb, NHC);

        // pooling
        hipLaunchKernelGGL(k_fill, dim3(128), dim3(256), 0, stream, psum, 0.f, NB * HC);
        hipLaunchKernelGGL(k_fill, dim3(128), dim3(256), 0, stream, pmaxb, -1e30f, NB * HC);
        hipLaunchKernelGGL(k_pool2, dim3(NB, 8), dim3(256), 0, stream, xout, batch, psum, pmaxb, cnt);
        hipLaunchKernelGGL(k_poolfin, dim3((NB * 1024 + 255) / 256), dim3(256), 0, stream,
                           psum, pmaxb, cnt, hsum, poolmode);
    };

    // layer 1: x_b (N,128) -> x1 (+x1_b) ; layer 2: x1_b (N,512) -> x1
    run_layer(x_b, IN_CH, wcat1, bcat1, w1e, x1, x1_b, /*poolmode=*/0);
    run_layer(x1_b, HC, wcat2, bcat2, w2e, x1, (ushort_t*)nullptr, /*poolmode=*/1);

    hipLaunchKernelGGL(k_head, dim3(NB), dim3(256), 0, stream,
                       hsum, fc1_W, fc1_b, fc2_W, fc2_b, (float*)d_out);
}

// Round 11
// 830.642 us; speedup vs baseline: 8.6323x; 1.0443x over previous
//
#include <hip/hip_runtime.h>
#include <cstdint>
#include <cstddef>

#define N_NODES 20000
#define N_EDGES 160000
#define IN_CH   128
#define NH      16
#define CD      32
#define HC      512   // NH*CD
#define ED      93
#define EDP     96    // ED padded to multiple of 32
#define NB      64
#define NCAT    2048  // q|k|v|skip GEMM output cols (all bf16)

typedef __attribute__((ext_vector_type(8))) short short8;
typedef __attribute__((ext_vector_type(4))) float f32x4;
typedef unsigned short ushort_t;

// ---------------------------------------------------------------- utilities

__device__ inline void atomicMaxF(float* addr, float val) {
    unsigned int* ua = (unsigned int*)addr;
    unsigned int old = *ua;
    while (__uint_as_float(old) < val) {
        unsigned int assumed = old;
        old = atomicCAS(ua, assumed, __float_as_uint(val));
        if (old == assumed) break;
    }
}

__device__ inline ushort_t f2bf(float f) {
    unsigned int u = __float_as_uint(f);
    u = (u + 0x7FFF + ((u >> 16) & 1)) >> 16;   // RNE
    return (ushort_t)u;
}
__device__ inline float bf2f(ushort_t u) {
    return __uint_as_float((unsigned)u << 16);
}
__device__ inline void unpack8(uint4 u, float* o) {
    o[0] = bf2f((ushort_t)(u.x & 0xffff)); o[1] = bf2f((ushort_t)(u.x >> 16));
    o[2] = bf2f((ushort_t)(u.y & 0xffff)); o[3] = bf2f((ushort_t)(u.y >> 16));
    o[4] = bf2f((ushort_t)(u.z & 0xffff)); o[5] = bf2f((ushort_t)(u.z >> 16));
    o[6] = bf2f((ushort_t)(u.w & 0xffff)); o[7] = bf2f((ushort_t)(u.w >> 16));
}

__global__ void k_fill(float* __restrict__ p, float v, int n) {
    int i = blockIdx.x * blockDim.x + threadIdx.x;
    int stride = gridDim.x * blockDim.x;
    for (; i < n; i += stride) p[i] = v;
}
__global__ void k_zero_i(int* __restrict__ p, int n) {
    int i = blockIdx.x * blockDim.x + threadIdx.x;
    int stride = gridDim.x * blockDim.x;
    for (; i < n; i += stride) p[i] = 0;
}
__global__ void k_copy_i(const int* __restrict__ a, int* __restrict__ b, int n) {
    int i = blockIdx.x * blockDim.x + threadIdx.x;
    int stride = gridDim.x * blockDim.x;
    for (; i < n; i += stride) b[i] = a[i];
}

// f32 [M,K] -> bf16 [M,Kp] zero-padded rows
__global__ void k_cvt_pad(const float* __restrict__ in, ushort_t* __restrict__ out,
                          int M, int K, int Kp) {
    int i = blockIdx.x * blockDim.x + threadIdx.x;
    int stride = gridDim.x * blockDim.x;
    int total = M * Kp;
    for (; i < total; i += stride) {
        int m = i / Kp, k = i - m * Kp;
        out[i] = (k < K) ? f2bf(in[(size_t)m * K + k]) : (ushort_t)0;
    }
}

// W [K,N] f32 -> Wt [N,Kp] bf16 (transpose + pad)
__global__ void k_cvt_wt(const float* __restrict__ W, ushort_t* __restrict__ Wt,
                         int K, int N, int Kp) {
    int i = blockIdx.x * blockDim.x + threadIdx.x;
    int stride = gridDim.x * blockDim.x;
    int total = N * Kp;
    for (; i < total; i += stride) {
        int n = i / Kp, k = i - n * Kp;
        Wt[i] = (k < K) ? f2bf(W[(size_t)k * N + n]) : (ushort_t)0;
    }
}

// bcat[2048] = bq|bk|bv|bs
__global__ void k_bcat(const float* __restrict__ bq, const float* __restrict__ bk,
                       const float* __restrict__ bv, const float* __restrict__ bs,
                       float* __restrict__ out) {
    int i = blockIdx.x * blockDim.x + threadIdx.x;
    if (i >= NCAT) return;
    int s = i >> 9, j = i & 511;
    float v = (s == 0) ? bq[j] : (s == 1) ? bk[j] : (s == 2) ? bv[j] : bs[j];
    out[i] = v;
}

// ---------------------------------------------------------------- CSR build

__global__ void k_hist(const int* __restrict__ dst, int* __restrict__ deg) {
    int i = blockIdx.x * blockDim.x + threadIdx.x;
    if (i < N_EDGES) atomicAdd(&deg[dst[i]], 1);
}

__global__ __launch_bounds__(1024) void k_scan(const int* __restrict__ deg,
                                               int* __restrict__ rowptr) {
    __shared__ int part[1024];
    int t = threadIdx.x;
    int base = t * 20;
    int loc[20];
    int s = 0;
#pragma unroll
    for (int i = 0; i < 20; ++i) {
        int idx = base + i;
        int v = (idx < N_NODES) ? deg[idx] : 0;
        loc[i] = s; s += v;
    }
    part[t] = s;
    __syncthreads();
    for (int off = 1; off < 1024; off <<= 1) {
        int v = (t >= off) ? part[t - off] : 0;
        __syncthreads();
        part[t] += v;
        __syncthreads();
    }
    int pre = (t > 0) ? part[t - 1] : 0;
#pragma unroll
    for (int i = 0; i < 20; ++i) {
        int idx = base + i;
        if (idx < N_NODES) rowptr[idx] = pre + loc[i];
    }
    if (t == 1023) rowptr[N_NODES] = part[1023];
}

__global__ void k_scatter(const int* __restrict__ src, const int* __restrict__ dst,
                          int* __restrict__ cursor, int* __restrict__ perm,
                          int* __restrict__ psrc) {
    int i = blockIdx.x * blockDim.x + threadIdx.x;
    if (i >= N_EDGES) return;
    int d = dst[i];
    int p = atomicAdd(&cursor[d], 1);
    perm[p] = i;
    psrc[p] = src[i];
}

// ---------------------------------------------------------------- MFMA GEMM (QKVS)
// Yb[M,N](bf16) = A[M,K](bf16) @ Bt[N,K]^T + bias. BK=64, 128x128 tile, 4 waves.
// 1-D grid n-fastest + bijective XCD swizzle. LDS rows 128B, unit swizzle ^(row&7).
// Epilogue: LDS bounce (XOR-swizzled) -> 128B/thread coalesced stores.

__global__ __launch_bounds__(256) void k_mfma_gemm(
    const ushort_t* __restrict__ A, const ushort_t* __restrict__ Bt,
    const float* __restrict__ bias, ushort_t* __restrict__ Yb,
    int M, int K, int N) {
    __shared__ char smem[32768];
    char* As = smem;
    char* Bs = smem + 16384;

    int tid  = threadIdx.x;
    int lane = tid & 63, wave = tid >> 6;
    int l15 = lane & 15, lg = lane >> 4;
    int nt = N >> 7;
    int nwg = gridDim.x;
    int bid = blockIdx.x;
    int wg;
    if ((nwg & 7) == 0) { int cpx = nwg >> 3; wg = (bid & 7) * cpx + (bid >> 3); }
    else wg = bid;
    int bm = (wg / nt) * 128, bn = (wg % nt) * 128;
    int wm = (wave >> 1) * 64, wn = (wave & 1) * 64;

    f32x4 acc[4][4] = {};

    int srow = tid >> 1;
    int half = tid & 1;
    int grow = bm + srow;
    int brow = bn + srow;

    for (int k0 = 0; k0 < K; k0 += 64) {
        // stage A: row srow, 64B half, 4x16B units c = half*4+i, phys = c^(row&7)
        {
            uint4 v[4];
#pragma unroll
            for (int i = 0; i < 4; ++i) { v[i].x = v[i].y = v[i].z = v[i].w = 0; }
            if (grow < M) {
                const uint4* ga = (const uint4*)(A + (size_t)grow * K + k0 + half * 32);
#pragma unroll
                for (int i = 0; i < 4; ++i) v[i] = ga[i];
            }
            char* d = As + srow * 128;
#pragma unroll
            for (int i = 0; i < 4; ++i)
                *(uint4*)(d + (((half * 4 + i) ^ (srow & 7)) << 4)) = v[i];
        }
        {
            uint4 v[4];
#pragma unroll
            for (int i = 0; i < 4; ++i) { v[i].x = v[i].y = v[i].z = v[i].w = 0; }
            if (brow < N) {
                const uint4* gb = (const uint4*)(Bt + (size_t)brow * K + k0 + half * 32);
#pragma unroll
                for (int i = 0; i < 4; ++i) v[i] = gb[i];
            }
            char* d = Bs + srow * 128;
#pragma unroll
            for (int i = 0; i < 4; ++i)
                *(uint4*)(d + (((half * 4 + i) ^ (srow & 7)) << 4)) = v[i];
        }
        __syncthreads();

#pragma unroll
        for (int ks = 0; ks < 2; ++ks) {
            short8 af[4], bfr[4];
#pragma unroll
            for (int mr = 0; mr < 4; ++mr) {
                int r = wm + mr * 16 + l15;
                af[mr] = *(const short8*)(As + r * 128 + (((ks * 4 + lg) ^ (r & 7)) << 4));
            }
#pragma unroll
            for (int nc = 0; nc < 4; ++nc) {
                int r = wn + nc * 16 + l15;
                bfr[nc] = *(const short8*)(Bs + r * 128 + (((ks * 4 + lg) ^ (r & 7)) << 4));
            }
#pragma unroll
            for (int mr = 0; mr < 4; ++mr)
#pragma unroll
                for (int nc = 0; nc < 4; ++nc)
                    acc[mr][nc] = __builtin_amdgcn_mfma_f32_16x16x32_bf16(
                        af[mr], bfr[nc], acc[mr][nc], 0, 0, 0);
        }
        __syncthreads();
    }

    // epilogue: bf16 C tile into LDS (128 rows x 256B, 16B-unit XOR swizzle)
    char* Cs = smem;
#pragma unroll
    for (int mr = 0; mr < 4; ++mr) {
#pragma unroll
        for (int nc = 0; nc < 4; ++nc) {
            int coll = wn + nc * 16 + l15;
            float b = bias ? bias[bn + coll] : 0.f;
            int u0 = coll >> 3;
#pragma unroll
            for (int j = 0; j < 4; ++j) {
                int row = wm + mr * 16 + lg * 4 + j;
                int u = u0 ^ (row & 7);
                *(ushort_t*)(Cs + row * 256 + (u << 4) + ((coll & 7) << 1)) =
                    f2bf(acc[mr][nc][j] + b);
            }
        }
    }
    __syncthreads();
    {
        int row = tid >> 1;
        int hf = tid & 1;
        int gr = bm + row;
        if (gr < M) {
            uint4* d = (uint4*)(Yb + (size_t)gr * N + bn + hf * 64);
#pragma unroll
            for (int i = 0; i < 8; ++i) {
                int u = (hf * 8 + i) ^ (row & 7);
                d[i] = *(const uint4*)(Cs + row * 256 + (u << 4));
            }
        }
    }
}

// ---------------------------------------------------------------- edge GEMM
// eb[r, :512] = ea_b[perm[e0+r], :96] @ We[512,96]^T (bf16). Full-K single-stage.

#define EG_LDSB 49152

__global__ __launch_bounds__(256) void k_egemm(
    const ushort_t* __restrict__ Ab, const ushort_t* __restrict__ Bt,
    ushort_t* __restrict__ Yb, const int* __restrict__ perm,
    int pbase, int ec) {
    __shared__ char smem[EG_LDSB];
    char* As = smem;
    char* Bs = smem + 24576;

    int tid  = threadIdx.x;
    int lane = tid & 63, wave = tid >> 6;
    int l15 = lane & 15, lg = lane >> 4;
    int nwg = gridDim.x;
    int bid = blockIdx.x;
    int wg;
    if ((nwg & 7) == 0) { int cpx = nwg >> 3; wg = (bid & 7) * cpx + (bid >> 3); }
    else wg = bid;
    int bm = (wg >> 2) * 128;
    int n0 = (wg & 3) * 128;
    int wm = (wave >> 1) * 64, wn = (wave & 1) * 64;

    int srow = tid >> 1;
    int h    = tid & 1;
    int ssw  = ((srow >> 1) & 3) << 4;
    {
        int gm = bm + srow;
        uint4 va[6];
#pragma unroll
        for (int i = 0; i < 6; ++i) { va[i].x = va[i].y = va[i].z = va[i].w = 0; }
        if (gm < ec) {
            int ar = perm[pbase + gm];
            const uint4* ga = (const uint4*)(Ab + (size_t)ar * EDP + h * 48);
#pragma unroll
            for (int i = 0; i < 6; ++i) va[i] = ga[i];
        }
        char* dsta = As + srow * 192;
#pragma unroll
        for (int i = 0; i < 6; ++i) {
            int c = h * 96 + i * 16;
            *(uint4*)(dsta + ((c & ~63) | ((c & 63) ^ ssw))) = va[i];
        }
        uint4 vb[6];
        {
            const uint4* gb = (const uint4*)(Bt + (size_t)(n0 + srow) * EDP + h * 48);
#pragma unroll
            for (int i = 0; i < 6; ++i) vb[i] = gb[i];
        }
        char* dstb = Bs + srow * 192;
#pragma unroll
        for (int i = 0; i < 6; ++i) {
            int c = h * 96 + i * 16;
            *(uint4*)(dstb + ((c & ~63) | ((c & 63) ^ ssw))) = vb[i];
        }
    }
    __syncthreads();

    int fsw = ((l15 >> 1) & 3) << 4;

    f32x4 acc[4][4] = {};
#pragma unroll
    for (int ks = 0; ks < 3; ++ks) {
        short8 af[4], bfr[4];
#pragma unroll
        for (int mr = 0; mr < 4; ++mr) {
            int r = wm + mr * 16 + l15;
            int c = ks * 64 + ((lg * 16) ^ fsw);
            af[mr] = *(const short8*)(As + r * 192 + c);
        }
#pragma unroll
        for (int nc = 0; nc < 4; ++nc) {
            int r = wn + nc * 16 + l15;
            int c = ks * 64 + ((lg * 16) ^ fsw);
            bfr[nc] = *(const short8*)(Bs + r * 192 + c);
        }
#pragma unroll
        for (int mr = 0; mr < 4; ++mr)
#pragma unroll
            for (int nc = 0; nc < 4; ++nc)
                acc[mr][nc] = __builtin_amdgcn_mfma_f32_16x16x32_bf16(
                    af[mr], bfr[nc], acc[mr][nc], 0, 0, 0);
    }
    __syncthreads();

    char* Cs = smem;   // 128 * 288 = 36864
#pragma unroll
    for (int mr = 0; mr < 4; ++mr) {
#pragma unroll
        for (int nc = 0; nc < 4; ++nc) {
            int col = wn + nc * 16 + l15;
#pragma unroll
            for (int j = 0; j < 4; ++j) {
                int row = wm + mr * 16 + lg * 4 + j;
                *(ushort_t*)(Cs + row * 288 + col * 2) = f2bf(acc[mr][nc][j]);
            }
        }
    }
    __syncthreads();

    {
        int row = tid >> 1;
        int halfc = tid & 1;
        if (bm + row < ec) {
            const uint4* srcp = (const uint4*)(Cs + row * 288 + halfc * 128);
            uint4* dstg = (uint4*)(Yb + (size_t)(bm + row) * HC + n0 + halfc * 64);
#pragma unroll
            for (int i = 0; i < 8; ++i) dstg[i] = srcp[i];
        }
    }
}

// ---------------------------------------------------------------- fused edge phase
// One block (128 thr = 2 waves) per dst node. Wave w handles edges lo+w, lo+w+2,...
// Each lane owns 8 channels (16B loads). Online softmax; LDS merge of 2 states.
// fresh = node's first chunk -> init state in-register (no macc/mbuf read).

__global__ __launch_bounds__(128) void k_edge(
    const ushort_t* __restrict__ qkvs, const ushort_t* __restrict__ eb,
    const int* __restrict__ psrc, const int* __restrict__ rowptr,
    float* __restrict__ macc, float* __restrict__ mbuf, float* __restrict__ dbuf,
    int e0, int e1) {
    int n = blockIdx.x;
    int beg = rowptr[n], end = rowptr[n + 1];
    int lo = beg > e0 ? beg : e0;
    int hi = end < e1 ? end : e1;
    if (lo >= hi) return;

    int t = threadIdx.x;
    int w = t >> 6;
    int lane = t & 63;
    int c0 = lane * 8;
    int h = lane >> 2;
    bool fresh = (beg >= e0);

    float q[8];
    unpack8(*(const uint4*)(qkvs + (size_t)n * NCAT + c0), q);

    float mm, dd, a[8];
    if (w == 0 && !fresh) {
        mm = mbuf[n * NH + h];
        dd = dbuf[n * NH + h];
        float4 a0 = *(const float4*)(macc + (size_t)n * HC + c0);
        float4 a1 = *(const float4*)(macc + (size_t)n * HC + c0 + 4);
        a[0] = a0.x; a[1] = a0.y; a[2] = a0.z; a[3] = a0.w;
        a[4] = a1.x; a[5] = a1.y; a[6] = a1.z; a[7] = a1.w;
    } else {
        mm = -1e30f; dd = 0.f;
#pragma unroll
        for (int j = 0; j < 8; ++j) a[j] = 0.f;
    }

    int i = lo + w;
    uint4 ku4, vu4, eu4;
    if (i < hi) {
        int sn = psrc[i];
        ku4 = *(const uint4*)(qkvs + (size_t)sn * NCAT + 512 + c0);
        vu4 = *(const uint4*)(qkvs + (size_t)sn * NCAT + 1024 + c0);
        eu4 = *(const uint4*)(eb + (size_t)(i - e0) * HC + c0);
    }
    while (i < hi) {
        uint4 kc = ku4, vc = vu4, ec = eu4;
        int inext = i + 2;
        if (inext < hi) {
            int sn2 = psrc[inext];
            ku4 = *(const uint4*)(qkvs + (size_t)sn2 * NCAT + 512 + c0);
            vu4 = *(const uint4*)(qkvs + (size_t)sn2 * NCAT + 1024 + c0);
            eu4 = *(const uint4*)(eb + (size_t)(inext - e0) * HC + c0);
        }
        float kk[8], vv[8], ee[8];
        unpack8(kc, kk); unpack8(vc, vv); unpack8(ec, ee);
        float part = 0.f;
#pragma unroll
        for (int j = 0; j < 8; ++j) part += q[j] * (kk[j] + ee[j]);
        part += __shfl_xor(part, 1);
        part += __shfl_xor(part, 2);
        float s = part * 0.17677669529663687f;   // /sqrt(32)
        float mn = fmaxf(mm, s);
        float sc = __expf(mm - mn);
        float p  = __expf(s - mn);
        dd = dd * sc + p;
        mm = mn;
#pragma unroll
        for (int j = 0; j < 8; ++j) a[j] = a[j] * sc + p * (vv[j] + ee[j]);
        i = inext;
    }

    // merge the two wave states
    __shared__ float sm_acc[512];
    __shared__ float sm_m[16];
    __shared__ float sm_d[16];
    if (w == 1) {
#pragma unroll
        for (int j = 0; j < 8; ++j) sm_acc[c0 + j] = a[j];
        if ((lane & 3) == 0) { sm_m[h] = mm; sm_d[h] = dd; }
    }
    __syncthreads();
    if (w == 0) {
        float m1 = sm_m[h], d1 = sm_d[h];
        float M = fmaxf(mm, m1);
        float sc0 = __expf(mm - M);
        float sc1 = __expf(m1 - M);
        dd = dd * sc0 + d1 * sc1;
        float4 o0, o1;
        o0.x = a[0] * sc0 + sm_acc[c0 + 0] * sc1;
        o0.y = a[1] * sc0 + sm_acc[c0 + 1] * sc1;
        o0.z = a[2] * sc0 + sm_acc[c0 + 2] * sc1;
        o0.w = a[3] * sc0 + sm_acc[c0 + 3] * sc1;
        o1.x = a[4] * sc0 + sm_acc[c0 + 4] * sc1;
        o1.y = a[5] * sc0 + sm_acc[c0 + 5] * sc1;
        o1.z = a[6] * sc0 + sm_acc[c0 + 6] * sc1;
        o1.w = a[7] * sc0 + sm_acc[c0 + 7] * sc1;
        *(float4*)(macc + (size_t)n * HC + c0) = o0;
        *(float4*)(macc + (size_t)n * HC + c0 + 4) = o1;
        if ((lane & 3) == 0) { mbuf[n * NH + h] = M; dbuf[n * NH + h] = dd; }
    }
}

// x_out = leaky_relu(macc/d + skip, 0.2); skip read bf16 from qkvs[:,1536:2048]
__global__ void k_epi2(const float* __restrict__ macc, const float* __restrict__ dbuf,
                       const ushort_t* __restrict__ qkvs, float* __restrict__ xout,
                       ushort_t* __restrict__ xoutb, int n) {
    int i = blockIdx.x * blockDim.x + threadIdx.x;
    int stride = gridDim.x * blockDim.x;
    for (; i < n; i += stride) {
        int node = i >> 9, c = i & (HC - 1);
        int h = c >> 5;
        float dd = dbuf[node * NH + h];
        float msg = (dd > 0.f) ? macc[i] / dd : 0.f;
        float sk = bf2f(qkvs[(size_t)node * NCAT + 1536 + c]);
        float v = msg + sk;
        v = v >= 0.f ? v : 0.2f * v;
        xout[i] = v;
        if (xoutb) xoutb[i] = f2bf(v);
    }
}

// ---------------------------------------------------------------- pooling

__global__ __launch_bounds__(256) void k_pool2(
    const float* __restrict__ x, const int* __restrict__ batch,
    float* __restrict__ psum, float* __restrict__ pmax, int* __restrict__ cnt) {
    int b = blockIdx.x;
    int s = blockIdx.y;
    int lo = 0, hi = N_NODES;
    while (lo < hi) { int mid = (lo + hi) >> 1; if (batch[mid] < b) lo = mid + 1; else hi = mid; }
    int beg = lo;
    hi = N_NODES;
    while (lo < hi) { int mid = (lo + hi) >> 1; if (batch[mid] < b + 1) lo = mid + 1; else hi = mid; }
    int end = lo;
    if (s == 0 && threadIdx.x == 0) cnt[b] = end - beg;
    int cn = end - beg;
    int per = (cn + 7) >> 3;
    int nb = beg + s * per;
    int ne = nb + per; if (ne > end) ne = end;
    if (nb >= ne) return;
    int c0 = threadIdx.x * 2;
    float s0 = 0.f, s1 = 0.f, m0 = -1e30f, m1 = -1e30f;
    for (int n = nb; n < ne; ++n) {
        float2 v = *(const float2*)(x + (size_t)n * HC + c0);
        s0 += v.x; s1 += v.y;
        m0 = fmaxf(m0, v.x); m1 = fmaxf(m1, v.y);
    }
    atomicAdd(&psum[b * HC + c0], s0);
    atomicAdd(&psum[b * HC + c0 + 1], s1);
    atomicMaxF(&pmax[b * HC + c0], m0);
    atomicMaxF(&pmax[b * HC + c0 + 1], m1);
}

__global__ void k_poolfin(const float* __restrict__ psum, const float* __restrict__ pmax,
                          const int* __restrict__ cnt, float* __restrict__ hsum, int mode) {
    int i = blockIdx.x * blockDim.x + threadIdx.x;
    if (i >= NB * 1024) return;
    int b = i >> 10, c = i & 1023;
    float val;
    if (c < HC) {
        int ct = cnt[b];
        val = psum[b * HC + c] / (float)(ct > 0 ? ct : 1);
    } else {
        val = pmax[b * HC + (c - HC)];
    }
    if (mode == 0) hsum[i] = val;
    else hsum[i] += val;
}

// ---------------------------------------------------------------- MLP head

__global__ __launch_bounds__(256) void k_head(
    const float* __restrict__ hsum, const float* __restrict__ fc1W,
    const float* __restrict__ fc1b, const float* __restrict__ fc2W,
    const float* __restrict__ fc2b, float* __restrict__ out) {
    int b = blockIdx.x;
    int j = threadIdx.x;
    __shared__ float hs[256];
    float acc = fc1b[j];
    const float* hin = hsum + (size_t)b * 1024;
    for (int k = 0; k < 1024; ++k) {
        acc += hin[k] * fc1W[(size_t)k * 256 + j];
    }
    hs[j] = fmaxf(acc, 0.f);
    __syncthreads();
    if (j < 32) {
        float o = fc2b[j];
        for (int k = 0; k < 256; ++k) o += hs[k] * fc2W[(size_t)k * 32 + j];
        out[b * 32 + j] = o;
    }
}

// ---------------------------------------------------------------- driver

extern "C" void kernel_launch(void* const* d_in, const int* in_sizes, int n_in,
                              void* d_out, int out_size, void* d_ws, size_t ws_size,
                              hipStream_t stream) {
    const float* x      = (const float*)d_in[0];
    const float* ea     = (const float*)d_in[1];
    const int*   ei     = (const int*)d_in[2];
    const int*   batch  = (const int*)d_in[3];
    const int* src = ei;
    const int* dst = ei + N_EDGES;

    const float* t1_Wq = (const float*)d_in[4];
    const float* t1_bq = (const float*)d_in[5];
    const float* t1_Wk = (const float*)d_in[6];
    const float* t1_bk = (const float*)d_in[7];
    const float* t1_Wv = (const float*)d_in[8];
    const float* t1_bv = (const float*)d_in[9];
    const float* t1_We = (const float*)d_in[10];
    const float* t1_Ws = (const float*)d_in[11];
    const float* t1_bs = (const float*)d_in[12];
    const float* t2_Wq = (const float*)d_in[13];
    const float* t2_bq = (const float*)d_in[14];
    const float* t2_Wk = (const float*)d_in[15];
    const float* t2_bk = (const float*)d_in[16];
    const float* t2_Wv = (const float*)d_in[17];
    const float* t2_bv = (const float*)d_in[18];
    const float* t2_We = (const float*)d_in[19];
    const float* t2_Ws = (const float*)d_in[20];
    const float* t2_bs = (const float*)d_in[21];
    const float* fc1_W = (const float*)d_in[22];
    const float* fc1_b = (const float*)d_in[23];
    const float* fc2_W = (const float*)d_in[24];
    const float* fc2_b = (const float*)d_in[25];

    char* ws = (char*)d_ws;
    size_t off = 0;
    auto alloc = [&](size_t bytes) -> void* {
        void* p = ws + off;
        off = (off + bytes + 255) & ~(size_t)255;
        return p;
    };

    ushort_t* qkvs = (ushort_t*)alloc((size_t)N_NODES * NCAT * 2);  // q|k|v|skip bf16
    float* x1   = (float*)alloc((size_t)N_NODES * HC * 4);
    float* macc = (float*)alloc((size_t)N_NODES * HC * 4);
    float* mbuf = (float*)alloc((size_t)N_NODES * NH * 4);
    float* dbuf = (float*)alloc((size_t)N_NODES * NH * 4);
    float* psum = (float*)alloc((size_t)NB * HC * 4);
    float* pmaxb= (float*)alloc((size_t)NB * HC * 4);
    float* hsum = (float*)alloc((size_t)NB * 1024 * 4);
    int*   cnt  = (int*)alloc((size_t)NB * 4);
    // CSR
    int* deg    = (int*)alloc((size_t)N_NODES * 4);
    int* rowptr = (int*)alloc((size_t)(N_NODES + 1) * 4);
    int* cursor = (int*)alloc((size_t)N_NODES * 4);
    int* perm   = (int*)alloc((size_t)N_EDGES * 4);
    int* psrc   = (int*)alloc((size_t)N_EDGES * 4);
    // bf16 activations
    ushort_t* x_b  = (ushort_t*)alloc((size_t)N_NODES * IN_CH * 2);
    ushort_t* x1_b = (ushort_t*)alloc((size_t)N_NODES * HC * 2);
    // pre-padded bf16 edge_attr [E, 96]
    ushort_t* ea_b = (ushort_t*)alloc((size_t)N_EDGES * EDP * 2);
    // weights bf16
    ushort_t* wcat1 = (ushort_t*)alloc((size_t)NCAT * IN_CH * 2);
    ushort_t* wcat2 = (ushort_t*)alloc((size_t)NCAT * HC * 2);
    ushort_t* w1e   = (ushort_t*)alloc((size_t)HC * EDP * 2);
    ushort_t* w2e   = (ushort_t*)alloc((size_t)HC * EDP * 2);
    float* bcat1 = (float*)alloc((size_t)NCAT * 4);
    float* bcat2 = (float*)alloc((size_t)NCAT * 4);

    // remaining -> bf16 edge-feature chunk buffer eb [EC, HC]
    size_t remain = (ws_size > off) ? (ws_size - off) : 0;
    ushort_t* eb = (ushort_t*)(ws + off);
    size_t per_edge = (size_t)HC * 2;  // 1 KiB
    int EC;
    if (remain >= (size_t)N_EDGES * per_edge) {
        EC = N_EDGES;
    } else {
        EC = (int)(remain / per_edge);
        EC &= ~255;
        if (EC <= 0) EC = 256;
        if (EC > N_EDGES) EC = N_EDGES;
    }
    (void)in_sizes; (void)n_in; (void)out_size;

    const int NHC = N_NODES * HC;

    // ---- CSR build
    hipLaunchKernelGGL(k_zero_i, dim3(79), dim3(256), 0, stream, deg, N_NODES);
    hipLaunchKernelGGL(k_hist, dim3((N_EDGES + 255) / 256), dim3(256), 0, stream, dst, deg);
    hipLaunchKernelGGL(k_scan, dim3(1), dim3(1024), 0, stream, deg, rowptr);
    hipLaunchKernelGGL(k_copy_i, dim3(79), dim3(256), 0, stream, rowptr, cursor, N_NODES);
    hipLaunchKernelGGL(k_scatter, dim3((N_EDGES + 255) / 256), dim3(256), 0, stream,
                       src, dst, cursor, perm, psrc);

    // ---- conversions
    hipLaunchKernelGGL(k_cvt_pad, dim3(1024), dim3(256), 0, stream, x, x_b, N_NODES, IN_CH, IN_CH);
    hipLaunchKernelGGL(k_cvt_pad, dim3(4096), dim3(256), 0, stream, ea, ea_b, N_EDGES, ED, EDP);
    hipLaunchKernelGGL(k_cvt_wt, dim3(256), dim3(256), 0, stream, t1_Wq, wcat1 + (size_t)0 * HC * IN_CH, IN_CH, HC, IN_CH);
    hipLaunchKernelGGL(k_cvt_wt, dim3(256), dim3(256), 0, stream, t1_Wk, wcat1 + (size_t)1 * HC * IN_CH, IN_CH, HC, IN_CH);
    hipLaunchKernelGGL(k_cvt_wt, dim3(256), dim3(256), 0, stream, t1_Wv, wcat1 + (size_t)2 * HC * IN_CH, IN_CH, HC, IN_CH);
    hipLaunchKernelGGL(k_cvt_wt, dim3(256), dim3(256), 0, stream, t1_Ws, wcat1 + (size_t)3 * HC * IN_CH, IN_CH, HC, IN_CH);
    hipLaunchKernelGGL(k_cvt_wt, dim3(1024), dim3(256), 0, stream, t2_Wq, wcat2 + (size_t)0 * HC * HC, HC, HC, HC);
    hipLaunchKernelGGL(k_cvt_wt, dim3(1024), dim3(256), 0, stream, t2_Wk, wcat2 + (size_t)1 * HC * HC, HC, HC, HC);
    hipLaunchKernelGGL(k_cvt_wt, dim3(1024), dim3(256), 0, stream, t2_Wv, wcat2 + (size_t)2 * HC * HC, HC, HC, HC);
    hipLaunchKernelGGL(k_cvt_wt, dim3(1024), dim3(256), 0, stream, t2_Ws, wcat2 + (size_t)3 * HC * HC, HC, HC, HC);
    hipLaunchKernelGGL(k_cvt_wt, dim3(192), dim3(256), 0, stream, t1_We, w1e, ED, HC, EDP);
    hipLaunchKernelGGL(k_cvt_wt, dim3(192), dim3(256), 0, stream, t2_We, w2e, ED, HC, EDP);
    hipLaunchKernelGGL(k_bcat, dim3(8), dim3(256), 0, stream, t1_bq, t1_bk, t1_bv, t1_bs, bcat1);
    hipLaunchKernelGGL(k_bcat, dim3(8), dim3(256), 0, stream, t2_bq, t2_bk, t2_bv, t2_bs, bcat2);

    auto run_layer = [&](const ushort_t* xin_b, int Kin, const ushort_t* wcat,
                         const float* bcat, const ushort_t* we,
                         float* xout, ushort_t* xoutb, int poolmode) {
        // fused QKVS GEMM: [N_NODES, Kin] @ [Kin, 2048] -> qkvs bf16
        {
            int mt = (N_NODES + 127) / 128;
            int nt = NCAT / 128;
            hipLaunchKernelGGL(k_mfma_gemm, dim3(mt * nt), dim3(256), 0, stream,
                               xin_b, wcat, bcat, qkvs, N_NODES, Kin, NCAT);
        }
        // edge-phase state init: only dbuf needed (isolated-node guard in epi2);
        // k_edge fresh-inits per-node state on its first chunk.
        hipLaunchKernelGGL(k_fill, dim3(512), dim3(256), 0, stream, dbuf, 0.f, N_NODES * NH);

        // chunked: e-GEMM (gathered, bf16 out) + fused edge pass
        for (int e0 = 0; e0 < N_EDGES; e0 += EC) {
            int ec = (N_EDGES - e0 < EC) ? (N_EDGES - e0) : EC;
            int gm = (ec + 127) / 128;
            hipLaunchKernelGGL(k_egemm, dim3(gm * 4), dim3(256), 0, stream,
                               ea_b, we, eb, perm, e0, ec);
            hipLaunchKernelGGL(k_edge, dim3(N_NODES), dim3(128), 0, stream,
                               qkvs, eb, psrc, rowptr, macc, mbuf, dbuf, e0, e0 + ec);
        }
        hipLaunchKernelGGL(k_epi2, dim3(2048), dim3(256), 0, stream,
                           macc, dbuf, qkvs, xout, xoutb, NHC);

        // pooling
        hipLaunchKernelGGL(k_fill, dim3(128), dim3(256), 0, stream, psum, 0.f, NB * HC);
        hipLaunchKernelGGL(k_fill, dim3(128), dim3(256), 0, stream, pmaxb, -1e30f, NB * HC);
        hipLaunchKernelGGL(k_pool2, dim3(NB, 8), dim3(256), 0, stream, xout, batch, psum, pmaxb, cnt);
        hipLaunchKernelGGL(k_poolfin, dim3((NB * 1024 + 255) / 256), dim3(256), 0, stream,
                           psum, pmaxb, cnt, hsum, poolmode);
    };

    // layer 1: x_b (N,128) -> x1 (+x1_b) ; layer 2: x1_b (N,512) -> x1
    run_layer(x_b, IN_CH, wcat1, bcat1, w1e, x1, x1_b, /*poolmode=*/0);
    run_layer(x1_b, HC, wcat2, bcat2, w2e, x1, (ushort_t*)nullptr, /*poolmode=*/1);

    hipLaunchKernelGGL(k_head, dim3(NB), dim3(256), 0, stream,
                       hsum, fc1_W, fc1_b, fc2_W, fc2_b, (float*)d_out);
}